// Round 11
// baseline (789.375 us; speedup 1.0000x reference)
//
#include <hip/hip_runtime.h>
#include <math.h>

#define D_MODEL 512
#define N_LAYERS 4
#define LATENT 1024
#define D_INNER 1024
#define D_STATE 16
#define DT_RANK 32
#define KCONV 4
#define BATCH 4
#define SEQ 1024
#define NTOK (BATCH * SEQ) /* 4096 */
#define PCH 32
#define CLEN 32

typedef __attribute__((ext_vector_type(8))) short short8;
typedef __attribute__((ext_vector_type(4))) float floatx4;
typedef unsigned short ushort_t;

// gfx9 s_waitcnt immediates: vmcnt lo[3:0] hi[15:14], expcnt[6:4], lgkm[11:8]
#define WC_VM4   0x0F74  /* vmcnt(4) */
#define WC_VM8   0x0F78  /* vmcnt(8) */
#define WC_VM0   0x0F70  /* vmcnt(0) */
#define WC_LGKM0 0xC07F  /* lgkmcnt(0), vm/exp free */

__device__ __forceinline__ ushort_t f2bf(float f) {
    union { float f; unsigned u; } v; v.f = f;
    unsigned r = v.u + 0x7FFFu + ((v.u >> 16) & 1u);  // RNE
    return (ushort_t)(r >> 16);
}
__device__ __forceinline__ float bf2f(ushort_t u) {
    union { unsigned u; float f; } v; v.u = ((unsigned)u) << 16;
    return v.f;
}
// async global -> LDS, 16B per lane (verified width=16 on gfx950, m97).
__device__ __forceinline__ void gll16(const void* g, void* l) {
    __builtin_amdgcn_global_load_lds(
        (const __attribute__((address_space(1))) void*)g,
        (__attribute__((address_space(3))) void*)l, 16, 0, 0);
}

// ---------------------------------------------------------------------------
// 256x256 2-phase GEMM (inproj): bf16 out = A[M,K] @ Bt[N,K]^T.
// (r10: ~modest win over 64^2; kept. GEMM-rate work closed per r10 failure
// read — rounds 11+ are fusion-only.)
// ---------------------------------------------------------------------------
__global__ __launch_bounds__(512, 2) void gemm_bf16_t256(
    const ushort_t* __restrict__ A, int lda,
    const ushort_t* __restrict__ Bt, int ldb,
    ushort_t* __restrict__ Cb, int ldc,
    int M, int N, int K)
{
    __shared__ ushort_t As[2][16384];   // [buf][256 rows x 64 cols]
    __shared__ ushort_t Bs[2][16384];

    const int gx = gridDim.x;
    const int nwg = gx * gridDim.y;
    const int orig = blockIdx.y * gx + blockIdx.x;
    const int qq = nwg >> 3, rr = nwg & 7;
    const int xcd = orig & 7, loc = orig >> 3;
    const int swz = (xcd < rr ? xcd * (qq + 1) : rr * (qq + 1) + (xcd - rr) * qq) + loc;
    const int m0 = (swz / gx) * 256;
    const int n0 = (swz % gx) * 256;

    const int tid = threadIdx.x;          // 0..511
    const int w = tid >> 6;               // 0..7
    const int lane = tid & 63;
    const int quad = lane >> 4;
    const int l16 = lane & 15;
    const int wm = (w & 1) * 128;         // wave grid 2M x 4N
    const int wn = (w >> 1) * 64;

    const int srow = tid >> 3;                     // 0..63
    const int schunk = ((tid & 7) ^ (srow & 7)) * 8;
    const ushort_t* ga = A + (size_t)(m0 + srow) * lda + schunk;
    const ushort_t* gb = Bt + (size_t)(n0 + srow) * ldb + schunk;
    const int lofs = tid * 8;

    const int swz0 = ((0 * 4 + quad) ^ (l16 & 7)) * 8;
    const int swz1 = ((1 * 4 + quad) ^ (l16 & 7)) * 8;

    floatx4 acc[8][4] = {};
    const int nt = K >> 6;

    #define STAGE(t, b)                                                         \
        do {                                                                    \
            const ushort_t* pa_ = ga + (t) * 64;                                \
            const ushort_t* pb_ = gb + (t) * 64;                                \
            _Pragma("unroll")                                                   \
            for (int q = 0; q < 4; q++) {                                       \
                gll16(pa_ + (size_t)(q * 64) * lda, &As[(b)][q * 4096 + lofs]); \
                gll16(pb_ + (size_t)(q * 64) * ldb, &Bs[(b)][q * 4096 + lofs]); \
            }                                                                   \
        } while (0)

    STAGE(0, 0);

    for (int kt = 0; kt < nt; kt++) {
        const int cur = kt & 1;
        if (kt + 1 < nt) {
            STAGE(kt + 1, 1 - cur);
            __builtin_amdgcn_s_waitcnt(WC_VM8);
        } else {
            __builtin_amdgcn_s_waitcnt(WC_VM0);
        }
        __builtin_amdgcn_s_barrier();

        {
            short8 af[8], bfr[4];
            #pragma unroll
            for (int i = 0; i < 8; i++)
                af[i] = *(const short8*)&As[cur][(wm + i * 16 + l16) * 64 + swz0];
            #pragma unroll
            for (int j = 0; j < 4; j++)
                bfr[j] = *(const short8*)&Bs[cur][(wn + j * 16 + l16) * 64 + swz0];
            __builtin_amdgcn_s_waitcnt(WC_LGKM0);
            #pragma unroll
            for (int i = 0; i < 8; i++)
                #pragma unroll
                for (int j = 0; j < 4; j++)
                    acc[i][j] = __builtin_amdgcn_mfma_f32_16x16x32_bf16(
                        af[i], bfr[j], acc[i][j], 0, 0, 0);
        }
        {
            short8 af[8], bfr[4];
            #pragma unroll
            for (int i = 0; i < 8; i++)
                af[i] = *(const short8*)&As[cur][(wm + i * 16 + l16) * 64 + swz1];
            #pragma unroll
            for (int j = 0; j < 4; j++)
                bfr[j] = *(const short8*)&Bs[cur][(wn + j * 16 + l16) * 64 + swz1];
            __builtin_amdgcn_s_waitcnt(WC_LGKM0);
            #pragma unroll
            for (int i = 0; i < 8; i++)
                #pragma unroll
                for (int j = 0; j < 4; j++)
                    acc[i][j] = __builtin_amdgcn_mfma_f32_16x16x32_bf16(
                        af[i], bfr[j], acc[i][j], 0, 0, 0);
        }
        __builtin_amdgcn_s_barrier();
    }
    #undef STAGE

    #pragma unroll
    for (int j = 0; j < 4; j++) {
        int n = n0 + wn + j * 16 + l16;
        #pragma unroll
        for (int i = 0; i < 8; i++) {
            int mrow = m0 + wm + i * 16 + quad * 4;
            #pragma unroll
            for (int rr2 = 0; rr2 < 4; rr2++)
                Cb[(size_t)(mrow + rr2) * ldc + n] = f2bf(acc[i][j][rr2]);
        }
    }
}

// ---------------------------------------------------------------------------
// bf16 MFMA GEMM, 64x64 tile (r3 structure — proven across 6 passing runs).
// flags: 1 = add bias[n], 2 = accumulate into C (fp32),
//        4 = softplus(v + bias[n]) for n<1024,
//        8 = write bf16 to Cb only,
//       16 = also write bf16 to Cb (combine with 2),
//       32 = fused 32-wide softmax epilogue (lin2): softmax over column
//            groups {32g..32g+31}, written to C (fp32). r11 fusion — the
//            group {n0+wn..+31} is held by 16 lanes (l16) x 2 j-frags of
//            one quad; __shfl_xor masks 1..8 stay within the 16-group.
// ---------------------------------------------------------------------------
__global__ __launch_bounds__(256, 3) void gemm_bf16_tile(
    const ushort_t* __restrict__ A, int lda,
    const ushort_t* __restrict__ Bt, int ldb,
    float* __restrict__ C, ushort_t* __restrict__ Cb, int ldc,
    const float* __restrict__ bias,
    int M, int N, int K, int flags)
{
    __shared__ ushort_t As[3][4096];   // 3 x 8 KB
    __shared__ ushort_t Bs[3][4096];   // 3 x 8 KB

    const int gx = gridDim.x;
    const int nwg = gx * gridDim.y;
    const int orig = blockIdx.y * gx + blockIdx.x;
    const int qq = nwg >> 3, rr = nwg & 7;
    const int xcd = orig & 7, loc = orig >> 3;
    const int swz = (xcd < rr ? xcd * (qq + 1) : rr * (qq + 1) + (xcd - rr) * qq) + loc;
    const int m0 = (swz / gx) * 64;
    const int n0 = (swz % gx) * 64;

    const int tid = threadIdx.x;
    const int w = tid >> 6;
    const int lane = tid & 63;
    const int quad = lane >> 4;
    const int l16 = lane & 15;
    const int wm = (w & 1) * 32;
    const int wn = (w >> 1) * 32;

    const int srow = tid >> 3;
    const int schunk = ((tid & 7) ^ (srow & 7)) * 8;
    const ushort_t* ga = A + (size_t)(m0 + srow) * lda + schunk;
    const ushort_t* gb = Bt + (size_t)(n0 + srow) * ldb + schunk;
    const int lofs = tid * 8;

    const int swz0 = ((0 * 4 + quad) ^ (l16 & 7)) * 8;
    const int swz1 = ((1 * 4 + quad) ^ (l16 & 7)) * 8;

    floatx4 acc[2][2] = {};
    const int nt = K >> 6;

    #define STAGE(t, b)                                         \
        do {                                                    \
            const ushort_t* pa_ = ga + (t) * 64;                \
            const ushort_t* pb_ = gb + (t) * 64;                \
            gll16(pa_, &As[(b)][lofs]);                         \
            gll16(pa_ + (size_t)32 * lda, &As[(b)][2048 + lofs]); \
            gll16(pb_, &Bs[(b)][lofs]);                         \
            gll16(pb_ + (size_t)32 * ldb, &Bs[(b)][2048 + lofs]); \
        } while (0)

    STAGE(0, 0);
    if (nt > 1) STAGE(1, 1);

    int cur = 0;
    for (int kt = 0; kt < nt; kt++) {
        if (kt + 1 < nt) __builtin_amdgcn_s_waitcnt(WC_VM4);
        else             __builtin_amdgcn_s_waitcnt(WC_VM0);
        __builtin_amdgcn_s_barrier();
        __builtin_amdgcn_sched_barrier(0);

        if (kt + 2 < nt) {
            int nb = cur + 2; if (nb >= 3) nb -= 3;
            STAGE(kt + 2, nb);
        }

        short8 af[2][2], bfr[2][2];
        #pragma unroll
        for (int i = 0; i < 2; i++) {
            const int r = wm + i * 16 + l16;
            af[0][i] = *(const short8*)&As[cur][r * 64 + swz0];
            af[1][i] = *(const short8*)&As[cur][r * 64 + swz1];
        }
        #pragma unroll
        for (int j = 0; j < 2; j++) {
            const int r = wn + j * 16 + l16;
            bfr[0][j] = *(const short8*)&Bs[cur][r * 64 + swz0];
            bfr[1][j] = *(const short8*)&Bs[cur][r * 64 + swz1];
        }
        __builtin_amdgcn_s_waitcnt(WC_LGKM0);
        __builtin_amdgcn_sched_barrier(0);

        #pragma unroll
        for (int ks = 0; ks < 2; ks++)
            #pragma unroll
            for (int i = 0; i < 2; i++)
                #pragma unroll
                for (int j = 0; j < 2; j++)
                    acc[i][j] = __builtin_amdgcn_mfma_f32_16x16x32_bf16(
                        af[ks][i], bfr[ks][j], acc[i][j], 0, 0, 0);

        cur++; if (cur == 3) cur = 0;
    }
    #undef STAGE

    // C/D layout (m89-verified): col = lane&15, row = quad*4 + reg.
    if (flags & 32) {
        // fused softmax epilogue: per output row, softmax over the
        // 32-column group held by this quad's 16 lanes x 2 j-frags.
        #pragma unroll
        for (int i = 0; i < 2; i++) {
            #pragma unroll
            for (int rr2 = 0; rr2 < 4; rr2++) {
                float v0 = acc[i][0][rr2] + bias[n0 + wn + l16];
                float v1 = acc[i][1][rr2] + bias[n0 + wn + 16 + l16];
                float m = fmaxf(v0, v1);
                #pragma unroll
                for (int off = 1; off < 16; off <<= 1)
                    m = fmaxf(m, __shfl_xor(m, off));
                float e0 = __expf(v0 - m), e1 = __expf(v1 - m);
                float s = e0 + e1;
                #pragma unroll
                for (int off = 1; off < 16; off <<= 1)
                    s += __shfl_xor(s, off);
                float inv = 1.f / s;
                size_t row = (size_t)(m0 + wm + i * 16 + quad * 4 + rr2) * ldc;
                C[row + n0 + wn + l16] = e0 * inv;
                C[row + n0 + wn + 16 + l16] = e1 * inv;
            }
        }
        return;
    }
    #pragma unroll
    for (int j = 0; j < 2; j++) {
        int n = n0 + wn + j * 16 + l16;
        float bv = (flags & 1) ? bias[n] : 0.f;
        bool do_sp = (flags & 4) && (n < 1024);
        float spb = do_sp ? bias[n] : 0.f;
        #pragma unroll
        for (int i = 0; i < 2; i++) {
            int mrow = m0 + wm + i * 16 + quad * 4;
            #pragma unroll
            for (int rr2 = 0; rr2 < 4; rr2++) {
                size_t idx = (size_t)(mrow + rr2) * ldc + n;
                float v = acc[i][j][rr2] + bv;
                if (do_sp) {
                    v += spb;
                    v = (v > 20.f) ? v : log1pf(__expf(v));
                }
                if (flags & 8) {
                    Cb[idx] = f2bf(v);
                } else {
                    if (flags & 2) v += C[idx];
                    C[idx] = v;
                    if (flags & 16) Cb[idx] = f2bf(v);
                }
            }
        }
    }
}

// ---------------------------------------------------------------------------
// stepA split-K GEMM: Cpart[kq] = u[:, kq*256:(kq+1)*256] @ xw_t^T (N=64).
// ---------------------------------------------------------------------------
__global__ __launch_bounds__(256, 3) void gemm_stepA(
    const ushort_t* __restrict__ A,   // [NTOK][1024] bf16 (u)
    const ushort_t* __restrict__ Bt,  // [64][1024] bf16 (xw_t)
    float* __restrict__ Cpart)        // [4][NTOK][64]
{
    __shared__ ushort_t As[3][4096];
    __shared__ ushort_t Bs[3][4096];

    const int kq = blockIdx.x;          // 0..3 (K window)
    const int m0 = blockIdx.y * 64;
    const int k0 = kq * 256;

    const int tid = threadIdx.x;
    const int w = tid >> 6;
    const int lane = tid & 63;
    const int quad = lane >> 4;
    const int l16 = lane & 15;
    const int wm = (w & 1) * 32;
    const int wn = (w >> 1) * 32;

    const int srow = tid >> 3;
    const int schunk = ((tid & 7) ^ (srow & 7)) * 8;
    const ushort_t* ga = A + (size_t)(m0 + srow) * 1024 + k0 + schunk;
    const ushort_t* gb = Bt + (size_t)srow * 1024 + k0 + schunk;
    const int lofs = tid * 8;

    const int swz0 = ((0 * 4 + quad) ^ (l16 & 7)) * 8;
    const int swz1 = ((1 * 4 + quad) ^ (l16 & 7)) * 8;

    floatx4 acc[2][2] = {};
    const int nt = 4;

    #define STAGE(t, b)                                            \
        do {                                                       \
            const ushort_t* pa_ = ga + (t) * 64;                   \
            const ushort_t* pb_ = gb + (t) * 64;                   \
            gll16(pa_, &As[(b)][lofs]);                            \
            gll16(pa_ + (size_t)32 * 1024, &As[(b)][2048 + lofs]); \
            gll16(pb_, &Bs[(b)][lofs]);                            \
            gll16(pb_ + (size_t)32 * 1024, &Bs[(b)][2048 + lofs]); \
        } while (0)

    STAGE(0, 0);
    STAGE(1, 1);

    int cur = 0;
    for (int kt = 0; kt < nt; kt++) {
        if (kt + 1 < nt) __builtin_amdgcn_s_waitcnt(WC_VM4);
        else             __builtin_amdgcn_s_waitcnt(WC_VM0);
        __builtin_amdgcn_s_barrier();
        __builtin_amdgcn_sched_barrier(0);

        if (kt + 2 < nt) {
            int nb = cur + 2; if (nb >= 3) nb -= 3;
            STAGE(kt + 2, nb);
        }

        short8 af[2][2], bfr[2][2];
        #pragma unroll
        for (int i = 0; i < 2; i++) {
            const int r = wm + i * 16 + l16;
            af[0][i] = *(const short8*)&As[cur][r * 64 + swz0];
            af[1][i] = *(const short8*)&As[cur][r * 64 + swz1];
        }
        #pragma unroll
        for (int j = 0; j < 2; j++) {
            const int r = wn + j * 16 + l16;
            bfr[0][j] = *(const short8*)&Bs[cur][r * 64 + swz0];
            bfr[1][j] = *(const short8*)&Bs[cur][r * 64 + swz1];
        }
        __builtin_amdgcn_s_waitcnt(WC_LGKM0);
        __builtin_amdgcn_sched_barrier(0);

        #pragma unroll
        for (int ks = 0; ks < 2; ks++)
            #pragma unroll
            for (int i = 0; i < 2; i++)
                #pragma unroll
                for (int j = 0; j < 2; j++)
                    acc[i][j] = __builtin_amdgcn_mfma_f32_16x16x32_bf16(
                        af[ks][i], bfr[ks][j], acc[i][j], 0, 0, 0);

        cur++; if (cur == 3) cur = 0;
    }
    #undef STAGE

    float* Cp = Cpart + (size_t)kq * NTOK * 64;
    #pragma unroll
    for (int j = 0; j < 2; j++) {
        int n = wn + j * 16 + l16;
        #pragma unroll
        for (int i = 0; i < 2; i++) {
            int mrow = m0 + wm + i * 16 + quad * 4;
            #pragma unroll
            for (int rr2 = 0; rr2 < 4; rr2++)
                Cp[(size_t)(mrow + rr2) * 64 + n] = acc[i][j][rr2];
        }
    }
}

// ---------------------------------------------------------------------------
// reduce_dblr: dblr = sum of 4 split-K partials (fp32 only; bf16 copy no
// longer needed — stepB is gone, dt is computed inline in the scan).
// ---------------------------------------------------------------------------
__global__ __launch_bounds__(256) void reduce_dblr(
    const float* __restrict__ part, float* __restrict__ dblr)
{
    const int i = blockIdx.x * 256 + threadIdx.x;
    const size_t st = (size_t)NTOK * 64;
    dblr[i] = part[i] + part[i + st] + part[i + 2 * st] + part[i + 3 * st];
}

// ---------------------------------------------------------------------------
// Batched transpose+cast: z-dim = layer. in[l][K][N] -> out[l][N][K] bf16.
// ---------------------------------------------------------------------------
__global__ __launch_bounds__(256) void transpose_cast_b(
    const float* __restrict__ in0, ushort_t* __restrict__ out0, int K, int N,
    size_t in_ls, size_t out_ls)
{
    const float* in = in0 + (size_t)blockIdx.z * in_ls;
    ushort_t* out = out0 + (size_t)blockIdx.z * out_ls;
    __shared__ float tile[32][33];
    const int n0 = blockIdx.x * 32, k0 = blockIdx.y * 32;
    const int tx = threadIdx.x & 31, ty = threadIdx.x >> 5;
    #pragma unroll
    for (int i = 0; i < 4; i++)
        tile[ty + i * 8][tx] = in[(size_t)(k0 + ty + i * 8) * N + n0 + tx];
    __syncthreads();
    #pragma unroll
    for (int i = 0; i < 4; i++)
        out[(size_t)(n0 + ty + i * 8) * K + k0 + tx] = f2bf(tile[tx][ty + i * 8]);
}

// ---------------------------------------------------------------------------
__global__ __launch_bounds__(256) void cast_bf16_kernel(
    const float* __restrict__ in, ushort_t* __restrict__ out)
{
    const int i = blockIdx.x * 256 + threadIdx.x;
    out[i] = f2bf(in[i]);
}

// ---------------------------------------------------------------------------
__global__ __launch_bounds__(256) void rmsnorm_kernel(
    const float* __restrict__ x, const float* __restrict__ w,
    ushort_t* __restrict__ y)
{
    const int row = blockIdx.x;
    const float* xr = x + (size_t)row * D_MODEL;
    ushort_t* yr = y + (size_t)row * D_MODEL;
    const int tid = threadIdx.x;

    float v0 = xr[tid], v1 = xr[tid + 256];
    float ss = v0 * v0 + v1 * v1;
    #pragma unroll
    for (int off = 32; off > 0; off >>= 1) ss += __shfl_down(ss, off);

    __shared__ float wsum[4];
    __shared__ float scale_s;
    int wid = tid >> 6, lane = tid & 63;
    if (lane == 0) wsum[wid] = ss;
    __syncthreads();
    if (tid == 0) {
        float tot = wsum[0] + wsum[1] + wsum[2] + wsum[3];
        scale_s = 1.0f / sqrtf(tot / (float)D_MODEL + 1e-5f);
    }
    __syncthreads();
    float sc = scale_s;
    yr[tid] = f2bf(v0 * sc * w[tid]);
    yr[tid + 256] = f2bf(v1 * sc * w[tid + 256]);
}

// ---------------------------------------------------------------------------
// Causal dwconv (K=4) + bias + silu. Reads bf16 xz (stride 2048, xp plane),
// writes bf16 u.
// ---------------------------------------------------------------------------
__global__ __launch_bounds__(256) void conv_silu_kernel(
    const ushort_t* __restrict__ xz, const float* __restrict__ w,
    const float* __restrict__ bconv, ushort_t* __restrict__ outb)
{
    const int idx = blockIdx.x * 256 + threadIdx.x;
    const int d = idx & (D_INNER - 1);
    const int t = (idx >> 10) & (SEQ - 1);
    const int row = idx >> 10;
    const ushort_t* base = xz + (size_t)row * 2048 + d;

    float s = 0.f;
    #pragma unroll
    for (int k = 0; k < KCONV; k++) {
        int tt = t + k - (KCONV - 1);
        if (tt >= 0)
            s = fmaf(bf2f(base[(ptrdiff_t)(k - (KCONV - 1)) * 2048]), w[d * KCONV + k], s);
    }
    s += bconv[d];
    float r = s / (1.f + __expf(-s));
    outb[idx] = f2bf(r);
}

// ---------------------------------------------------------------------------
// Chunked selective scan (3 passes), CLEN=32. r11: dt computed INLINE from
// dblr[:, :32] (fp32) and dt_w/dt_b (fp32) — stepB + the dtb tensor are
// deleted (16MB write + 2x16MB read + 1 launch per layer). Block covers
// 256 consecutive d, 32 consecutive t: stage dt_w cols (32KB) + dblr chunk
// rows incl. B/C (8KB) in LDS, hoist w2 column to 32 registers, dt = 32
// FMA + softplus per t. Numerically STRICTER than stepB (fp32 vs bf16).
// ---------------------------------------------------------------------------
__global__ __launch_bounds__(256) void scan_pass1(
    const float* __restrict__ dblr, const ushort_t* __restrict__ ub,
    const float* __restrict__ A_log, const float* __restrict__ dtw,
    const float* __restrict__ dtbias,
    float* __restrict__ hfin, float* __restrict__ sumdt)
{
    const int tid = threadIdx.x;
    const int b = blockIdx.x >> 7;
    const int p = (blockIdx.x >> 2) & 31;
    const int d0 = (blockIdx.x & 3) << 8;
    const int d = d0 + tid;
    const int t0 = p * CLEN;

    __shared__ float w2s[32 * 256];   // dt_w[k][d0..d0+255]
    __shared__ float dbs[32 * 64];    // dblr rows of this chunk (dt|B|C)

    for (int i = tid; i < 32 * 256; i += 256)
        w2s[i] = dtw[(size_t)(i >> 8) * D_INNER + d0 + (i & 255)];
    for (int i = tid; i < 32 * 64; i += 256)
        dbs[i] = dblr[(size_t)(b * SEQ + t0 + (i >> 6)) * 64 + (i & 63)];
    __syncthreads();

    float w2c[32];
    #pragma unroll
    for (int k = 0; k < 32; k++) w2c[k] = w2s[k * 256 + tid];
    const float bias_d = dtbias[d];

    float A[D_STATE];
    #pragma unroll
    for (int n = 0; n < D_STATE; n++) A[n] = -expf(A_log[d * D_STATE + n]);

    float h[D_STATE] = {};
    float sdt = 0.f;
    const ushort_t* up = ub + ((size_t)b * SEQ + t0) * D_INNER + d;

    for (int t = 0; t < CLEN; t++) {
        float accd = bias_d;
        #pragma unroll
        for (int k = 0; k < 32; k++)
            accd = fmaf(dbs[t * 64 + k], w2c[k], accd);
        float dtv = (accd > 20.f) ? accd : log1pf(__expf(accd));
        float uv  = bf2f(up[(size_t)t * D_INNER]);
        float dtu = dtv * uv;
        sdt += dtv;
        #pragma unroll
        for (int n = 0; n < D_STATE; n++)
            h[n] = fmaf(__expf(dtv * A[n]), h[n], dtu * dbs[t * 64 + 32 + n]);
    }

    size_t base = (size_t)(b * PCH + p) * D_STATE * D_INNER + d;
    #pragma unroll
    for (int n = 0; n < D_STATE; n++) hfin[base + (size_t)n * D_INNER] = h[n];
    sumdt[(size_t)(b * PCH + p) * D_INNER + d] = sdt;
}

// preload all 32 chunk-final states + sumdt (independent loads), then the
// serial recurrence runs as pure VALU with fire-and-forget writes (r9 win).
__global__ __launch_bounds__(256) void scan_pass2(
    const float* __restrict__ A_log, const float* __restrict__ sumdt,
    float* __restrict__ hc)
{
    const int tid = threadIdx.x;
    const int b = blockIdx.x >> 6;
    const int n = (blockIdx.x >> 2) & 15;
    const int d = ((blockIdx.x & 3) << 8) + tid;

    const float Aval = -expf(A_log[d * D_STATE + n]);

    float fin[PCH], sd[PCH];
    #pragma unroll
    for (int p = 0; p < PCH; p++) {
        fin[p] = hc[((size_t)(b * PCH + p) * D_STATE + n) * D_INNER + d];
        sd[p]  = sumdt[(size_t)(b * PCH + p) * D_INNER + d];
    }
    float h = 0.f;
    #pragma unroll
    for (int p = 0; p < PCH; p++) {
        hc[((size_t)(b * PCH + p) * D_STATE + n) * D_INNER + d] = h;
        h = fmaf(__expf(Aval * sd[p]), h, fin[p]);
    }
}

// pass3: u (bf16, in ub) read then overwritten IN PLACE with y*silu(z).
// dt inline (same scheme as pass1).
__global__ __launch_bounds__(256) void scan_pass3(
    const float* __restrict__ dblr, const ushort_t* __restrict__ xz,
    const float* __restrict__ A_log, const float* __restrict__ dtw,
    const float* __restrict__ dtbias, const float* __restrict__ Dp,
    const float* __restrict__ hstart, ushort_t* ub)
{
    const int tid = threadIdx.x;
    const int b = blockIdx.x >> 7;
    const int p = (blockIdx.x >> 2) & 31;
    const int d0 = (blockIdx.x & 3) << 8;
    const int d = d0 + tid;
    const int t0 = p * CLEN;

    __shared__ float w2s[32 * 256];
    __shared__ float dbs[32 * 64];

    for (int i = tid; i < 32 * 256; i += 256)
        w2s[i] = dtw[(size_t)(i >> 8) * D_INNER + d0 + (i & 255)];
    for (int i = tid; i < 32 * 64; i += 256)
        dbs[i] = dblr[(size_t)(b * SEQ + t0 + (i >> 6)) * 64 + (i & 63)];
    __syncthreads();

    float w2c[32];
    #pragma unroll
    for (int k = 0; k < 32; k++) w2c[k] = w2s[k * 256 + tid];
    const float bias_d = dtbias[d];

    float A[D_STATE];
    #pragma unroll
    for (int n = 0; n < D_STATE; n++) A[n] = -expf(A_log[d * D_STATE + n]);
    const float Dv = Dp[d];

    float h[D_STATE];
    size_t base = (size_t)(b * PCH + p) * D_STATE * D_INNER + d;
    #pragma unroll
    for (int n = 0; n < D_STATE; n++) h[n] = hstart[base + (size_t)n * D_INNER];

    const ushort_t* zp = xz + ((size_t)b * SEQ + t0) * 2048 + 1024 + d;
    ushort_t* up = ub + ((size_t)b * SEQ + t0) * D_INNER + d;

    for (int t = 0; t < CLEN; t++) {
        float accd = bias_d;
        #pragma unroll
        for (int k = 0; k < 32; k++)
            accd = fmaf(dbs[t * 64 + k], w2c[k], accd);
        float dtv = (accd > 20.f) ? accd : log1pf(__expf(accd));
        float uv  = bf2f(up[(size_t)t * D_INNER]);
        float zv  = bf2f(zp[(size_t)t * 2048]);
        float dtu = dtv * uv;
        float y = 0.f;
        #pragma unroll
        for (int n = 0; n < D_STATE; n++) {
            h[n] = fmaf(__expf(dtv * A[n]), h[n], dtu * dbs[t * 64 + 32 + n]);
            y = fmaf(h[n], dbs[t * 64 + 48 + n], y);
        }
        float res = fmaf(uv, Dv, y);
        res *= zv / (1.f + __expf(-zv));
        up[(size_t)t * D_INNER] = f2bf(res);
    }
}

// ---------------------------------------------------------------------------
extern "C" void kernel_launch(void* const* d_in, const int* in_sizes, int n_in,
                              void* d_out, int out_size, void* d_ws, size_t ws_size,
                              hipStream_t stream)
{
    const float* x       = (const float*)d_in[0];
    const float* lin1_w  = (const float*)d_in[1];
    const float* lin1_b  = (const float*)d_in[2];
    const float* norm_w  = (const float*)d_in[3];
    const float* in_w    = (const float*)d_in[4];
    const float* conv_w  = (const float*)d_in[5];
    const float* conv_b  = (const float*)d_in[6];
    const float* xproj_w = (const float*)d_in[7];
    const float* dt_w    = (const float*)d_in[8];
    const float* dt_b    = (const float*)d_in[9];
    const float* A_log   = (const float*)d_in[10];
    const float* Dp      = (const float*)d_in[11];
    const float* out_w   = (const float*)d_in[12];
    const float* lin2_w  = (const float*)d_in[13];
    const float* lin2_b  = (const float*)d_in[14];
    float* outp = (float*)d_out;
    (void)ws_size; (void)in_sizes; (void)n_in; (void)out_size;

    float* ws = (float*)d_ws;
    const size_t F1M = 1u << 20;
    float* h     = ws;                                  // 2M fl
    float* dtb   = h + 2 * F1M;                         // 4M fl (unused now)
    float* dblr  = dtb + 4 * F1M;                       // 256K fl
    float* dpart = dblr + (size_t)NTOK * 64;            // 1M fl (4 split-K partials)
    float* sumdt = dpart + (size_t)4 * NTOK * 64;       // 128K fl
    float* hfin  = sumdt + (size_t)BATCH * PCH * D_INNER;  // 2M fl
    ushort_t* xzb     = (ushort_t*)(hfin + 2 * F1M);       // 8M us (xp|z, 2048)
    ushort_t* hn_bf   = xzb + 8 * F1M;                     // 2M us
    ushort_t* xb      = hn_bf + 2 * F1M;                   // 4M us
    ushort_t* dblr_bf = xb + 4 * F1M;                      // 256K us (unused now)
    ushort_t* lin1_wt = dblr_bf + (size_t)NTOK * 64;       // 512*1024
    ushort_t* in_wt   = lin1_wt + (size_t)512 * 1024;      // 4*2048*512
    ushort_t* out_wt  = in_wt + (size_t)4 * 2048 * 512;    // 4*512*1024
    ushort_t* lin2_wt = out_wt + (size_t)4 * 512 * 1024;   // 1024*512
    ushort_t* xw_t    = lin2_wt + (size_t)1024 * 512;      // 4*64*1024

    dim3 blk(256);

    // --- weight prep (batched: 5 launches; build_w2t deleted) ---
    transpose_cast_b<<<dim3(512 / 32, 1024 / 32, 1), blk, 0, stream>>>(
        lin1_w, lin1_wt, LATENT, D_MODEL, 0, 0);
    transpose_cast_b<<<dim3(2048 / 32, 512 / 32, N_LAYERS), blk, 0, stream>>>(
        in_w, in_wt, 512, 2048, (size_t)512 * 2048, (size_t)2048 * 512);
    transpose_cast_b<<<dim3(512 / 32, 1024 / 32, N_LAYERS), blk, 0, stream>>>(
        out_w, out_wt, 1024, 512, (size_t)1024 * 512, (size_t)512 * 1024);
    transpose_cast_b<<<dim3(64 / 32, 1024 / 32, N_LAYERS), blk, 0, stream>>>(
        xproj_w, xw_t, 1024, 64, (size_t)1024 * 64, (size_t)64 * 1024);
    transpose_cast_b<<<dim3(1024 / 32, 512 / 32, 1), blk, 0, stream>>>(
        lin2_w, lin2_wt, D_MODEL, LATENT, 0, 0);

    // x -> bf16
    cast_bf16_kernel<<<dim3((NTOK * LATENT) / 256), blk, 0, stream>>>(x, xb);

    // lin1: h = x_bf @ lin1_wt^T + b  (fp32 out; 8x64=512 blocks)
    gemm_bf16_tile<<<dim3(D_MODEL / 64, NTOK / 64), blk, 0, stream>>>(
        xb, LATENT, lin1_wt, LATENT, h, nullptr, D_MODEL, lin1_b,
        NTOK, D_MODEL, LATENT, 1);

    for (int l = 0; l < N_LAYERS; l++) {
        const float* nw = norm_w + (size_t)l * D_MODEL;
        const float* cw = conv_w + (size_t)l * D_INNER * KCONV;
        const float* cb = conv_b + (size_t)l * D_INNER;
        const float* db = dt_b + (size_t)l * D_INNER;
        const float* al = A_log + (size_t)l * D_INNER * D_STATE;
        const float* dp = Dp + (size_t)l * D_INNER;
        const float* dw = dt_w + (size_t)l * DT_RANK * D_INNER;
        const ushort_t* iwt = in_wt + (size_t)l * 2048 * 512;
        const ushort_t* owt = out_wt + (size_t)l * 512 * 1024;
        const ushort_t* xwt = xw_t + (size_t)l * 64 * 1024;

        rmsnorm_kernel<<<dim3(NTOK), blk, 0, stream>>>(h, nw, hn_bf);

        // fused in-proj: xzb = hn @ in_w[l] (bf16 out; 256^2 2-phase)
        gemm_bf16_t256<<<dim3(2048 / 256, NTOK / 256), dim3(512), 0, stream>>>(
            hn_bf, D_MODEL, iwt, D_MODEL, xzb, 2048, NTOK, 2048, D_MODEL);

        // conv + silu: xzb[:, :1024] -> xb (bf16 u)
        conv_silu_kernel<<<dim3((NTOK * D_INNER) / 256), blk, 0, stream>>>(
            xzb, cw, cb, xb);

        // xproj step A (split-K x4): dpart[kq] = u @ xw_t^T  (4x64=256 blocks)
        gemm_stepA<<<dim3(4, NTOK / 64), blk, 0, stream>>>(xb, xwt, dpart);
        reduce_dblr<<<dim3((NTOK * 64) / 256), blk, 0, stream>>>(dpart, dblr);

        // chunked scan with INLINE dt (stepB deleted); pass3 overwrites xb
        // in place with y*silu(z)
        scan_pass1<<<dim3(BATCH * PCH * (D_INNER / 256)), blk, 0, stream>>>(
            dblr, xb, al, dw, db, hfin, sumdt);
        scan_pass2<<<dim3(BATCH * D_STATE * (D_INNER / 256)), blk, 0, stream>>>(
            al, sumdt, hfin);
        scan_pass3<<<dim3(BATCH * PCH * (D_INNER / 256)), blk, 0, stream>>>(
            dblr, xzb, al, dw, db, dp, hfin, xb);

        // h += y_bf @ out_wt^T  (fp32 accumulate; 8x64=512 blocks).
        // Last layer also emits bf16(h) -> hn_bf for lin2 (flag 16).
        gemm_bf16_tile<<<dim3(D_MODEL / 64, NTOK / 64), blk, 0, stream>>>(
            xb, D_INNER, owt, D_INNER, h, hn_bf, D_MODEL, nullptr,
            NTOK, D_MODEL, D_INNER, (l == N_LAYERS - 1) ? 18 : 2);
    }

    // lin2 with FUSED softmax epilogue (flag 32): writes outp directly.
    gemm_bf16_tile<<<dim3(LATENT / 64, NTOK / 64), blk, 0, stream>>>(
        hn_bf, D_MODEL, lin2_wt, D_MODEL, outp, nullptr, LATENT, lin2_b,
        NTOK, LATENT, D_MODEL, 1 | 32);
}

// Round 12
// 698.993 us; speedup vs baseline: 1.1293x; 1.1293x over previous
//
#include <hip/hip_runtime.h>
#include <math.h>

#define D_MODEL 512
#define N_LAYERS 4
#define LATENT 1024
#define D_INNER 1024
#define D_STATE 16
#define DT_RANK 32
#define KCONV 4
#define BATCH 4
#define SEQ 1024
#define NTOK (BATCH * SEQ) /* 4096 */
#define PCH 32
#define CLEN 32

typedef __attribute__((ext_vector_type(8))) short short8;
typedef __attribute__((ext_vector_type(4))) float floatx4;
typedef unsigned short ushort_t;

// gfx9 s_waitcnt immediates: vmcnt lo[3:0] hi[15:14], expcnt[6:4], lgkm[11:8]
#define WC_VM4   0x0F74  /* vmcnt(4) */
#define WC_VM8   0x0F78  /* vmcnt(8) */
#define WC_VM0   0x0F70  /* vmcnt(0) */
#define WC_LGKM0 0xC07F  /* lgkmcnt(0), vm/exp free */

__device__ __forceinline__ ushort_t f2bf(float f) {
    union { float f; unsigned u; } v; v.f = f;
    unsigned r = v.u + 0x7FFFu + ((v.u >> 16) & 1u);  // RNE
    return (ushort_t)(r >> 16);
}
__device__ __forceinline__ float bf2f(ushort_t u) {
    union { unsigned u; float f; } v; v.u = ((unsigned)u) << 16;
    return v.f;
}
// async global -> LDS, 16B per lane (verified width=16 on gfx950, m97).
__device__ __forceinline__ void gll16(const void* g, void* l) {
    __builtin_amdgcn_global_load_lds(
        (const __attribute__((address_space(1))) void*)g,
        (__attribute__((address_space(3))) void*)l, 16, 0, 0);
}

// ---------------------------------------------------------------------------
// 256x256 2-phase GEMM (inproj): bf16 out = A[M,K] @ Bt[N,K]^T.
// ---------------------------------------------------------------------------
__global__ __launch_bounds__(512, 2) void gemm_bf16_t256(
    const ushort_t* __restrict__ A, int lda,
    const ushort_t* __restrict__ Bt, int ldb,
    ushort_t* __restrict__ Cb, int ldc,
    int M, int N, int K)
{
    __shared__ ushort_t As[2][16384];   // [buf][256 rows x 64 cols]
    __shared__ ushort_t Bs[2][16384];

    const int gx = gridDim.x;
    const int nwg = gx * gridDim.y;
    const int orig = blockIdx.y * gx + blockIdx.x;
    const int qq = nwg >> 3, rr = nwg & 7;
    const int xcd = orig & 7, loc = orig >> 3;
    const int swz = (xcd < rr ? xcd * (qq + 1) : rr * (qq + 1) + (xcd - rr) * qq) + loc;
    const int m0 = (swz / gx) * 256;
    const int n0 = (swz % gx) * 256;

    const int tid = threadIdx.x;          // 0..511
    const int w = tid >> 6;               // 0..7
    const int lane = tid & 63;
    const int quad = lane >> 4;
    const int l16 = lane & 15;
    const int wm = (w & 1) * 128;         // wave grid 2M x 4N
    const int wn = (w >> 1) * 64;

    const int srow = tid >> 3;                     // 0..63
    const int schunk = ((tid & 7) ^ (srow & 7)) * 8;
    const ushort_t* ga = A + (size_t)(m0 + srow) * lda + schunk;
    const ushort_t* gb = Bt + (size_t)(n0 + srow) * ldb + schunk;
    const int lofs = tid * 8;

    const int swz0 = ((0 * 4 + quad) ^ (l16 & 7)) * 8;
    const int swz1 = ((1 * 4 + quad) ^ (l16 & 7)) * 8;

    floatx4 acc[8][4] = {};
    const int nt = K >> 6;

    #define STAGE(t, b)                                                         \
        do {                                                                    \
            const ushort_t* pa_ = ga + (t) * 64;                                \
            const ushort_t* pb_ = gb + (t) * 64;                                \
            _Pragma("unroll")                                                   \
            for (int q = 0; q < 4; q++) {                                       \
                gll16(pa_ + (size_t)(q * 64) * lda, &As[(b)][q * 4096 + lofs]); \
                gll16(pb_ + (size_t)(q * 64) * ldb, &Bs[(b)][q * 4096 + lofs]); \
            }                                                                   \
        } while (0)

    STAGE(0, 0);

    for (int kt = 0; kt < nt; kt++) {
        const int cur = kt & 1;
        if (kt + 1 < nt) {
            STAGE(kt + 1, 1 - cur);
            __builtin_amdgcn_s_waitcnt(WC_VM8);
        } else {
            __builtin_amdgcn_s_waitcnt(WC_VM0);
        }
        __builtin_amdgcn_s_barrier();

        {
            short8 af[8], bfr[4];
            #pragma unroll
            for (int i = 0; i < 8; i++)
                af[i] = *(const short8*)&As[cur][(wm + i * 16 + l16) * 64 + swz0];
            #pragma unroll
            for (int j = 0; j < 4; j++)
                bfr[j] = *(const short8*)&Bs[cur][(wn + j * 16 + l16) * 64 + swz0];
            __builtin_amdgcn_s_waitcnt(WC_LGKM0);
            #pragma unroll
            for (int i = 0; i < 8; i++)
                #pragma unroll
                for (int j = 0; j < 4; j++)
                    acc[i][j] = __builtin_amdgcn_mfma_f32_16x16x32_bf16(
                        af[i], bfr[j], acc[i][j], 0, 0, 0);
        }
        {
            short8 af[8], bfr[4];
            #pragma unroll
            for (int i = 0; i < 8; i++)
                af[i] = *(const short8*)&As[cur][(wm + i * 16 + l16) * 64 + swz1];
            #pragma unroll
            for (int j = 0; j < 4; j++)
                bfr[j] = *(const short8*)&Bs[cur][(wn + j * 16 + l16) * 64 + swz1];
            __builtin_amdgcn_s_waitcnt(WC_LGKM0);
            #pragma unroll
            for (int i = 0; i < 8; i++)
                #pragma unroll
                for (int j = 0; j < 4; j++)
                    acc[i][j] = __builtin_amdgcn_mfma_f32_16x16x32_bf16(
                        af[i], bfr[j], acc[i][j], 0, 0, 0);
        }
        __builtin_amdgcn_s_barrier();
    }
    #undef STAGE

    #pragma unroll
    for (int j = 0; j < 4; j++) {
        int n = n0 + wn + j * 16 + l16;
        #pragma unroll
        for (int i = 0; i < 8; i++) {
            int mrow = m0 + wm + i * 16 + quad * 4;
            #pragma unroll
            for (int rr2 = 0; rr2 < 4; rr2++)
                Cb[(size_t)(mrow + rr2) * ldc + n] = f2bf(acc[i][j][rr2]);
        }
    }
}

// ---------------------------------------------------------------------------
// bf16 MFMA GEMM, 64x64 tile (r3 structure — proven across 7 passing runs).
// flags: 1 = add bias[n], 2 = accumulate into C (fp32),
//        4 = softplus(v + bias[n]) for n<1024,
//        8 = write bf16 to Cb only,
//       16 = also write bf16 to Cb (combine with 2),
//       32 = fused 32-wide softmax epilogue (lin2, r11-verified): softmax
//            over column groups {32g..32g+31} -> C (fp32). Group held by
//            one quad's 16 lanes x 2 j-frags; shfl_xor masks 1..8 stay
//            inside the 16-lane group.
// ---------------------------------------------------------------------------
__global__ __launch_bounds__(256, 3) void gemm_bf16_tile(
    const ushort_t* __restrict__ A, int lda,
    const ushort_t* __restrict__ Bt, int ldb,
    float* __restrict__ C, ushort_t* __restrict__ Cb, int ldc,
    const float* __restrict__ bias,
    int M, int N, int K, int flags)
{
    __shared__ ushort_t As[3][4096];   // 3 x 8 KB
    __shared__ ushort_t Bs[3][4096];   // 3 x 8 KB

    const int gx = gridDim.x;
    const int nwg = gx * gridDim.y;
    const int orig = blockIdx.y * gx + blockIdx.x;
    const int qq = nwg >> 3, rr = nwg & 7;
    const int xcd = orig & 7, loc = orig >> 3;
    const int swz = (xcd < rr ? xcd * (qq + 1) : rr * (qq + 1) + (xcd - rr) * qq) + loc;
    const int m0 = (swz / gx) * 64;
    const int n0 = (swz % gx) * 64;

    const int tid = threadIdx.x;
    const int w = tid >> 6;
    const int lane = tid & 63;
    const int quad = lane >> 4;
    const int l16 = lane & 15;
    const int wm = (w & 1) * 32;
    const int wn = (w >> 1) * 32;

    const int srow = tid >> 3;
    const int schunk = ((tid & 7) ^ (srow & 7)) * 8;
    const ushort_t* ga = A + (size_t)(m0 + srow) * lda + schunk;
    const ushort_t* gb = Bt + (size_t)(n0 + srow) * ldb + schunk;
    const int lofs = tid * 8;

    const int swz0 = ((0 * 4 + quad) ^ (l16 & 7)) * 8;
    const int swz1 = ((1 * 4 + quad) ^ (l16 & 7)) * 8;

    floatx4 acc[2][2] = {};
    const int nt = K >> 6;

    #define STAGE(t, b)                                         \
        do {                                                    \
            const ushort_t* pa_ = ga + (t) * 64;                \
            const ushort_t* pb_ = gb + (t) * 64;                \
            gll16(pa_, &As[(b)][lofs]);                         \
            gll16(pa_ + (size_t)32 * lda, &As[(b)][2048 + lofs]); \
            gll16(pb_, &Bs[(b)][lofs]);                         \
            gll16(pb_ + (size_t)32 * ldb, &Bs[(b)][2048 + lofs]); \
        } while (0)

    STAGE(0, 0);
    if (nt > 1) STAGE(1, 1);

    int cur = 0;
    for (int kt = 0; kt < nt; kt++) {
        if (kt + 1 < nt) __builtin_amdgcn_s_waitcnt(WC_VM4);
        else             __builtin_amdgcn_s_waitcnt(WC_VM0);
        __builtin_amdgcn_s_barrier();
        __builtin_amdgcn_sched_barrier(0);

        if (kt + 2 < nt) {
            int nb = cur + 2; if (nb >= 3) nb -= 3;
            STAGE(kt + 2, nb);
        }

        short8 af[2][2], bfr[2][2];
        #pragma unroll
        for (int i = 0; i < 2; i++) {
            const int r = wm + i * 16 + l16;
            af[0][i] = *(const short8*)&As[cur][r * 64 + swz0];
            af[1][i] = *(const short8*)&As[cur][r * 64 + swz1];
        }
        #pragma unroll
        for (int j = 0; j < 2; j++) {
            const int r = wn + j * 16 + l16;
            bfr[0][j] = *(const short8*)&Bs[cur][r * 64 + swz0];
            bfr[1][j] = *(const short8*)&Bs[cur][r * 64 + swz1];
        }
        __builtin_amdgcn_s_waitcnt(WC_LGKM0);
        __builtin_amdgcn_sched_barrier(0);

        #pragma unroll
        for (int ks = 0; ks < 2; ks++)
            #pragma unroll
            for (int i = 0; i < 2; i++)
                #pragma unroll
                for (int j = 0; j < 2; j++)
                    acc[i][j] = __builtin_amdgcn_mfma_f32_16x16x32_bf16(
                        af[ks][i], bfr[ks][j], acc[i][j], 0, 0, 0);

        cur++; if (cur == 3) cur = 0;
    }
    #undef STAGE

    // C/D layout (m89-verified): col = lane&15, row = quad*4 + reg.
    if (flags & 32) {
        #pragma unroll
        for (int i = 0; i < 2; i++) {
            #pragma unroll
            for (int rr2 = 0; rr2 < 4; rr2++) {
                float v0 = acc[i][0][rr2] + bias[n0 + wn + l16];
                float v1 = acc[i][1][rr2] + bias[n0 + wn + 16 + l16];
                float m = fmaxf(v0, v1);
                #pragma unroll
                for (int off = 1; off < 16; off <<= 1)
                    m = fmaxf(m, __shfl_xor(m, off));
                float e0 = __expf(v0 - m), e1 = __expf(v1 - m);
                float s = e0 + e1;
                #pragma unroll
                for (int off = 1; off < 16; off <<= 1)
                    s += __shfl_xor(s, off);
                float inv = 1.f / s;
                size_t row = (size_t)(m0 + wm + i * 16 + quad * 4 + rr2) * ldc;
                C[row + n0 + wn + l16] = e0 * inv;
                C[row + n0 + wn + 16 + l16] = e1 * inv;
            }
        }
        return;
    }
    #pragma unroll
    for (int j = 0; j < 2; j++) {
        int n = n0 + wn + j * 16 + l16;
        float bv = (flags & 1) ? bias[n] : 0.f;
        bool do_sp = (flags & 4) && (n < 1024);
        float spb = do_sp ? bias[n] : 0.f;
        #pragma unroll
        for (int i = 0; i < 2; i++) {
            int mrow = m0 + wm + i * 16 + quad * 4;
            #pragma unroll
            for (int rr2 = 0; rr2 < 4; rr2++) {
                size_t idx = (size_t)(mrow + rr2) * ldc + n;
                float v = acc[i][j][rr2] + bv;
                if (do_sp) {
                    v += spb;
                    v = (v > 20.f) ? v : log1pf(__expf(v));
                }
                if (flags & 8) {
                    Cb[idx] = f2bf(v);
                } else {
                    if (flags & 2) v += C[idx];
                    C[idx] = v;
                    if (flags & 16) Cb[idx] = f2bf(v);
                }
            }
        }
    }
}

// ---------------------------------------------------------------------------
// stepA split-K GEMM: Cpart[kq] = u[:, kq*256:(kq+1)*256] @ xw_t^T (N=64).
// ---------------------------------------------------------------------------
__global__ __launch_bounds__(256, 3) void gemm_stepA(
    const ushort_t* __restrict__ A,   // [NTOK][1024] bf16 (u)
    const ushort_t* __restrict__ Bt,  // [64][1024] bf16 (xw_t)
    float* __restrict__ Cpart)        // [4][NTOK][64]
{
    __shared__ ushort_t As[3][4096];
    __shared__ ushort_t Bs[3][4096];

    const int kq = blockIdx.x;          // 0..3 (K window)
    const int m0 = blockIdx.y * 64;
    const int k0 = kq * 256;

    const int tid = threadIdx.x;
    const int w = tid >> 6;
    const int lane = tid & 63;
    const int quad = lane >> 4;
    const int l16 = lane & 15;
    const int wm = (w & 1) * 32;
    const int wn = (w >> 1) * 32;

    const int srow = tid >> 3;
    const int schunk = ((tid & 7) ^ (srow & 7)) * 8;
    const ushort_t* ga = A + (size_t)(m0 + srow) * 1024 + k0 + schunk;
    const ushort_t* gb = Bt + (size_t)srow * 1024 + k0 + schunk;
    const int lofs = tid * 8;

    const int swz0 = ((0 * 4 + quad) ^ (l16 & 7)) * 8;
    const int swz1 = ((1 * 4 + quad) ^ (l16 & 7)) * 8;

    floatx4 acc[2][2] = {};
    const int nt = 4;

    #define STAGE(t, b)                                            \
        do {                                                       \
            const ushort_t* pa_ = ga + (t) * 64;                   \
            const ushort_t* pb_ = gb + (t) * 64;                   \
            gll16(pa_, &As[(b)][lofs]);                            \
            gll16(pa_ + (size_t)32 * 1024, &As[(b)][2048 + lofs]); \
            gll16(pb_, &Bs[(b)][lofs]);                            \
            gll16(pb_ + (size_t)32 * 1024, &Bs[(b)][2048 + lofs]); \
        } while (0)

    STAGE(0, 0);
    STAGE(1, 1);

    int cur = 0;
    for (int kt = 0; kt < nt; kt++) {
        if (kt + 1 < nt) __builtin_amdgcn_s_waitcnt(WC_VM4);
        else             __builtin_amdgcn_s_waitcnt(WC_VM0);
        __builtin_amdgcn_s_barrier();
        __builtin_amdgcn_sched_barrier(0);

        if (kt + 2 < nt) {
            int nb = cur + 2; if (nb >= 3) nb -= 3;
            STAGE(kt + 2, nb);
        }

        short8 af[2][2], bfr[2][2];
        #pragma unroll
        for (int i = 0; i < 2; i++) {
            const int r = wm + i * 16 + l16;
            af[0][i] = *(const short8*)&As[cur][r * 64 + swz0];
            af[1][i] = *(const short8*)&As[cur][r * 64 + swz1];
        }
        #pragma unroll
        for (int j = 0; j < 2; j++) {
            const int r = wn + j * 16 + l16;
            bfr[0][j] = *(const short8*)&Bs[cur][r * 64 + swz0];
            bfr[1][j] = *(const short8*)&Bs[cur][r * 64 + swz1];
        }
        __builtin_amdgcn_s_waitcnt(WC_LGKM0);
        __builtin_amdgcn_sched_barrier(0);

        #pragma unroll
        for (int ks = 0; ks < 2; ks++)
            #pragma unroll
            for (int i = 0; i < 2; i++)
                #pragma unroll
                for (int j = 0; j < 2; j++)
                    acc[i][j] = __builtin_amdgcn_mfma_f32_16x16x32_bf16(
                        af[ks][i], bfr[ks][j], acc[i][j], 0, 0, 0);

        cur++; if (cur == 3) cur = 0;
    }
    #undef STAGE

    float* Cp = Cpart + (size_t)kq * NTOK * 64;
    #pragma unroll
    for (int j = 0; j < 2; j++) {
        int n = wn + j * 16 + l16;
        #pragma unroll
        for (int i = 0; i < 2; i++) {
            int mrow = m0 + wm + i * 16 + quad * 4;
            #pragma unroll
            for (int rr2 = 0; rr2 < 4; rr2++)
                Cp[(size_t)(mrow + rr2) * 64 + n] = acc[i][j][rr2];
        }
    }
}

// ---------------------------------------------------------------------------
// reduce_dblr: dblr = sum of 4 split-K partials (fp32) + bf16 copy for stepB.
// ---------------------------------------------------------------------------
__global__ __launch_bounds__(256) void reduce_dblr(
    const float* __restrict__ part, float* __restrict__ dblr,
    ushort_t* __restrict__ dblr_bf)
{
    const int i = blockIdx.x * 256 + threadIdx.x;
    const size_t st = (size_t)NTOK * 64;
    float s = part[i] + part[i + st] + part[i + 2 * st] + part[i + 3 * st];
    dblr[i] = s;
    dblr_bf[i] = f2bf(s);
}

// ---------------------------------------------------------------------------
// build_w2t: W2t[l][n][k] = (k<32) ? bf16(dt_w[l][k][n]) : 0.
// (Pad MUST be written every launch: d_ws is re-poisoned to 0xAA.)
// ---------------------------------------------------------------------------
__global__ __launch_bounds__(256) void build_w2t_kernel(
    const float* __restrict__ dt_w, ushort_t* __restrict__ w2t)
{
    const int idx = blockIdx.x * 256 + threadIdx.x;
    const int k = idx & 63;
    const int n = (idx >> 6) & 1023;
    const int l = idx >> 16;
    ushort_t v = 0;
    if (k < 32)
        v = f2bf(dt_w[((size_t)l * DT_RANK + k) * D_INNER + n]);
    w2t[((size_t)l * 1024 + n) * 64 + k] = v;
}

// ---------------------------------------------------------------------------
// Batched transpose+cast: z-dim = layer. in[l][K][N] -> out[l][N][K] bf16.
// ---------------------------------------------------------------------------
__global__ __launch_bounds__(256) void transpose_cast_b(
    const float* __restrict__ in0, ushort_t* __restrict__ out0, int K, int N,
    size_t in_ls, size_t out_ls)
{
    const float* in = in0 + (size_t)blockIdx.z * in_ls;
    ushort_t* out = out0 + (size_t)blockIdx.z * out_ls;
    __shared__ float tile[32][33];
    const int n0 = blockIdx.x * 32, k0 = blockIdx.y * 32;
    const int tx = threadIdx.x & 31, ty = threadIdx.x >> 5;
    #pragma unroll
    for (int i = 0; i < 4; i++)
        tile[ty + i * 8][tx] = in[(size_t)(k0 + ty + i * 8) * N + n0 + tx];
    __syncthreads();
    #pragma unroll
    for (int i = 0; i < 4; i++)
        out[(size_t)(n0 + ty + i * 8) * K + k0 + tx] = f2bf(tile[tx][ty + i * 8]);
}

// ---------------------------------------------------------------------------
__global__ __launch_bounds__(256) void cast_bf16_kernel(
    const float* __restrict__ in, ushort_t* __restrict__ out)
{
    const int i = blockIdx.x * 256 + threadIdx.x;
    out[i] = f2bf(in[i]);
}

// ---------------------------------------------------------------------------
__global__ __launch_bounds__(256) void rmsnorm_kernel(
    const float* __restrict__ x, const float* __restrict__ w,
    ushort_t* __restrict__ y)
{
    const int row = blockIdx.x;
    const float* xr = x + (size_t)row * D_MODEL;
    ushort_t* yr = y + (size_t)row * D_MODEL;
    const int tid = threadIdx.x;

    float v0 = xr[tid], v1 = xr[tid + 256];
    float ss = v0 * v0 + v1 * v1;
    #pragma unroll
    for (int off = 32; off > 0; off >>= 1) ss += __shfl_down(ss, off);

    __shared__ float wsum[4];
    __shared__ float scale_s;
    int wid = tid >> 6, lane = tid & 63;
    if (lane == 0) wsum[wid] = ss;
    __syncthreads();
    if (tid == 0) {
        float tot = wsum[0] + wsum[1] + wsum[2] + wsum[3];
        scale_s = 1.0f / sqrtf(tot / (float)D_MODEL + 1e-5f);
    }
    __syncthreads();
    float sc = scale_s;
    yr[tid] = f2bf(v0 * sc * w[tid]);
    yr[tid + 256] = f2bf(v1 * sc * w[tid + 256]);
}

// ---------------------------------------------------------------------------
// Causal dwconv (K=4) + bias + silu. Reads bf16 xz (stride 2048, xp plane),
// writes bf16 u.
// ---------------------------------------------------------------------------
__global__ __launch_bounds__(256) void conv_silu_kernel(
    const ushort_t* __restrict__ xz, const float* __restrict__ w,
    const float* __restrict__ bconv, ushort_t* __restrict__ outb)
{
    const int idx = blockIdx.x * 256 + threadIdx.x;
    const int d = idx & (D_INNER - 1);
    const int t = (idx >> 10) & (SEQ - 1);
    const int row = idx >> 10;
    const ushort_t* base = xz + (size_t)row * 2048 + d;

    float s = 0.f;
    #pragma unroll
    for (int k = 0; k < KCONV; k++) {
        int tt = t + k - (KCONV - 1);
        if (tt >= 0)
            s = fmaf(bf2f(base[(ptrdiff_t)(k - (KCONV - 1)) * 2048]), w[d * KCONV + k], s);
    }
    s += bconv[d];
    float r = s / (1.f + __expf(-s));
    outb[idx] = f2bf(r);
}

// ---------------------------------------------------------------------------
// Chunked selective scan (3 passes), CLEN=32 — r10 version (dt from dtb,
// the r11 inline-dt was LDS-broadcast-bound: 1024 ds_reads/thread, +250%).
// dt in dtb (stride 1024, softplus'ed); B/C in bc (stride 64):
// bc[row][32+n]=B[n], bc[row][48+n]=C[n]. u bf16 in ub; z bf16 in xz[:,1024:].
// ---------------------------------------------------------------------------
__global__ __launch_bounds__(256) void scan_pass1(
    const float* __restrict__ dtb, const float* __restrict__ bc,
    const ushort_t* __restrict__ ub, const float* __restrict__ A_log,
    float* __restrict__ hfin, float* __restrict__ sumdt)
{
    const int tid = threadIdx.x;
    const int b = blockIdx.x >> 7;
    const int p = (blockIdx.x >> 2) & 31;
    const int d = ((blockIdx.x & 3) << 8) + tid;
    const int t0 = p * CLEN;

    float A[D_STATE];
    #pragma unroll
    for (int n = 0; n < D_STATE; n++) A[n] = -expf(A_log[d * D_STATE + n]);

    float h[D_STATE] = {};
    float sdt = 0.f;

    const float* dtp = dtb + ((size_t)b * SEQ + t0) * 1024 + d;
    const float* bp  = bc + ((size_t)b * SEQ + t0) * 64 + 32;
    const ushort_t* up = ub + ((size_t)b * SEQ + t0) * D_INNER + d;

    for (int t = 0; t < CLEN; t++) {
        float dtv = dtp[(size_t)t * 1024];
        float uv  = bf2f(up[(size_t)t * D_INNER]);
        float dtu = dtv * uv;
        sdt += dtv;
        #pragma unroll
        for (int n = 0; n < D_STATE; n++)
            h[n] = fmaf(__expf(dtv * A[n]), h[n], dtu * bp[t * 64 + n]);
    }

    size_t base = (size_t)(b * PCH + p) * D_STATE * D_INNER + d;
    #pragma unroll
    for (int n = 0; n < D_STATE; n++) hfin[base + (size_t)n * D_INNER] = h[n];
    sumdt[(size_t)(b * PCH + p) * D_INNER + d] = sdt;
}

// preload all 32 chunk-final states + sumdt (independent loads), then the
// serial recurrence runs as pure VALU with fire-and-forget writes (r9 win).
__global__ __launch_bounds__(256) void scan_pass2(
    const float* __restrict__ A_log, const float* __restrict__ sumdt,
    float* __restrict__ hc)
{
    const int tid = threadIdx.x;
    const int b = blockIdx.x >> 6;
    const int n = (blockIdx.x >> 2) & 15;
    const int d = ((blockIdx.x & 3) << 8) + tid;

    const float Aval = -expf(A_log[d * D_STATE + n]);

    float fin[PCH], sd[PCH];
    #pragma unroll
    for (int p = 0; p < PCH; p++) {
        fin[p] = hc[((size_t)(b * PCH + p) * D_STATE + n) * D_INNER + d];
        sd[p]  = sumdt[(size_t)(b * PCH + p) * D_INNER + d];
    }
    float h = 0.f;
    #pragma unroll
    for (int p = 0; p < PCH; p++) {
        hc[((size_t)(b * PCH + p) * D_STATE + n) * D_INNER + d] = h;
        h = fmaf(__expf(Aval * sd[p]), h, fin[p]);
    }
}

// pass3: u (bf16, in ub) read then overwritten IN PLACE with y*silu(z).
__global__ __launch_bounds__(256) void scan_pass3(
    const float* __restrict__ dtb, const float* __restrict__ bc,
    const ushort_t* __restrict__ xz, const float* __restrict__ A_log,
    const float* __restrict__ Dp, const float* __restrict__ hstart,
    ushort_t* ub)
{
    const int tid = threadIdx.x;
    const int b = blockIdx.x >> 7;
    const int p = (blockIdx.x >> 2) & 31;
    const int d = ((blockIdx.x & 3) << 8) + tid;
    const int t0 = p * CLEN;

    float A[D_STATE];
    #pragma unroll
    for (int n = 0; n < D_STATE; n++) A[n] = -expf(A_log[d * D_STATE + n]);
    const float Dv = Dp[d];

    float h[D_STATE];
    size_t base = (size_t)(b * PCH + p) * D_STATE * D_INNER + d;
    #pragma unroll
    for (int n = 0; n < D_STATE; n++) h[n] = hstart[base + (size_t)n * D_INNER];

    const float* dtp = dtb + ((size_t)b * SEQ + t0) * 1024 + d;
    const float* bp  = bc + ((size_t)b * SEQ + t0) * 64 + 32;
    const ushort_t* zp = xz + ((size_t)b * SEQ + t0) * 2048 + 1024 + d;
    ushort_t* up = ub + ((size_t)b * SEQ + t0) * D_INNER + d;

    for (int t = 0; t < CLEN; t++) {
        float dtv = dtp[(size_t)t * 1024];
        float uv  = bf2f(up[(size_t)t * D_INNER]);
        float zv  = bf2f(zp[(size_t)t * 2048]);
        float dtu = dtv * uv;
        float y = 0.f;
        #pragma unroll
        for (int n = 0; n < D_STATE; n++) {
            h[n] = fmaf(__expf(dtv * A[n]), h[n], dtu * bp[t * 64 + n]);
            y = fmaf(h[n], bp[t * 64 + 16 + n], y);
        }
        float res = fmaf(uv, Dv, y);
        res *= zv / (1.f + __expf(-zv));
        up[(size_t)t * D_INNER] = f2bf(res);
    }
}

// ---------------------------------------------------------------------------
extern "C" void kernel_launch(void* const* d_in, const int* in_sizes, int n_in,
                              void* d_out, int out_size, void* d_ws, size_t ws_size,
                              hipStream_t stream)
{
    const float* x       = (const float*)d_in[0];
    const float* lin1_w  = (const float*)d_in[1];
    const float* lin1_b  = (const float*)d_in[2];
    const float* norm_w  = (const float*)d_in[3];
    const float* in_w    = (const float*)d_in[4];
    const float* conv_w  = (const float*)d_in[5];
    const float* conv_b  = (const float*)d_in[6];
    const float* xproj_w = (const float*)d_in[7];
    const float* dt_w    = (const float*)d_in[8];
    const float* dt_b    = (const float*)d_in[9];
    const float* A_log   = (const float*)d_in[10];
    const float* Dp      = (const float*)d_in[11];
    const float* out_w   = (const float*)d_in[12];
    const float* lin2_w  = (const float*)d_in[13];
    const float* lin2_b  = (const float*)d_in[14];
    float* outp = (float*)d_out;
    (void)ws_size; (void)in_sizes; (void)n_in; (void)out_size;

    float* ws = (float*)d_ws;
    const size_t F1M = 1u << 20;
    float* h     = ws;                                  // 2M fl
    float* dtb   = h + 2 * F1M;                         // 4M fl (dt)
    float* dblr  = dtb + 4 * F1M;                       // 256K fl
    float* dpart = dblr + (size_t)NTOK * 64;            // 1M fl (4 split-K partials)
    float* sumdt = dpart + (size_t)4 * NTOK * 64;       // 128K fl
    float* hfin  = sumdt + (size_t)BATCH * PCH * D_INNER;  // 2M fl
    ushort_t* xzb     = (ushort_t*)(hfin + 2 * F1M);       // 8M us (xp|z, 2048)
    ushort_t* hn_bf   = xzb + 8 * F1M;                     // 2M us
    ushort_t* xb      = hn_bf + 2 * F1M;                   // 4M us
    ushort_t* dblr_bf = xb + 4 * F1M;                      // 256K us
    ushort_t* lin1_wt = dblr_bf + (size_t)NTOK * 64;       // 512*1024
    ushort_t* in_wt   = lin1_wt + (size_t)512 * 1024;      // 4*2048*512
    ushort_t* out_wt  = in_wt + (size_t)4 * 2048 * 512;    // 4*512*1024
    ushort_t* lin2_wt = out_wt + (size_t)4 * 512 * 1024;   // 1024*512
    ushort_t* xw_t    = lin2_wt + (size_t)1024 * 512;      // 4*64*1024
    ushort_t* w2t     = xw_t + (size_t)4 * 64 * 1024;      // 4*1024*64

    dim3 blk(256);

    // --- weight prep (batched: 6 launches) ---
    transpose_cast_b<<<dim3(512 / 32, 1024 / 32, 1), blk, 0, stream>>>(
        lin1_w, lin1_wt, LATENT, D_MODEL, 0, 0);
    transpose_cast_b<<<dim3(2048 / 32, 512 / 32, N_LAYERS), blk, 0, stream>>>(
        in_w, in_wt, 512, 2048, (size_t)512 * 2048, (size_t)2048 * 512);
    transpose_cast_b<<<dim3(512 / 32, 1024 / 32, N_LAYERS), blk, 0, stream>>>(
        out_w, out_wt, 1024, 512, (size_t)1024 * 512, (size_t)512 * 1024);
    transpose_cast_b<<<dim3(64 / 32, 1024 / 32, N_LAYERS), blk, 0, stream>>>(
        xproj_w, xw_t, 1024, 64, (size_t)1024 * 64, (size_t)64 * 1024);
    transpose_cast_b<<<dim3(1024 / 32, 512 / 32, 1), blk, 0, stream>>>(
        lin2_w, lin2_wt, D_MODEL, LATENT, 0, 0);
    build_w2t_kernel<<<dim3((N_LAYERS * 1024 * 64) / 256), blk, 0, stream>>>(
        dt_w, w2t);

    // x -> bf16
    cast_bf16_kernel<<<dim3((NTOK * LATENT) / 256), blk, 0, stream>>>(x, xb);

    // lin1: h = x_bf @ lin1_wt^T + b  (fp32 out; 8x64=512 blocks)
    gemm_bf16_tile<<<dim3(D_MODEL / 64, NTOK / 64), blk, 0, stream>>>(
        xb, LATENT, lin1_wt, LATENT, h, nullptr, D_MODEL, lin1_b,
        NTOK, D_MODEL, LATENT, 1);

    for (int l = 0; l < N_LAYERS; l++) {
        const float* nw = norm_w + (size_t)l * D_MODEL;
        const float* cw = conv_w + (size_t)l * D_INNER * KCONV;
        const float* cb = conv_b + (size_t)l * D_INNER;
        const float* db = dt_b + (size_t)l * D_INNER;
        const float* al = A_log + (size_t)l * D_INNER * D_STATE;
        const float* dp = Dp + (size_t)l * D_INNER;
        const ushort_t* iwt = in_wt + (size_t)l * 2048 * 512;
        const ushort_t* owt = out_wt + (size_t)l * 512 * 1024;
        const ushort_t* xwt = xw_t + (size_t)l * 64 * 1024;
        const ushort_t* w2  = w2t + (size_t)l * 1024 * 64;

        rmsnorm_kernel<<<dim3(NTOK), blk, 0, stream>>>(h, nw, hn_bf);

        // fused in-proj: xzb = hn @ in_w[l] (bf16 out; 256^2 2-phase)
        gemm_bf16_t256<<<dim3(2048 / 256, NTOK / 256), dim3(512), 0, stream>>>(
            hn_bf, D_MODEL, iwt, D_MODEL, xzb, 2048, NTOK, 2048, D_MODEL);

        // conv + silu: xzb[:, :1024] -> xb (bf16 u)
        conv_silu_kernel<<<dim3((NTOK * D_INNER) / 256), blk, 0, stream>>>(
            xzb, cw, cb, xb);

        // xproj step A (split-K x4): dpart[kq] = u @ xw_t^T  (4x64=256 blocks)
        gemm_stepA<<<dim3(4, NTOK / 64), blk, 0, stream>>>(xb, xwt, dpart);
        reduce_dblr<<<dim3((NTOK * 64) / 256), blk, 0, stream>>>(
            dpart, dblr, dblr_bf);

        // step B: dtb = softplus(dblr_bf @ W2t^T + dt_b)  (N=1024, K=64)
        gemm_bf16_tile<<<dim3(1024 / 64, NTOK / 64), blk, 0, stream>>>(
            dblr_bf, 64, w2, 64, dtb, nullptr, 1024, db,
            NTOK, 1024, 64, 4);

        // chunked scan; pass3 overwrites xb in place with y*silu(z)
        scan_pass1<<<dim3(BATCH * PCH * (D_INNER / 256)), blk, 0, stream>>>(
            dtb, dblr, xb, al, hfin, sumdt);
        scan_pass2<<<dim3(BATCH * D_STATE * (D_INNER / 256)), blk, 0, stream>>>(
            al, sumdt, hfin);
        scan_pass3<<<dim3(BATCH * PCH * (D_INNER / 256)), blk, 0, stream>>>(
            dtb, dblr, xzb, al, dp, hfin, xb);

        // h += y_bf @ out_wt^T  (fp32 accumulate; 8x64=512 blocks).
        // Last layer also emits bf16(h) -> hn_bf for lin2 (flag 16).
        gemm_bf16_tile<<<dim3(D_MODEL / 64, NTOK / 64), blk, 0, stream>>>(
            xb, D_INNER, owt, D_INNER, h, hn_bf, D_MODEL, nullptr,
            NTOK, D_MODEL, D_INNER, (l == N_LAYERS - 1) ? 18 : 2);
    }

    // lin2 with FUSED softmax epilogue (flag 32): writes outp directly.
    gemm_bf16_tile<<<dim3(LATENT / 64, NTOK / 64), blk, 0, stream>>>(
        hn_bf, D_MODEL, lin2_wt, D_MODEL, outp, nullptr, LATENT, lin2_b,
        NTOK, LATENT, D_MODEL, 1 | 32);
}

// Round 14
// 659.439 us; speedup vs baseline: 1.1970x; 1.0600x over previous
//
#include <hip/hip_runtime.h>
#include <math.h>

#define D_MODEL 512
#define N_LAYERS 4
#define LATENT 1024
#define D_INNER 1024
#define D_STATE 16
#define DT_RANK 32
#define KCONV 4
#define BATCH 4
#define SEQ 1024
#define NTOK (BATCH * SEQ) /* 4096 */
#define PCH 32
#define CLEN 32

typedef __attribute__((ext_vector_type(8))) short short8;
typedef __attribute__((ext_vector_type(4))) float floatx4;
typedef unsigned short ushort_t;

// gfx9 s_waitcnt immediates: vmcnt lo[3:0] hi[15:14], expcnt[6:4], lgkm[11:8]
#define WC_VM4   0x0F74  /* vmcnt(4) */
#define WC_VM8   0x0F78  /* vmcnt(8) */
#define WC_VM0   0x0F70  /* vmcnt(0) */
#define WC_LGKM0 0xC07F  /* lgkmcnt(0), vm/exp free */

__device__ __forceinline__ ushort_t f2bf(float f) {
    union { float f; unsigned u; } v; v.f = f;
    unsigned r = v.u + 0x7FFFu + ((v.u >> 16) & 1u);  // RNE
    return (ushort_t)(r >> 16);
}
__device__ __forceinline__ float bf2f(ushort_t u) {
    union { unsigned u; float f; } v; v.u = ((unsigned)u) << 16;
    return v.f;
}
// async global -> LDS, 16B per lane (verified width=16 on gfx950, m97).
__device__ __forceinline__ void gll16(const void* g, void* l) {
    __builtin_amdgcn_global_load_lds(
        (const __attribute__((address_space(1))) void*)g,
        (__attribute__((address_space(3))) void*)l, 16, 0, 0);
}

// ---------------------------------------------------------------------------
// 256x256 2-phase GEMM (inproj): bf16 out = A[M,K] @ Bt[N,K]^T.
// ---------------------------------------------------------------------------
__global__ __launch_bounds__(512, 2) void gemm_bf16_t256(
    const ushort_t* __restrict__ A, int lda,
    const ushort_t* __restrict__ Bt, int ldb,
    ushort_t* __restrict__ Cb, int ldc,
    int M, int N, int K)
{
    __shared__ ushort_t As[2][16384];   // [buf][256 rows x 64 cols]
    __shared__ ushort_t Bs[2][16384];

    const int gx = gridDim.x;
    const int nwg = gx * gridDim.y;
    const int orig = blockIdx.y * gx + blockIdx.x;
    const int qq = nwg >> 3, rr = nwg & 7;
    const int xcd = orig & 7, loc = orig >> 3;
    const int swz = (xcd < rr ? xcd * (qq + 1) : rr * (qq + 1) + (xcd - rr) * qq) + loc;
    const int m0 = (swz / gx) * 256;
    const int n0 = (swz % gx) * 256;

    const int tid = threadIdx.x;          // 0..511
    const int w = tid >> 6;               // 0..7
    const int lane = tid & 63;
    const int quad = lane >> 4;
    const int l16 = lane & 15;
    const int wm = (w & 1) * 128;         // wave grid 2M x 4N
    const int wn = (w >> 1) * 64;

    const int srow = tid >> 3;                     // 0..63
    const int schunk = ((tid & 7) ^ (srow & 7)) * 8;
    const ushort_t* ga = A + (size_t)(m0 + srow) * lda + schunk;
    const ushort_t* gb = Bt + (size_t)(n0 + srow) * ldb + schunk;
    const int lofs = tid * 8;

    const int swz0 = ((0 * 4 + quad) ^ (l16 & 7)) * 8;
    const int swz1 = ((1 * 4 + quad) ^ (l16 & 7)) * 8;

    floatx4 acc[8][4] = {};
    const int nt = K >> 6;

    #define STAGE(t, b)                                                         \
        do {                                                                    \
            const ushort_t* pa_ = ga + (t) * 64;                                \
            const ushort_t* pb_ = gb + (t) * 64;                                \
            _Pragma("unroll")                                                   \
            for (int q = 0; q < 4; q++) {                                       \
                gll16(pa_ + (size_t)(q * 64) * lda, &As[(b)][q * 4096 + lofs]); \
                gll16(pb_ + (size_t)(q * 64) * ldb, &Bs[(b)][q * 4096 + lofs]); \
            }                                                                   \
        } while (0)

    STAGE(0, 0);

    for (int kt = 0; kt < nt; kt++) {
        const int cur = kt & 1;
        if (kt + 1 < nt) {
            STAGE(kt + 1, 1 - cur);
            __builtin_amdgcn_s_waitcnt(WC_VM8);
        } else {
            __builtin_amdgcn_s_waitcnt(WC_VM0);
        }
        __builtin_amdgcn_s_barrier();

        {
            short8 af[8], bfr[4];
            #pragma unroll
            for (int i = 0; i < 8; i++)
                af[i] = *(const short8*)&As[cur][(wm + i * 16 + l16) * 64 + swz0];
            #pragma unroll
            for (int j = 0; j < 4; j++)
                bfr[j] = *(const short8*)&Bs[cur][(wn + j * 16 + l16) * 64 + swz0];
            __builtin_amdgcn_s_waitcnt(WC_LGKM0);
            #pragma unroll
            for (int i = 0; i < 8; i++)
                #pragma unroll
                for (int j = 0; j < 4; j++)
                    acc[i][j] = __builtin_amdgcn_mfma_f32_16x16x32_bf16(
                        af[i], bfr[j], acc[i][j], 0, 0, 0);
        }
        {
            short8 af[8], bfr[4];
            #pragma unroll
            for (int i = 0; i < 8; i++)
                af[i] = *(const short8*)&As[cur][(wm + i * 16 + l16) * 64 + swz1];
            #pragma unroll
            for (int j = 0; j < 4; j++)
                bfr[j] = *(const short8*)&Bs[cur][(wn + j * 16 + l16) * 64 + swz1];
            __builtin_amdgcn_s_waitcnt(WC_LGKM0);
            #pragma unroll
            for (int i = 0; i < 8; i++)
                #pragma unroll
                for (int j = 0; j < 4; j++)
                    acc[i][j] = __builtin_amdgcn_mfma_f32_16x16x32_bf16(
                        af[i], bfr[j], acc[i][j], 0, 0, 0);
        }
        __builtin_amdgcn_s_barrier();
    }
    #undef STAGE

    #pragma unroll
    for (int j = 0; j < 4; j++) {
        int n = n0 + wn + j * 16 + l16;
        #pragma unroll
        for (int i = 0; i < 8; i++) {
            int mrow = m0 + wm + i * 16 + quad * 4;
            #pragma unroll
            for (int rr2 = 0; rr2 < 4; rr2++)
                Cb[(size_t)(mrow + rr2) * ldc + n] = f2bf(acc[i][j][rr2]);
        }
    }
}

// ---------------------------------------------------------------------------
// bf16 MFMA GEMM, 64x64 tile (r3 structure — proven across 8 passing runs).
// flags: 1 = add bias[n], 2 = accumulate into C (fp32),
//        4 = softplus(v + bias[n]) for n<1024,
//        8 = write bf16 to Cb only,
//       16 = also write bf16 to Cb (combine with 2),
//       32 = fused 32-wide softmax epilogue (lin2, r11/r12-verified).
// ---------------------------------------------------------------------------
__global__ __launch_bounds__(256, 3) void gemm_bf16_tile(
    const ushort_t* __restrict__ A, int lda,
    const ushort_t* __restrict__ Bt, int ldb,
    float* __restrict__ C, ushort_t* __restrict__ Cb, int ldc,
    const float* __restrict__ bias,
    int M, int N, int K, int flags)
{
    __shared__ ushort_t As[3][4096];   // 3 x 8 KB
    __shared__ ushort_t Bs[3][4096];   // 3 x 8 KB

    const int gx = gridDim.x;
    const int nwg = gx * gridDim.y;
    const int orig = blockIdx.y * gx + blockIdx.x;
    const int qq = nwg >> 3, rr = nwg & 7;
    const int xcd = orig & 7, loc = orig >> 3;
    const int swz = (xcd < rr ? xcd * (qq + 1) : rr * (qq + 1) + (xcd - rr) * qq) + loc;
    const int m0 = (swz / gx) * 64;
    const int n0 = (swz % gx) * 64;

    const int tid = threadIdx.x;
    const int w = tid >> 6;
    const int lane = tid & 63;
    const int quad = lane >> 4;
    const int l16 = lane & 15;
    const int wm = (w & 1) * 32;
    const int wn = (w >> 1) * 32;

    const int srow = tid >> 3;
    const int schunk = ((tid & 7) ^ (srow & 7)) * 8;
    const ushort_t* ga = A + (size_t)(m0 + srow) * lda + schunk;
    const ushort_t* gb = Bt + (size_t)(n0 + srow) * ldb + schunk;
    const int lofs = tid * 8;

    const int swz0 = ((0 * 4 + quad) ^ (l16 & 7)) * 8;
    const int swz1 = ((1 * 4 + quad) ^ (l16 & 7)) * 8;

    floatx4 acc[2][2] = {};
    const int nt = K >> 6;

    #define STAGE(t, b)                                         \
        do {                                                    \
            const ushort_t* pa_ = ga + (t) * 64;                \
            const ushort_t* pb_ = gb + (t) * 64;                \
            gll16(pa_, &As[(b)][lofs]);                         \
            gll16(pa_ + (size_t)32 * lda, &As[(b)][2048 + lofs]); \
            gll16(pb_, &Bs[(b)][lofs]);                         \
            gll16(pb_ + (size_t)32 * ldb, &Bs[(b)][2048 + lofs]); \
        } while (0)

    STAGE(0, 0);
    if (nt > 1) STAGE(1, 1);

    int cur = 0;
    for (int kt = 0; kt < nt; kt++) {
        if (kt + 1 < nt) __builtin_amdgcn_s_waitcnt(WC_VM4);
        else             __builtin_amdgcn_s_waitcnt(WC_VM0);
        __builtin_amdgcn_s_barrier();
        __builtin_amdgcn_sched_barrier(0);

        if (kt + 2 < nt) {
            int nb = cur + 2; if (nb >= 3) nb -= 3;
            STAGE(kt + 2, nb);
        }

        short8 af[2][2], bfr[2][2];
        #pragma unroll
        for (int i = 0; i < 2; i++) {
            const int r = wm + i * 16 + l16;
            af[0][i] = *(const short8*)&As[cur][r * 64 + swz0];
            af[1][i] = *(const short8*)&As[cur][r * 64 + swz1];
        }
        #pragma unroll
        for (int j = 0; j < 2; j++) {
            const int r = wn + j * 16 + l16;
            bfr[0][j] = *(const short8*)&Bs[cur][r * 64 + swz0];
            bfr[1][j] = *(const short8*)&Bs[cur][r * 64 + swz1];
        }
        __builtin_amdgcn_s_waitcnt(WC_LGKM0);
        __builtin_amdgcn_sched_barrier(0);

        #pragma unroll
        for (int ks = 0; ks < 2; ks++)
            #pragma unroll
            for (int i = 0; i < 2; i++)
                #pragma unroll
                for (int j = 0; j < 2; j++)
                    acc[i][j] = __builtin_amdgcn_mfma_f32_16x16x32_bf16(
                        af[ks][i], bfr[ks][j], acc[i][j], 0, 0, 0);

        cur++; if (cur == 3) cur = 0;
    }
    #undef STAGE

    // C/D layout (m89-verified): col = lane&15, row = quad*4 + reg.
    if (flags & 32) {
        #pragma unroll
        for (int i = 0; i < 2; i++) {
            #pragma unroll
            for (int rr2 = 0; rr2 < 4; rr2++) {
                float v0 = acc[i][0][rr2] + bias[n0 + wn + l16];
                float v1 = acc[i][1][rr2] + bias[n0 + wn + 16 + l16];
                float m = fmaxf(v0, v1);
                #pragma unroll
                for (int off = 1; off < 16; off <<= 1)
                    m = fmaxf(m, __shfl_xor(m, off));
                float e0 = __expf(v0 - m), e1 = __expf(v1 - m);
                float s = e0 + e1;
                #pragma unroll
                for (int off = 1; off < 16; off <<= 1)
                    s += __shfl_xor(s, off);
                float inv = 1.f / s;
                size_t row = (size_t)(m0 + wm + i * 16 + quad * 4 + rr2) * ldc;
                C[row + n0 + wn + l16] = e0 * inv;
                C[row + n0 + wn + 16 + l16] = e1 * inv;
            }
        }
        return;
    }
    #pragma unroll
    for (int j = 0; j < 2; j++) {
        int n = n0 + wn + j * 16 + l16;
        float bv = (flags & 1) ? bias[n] : 0.f;
        bool do_sp = (flags & 4) && (n < 1024);
        float spb = do_sp ? bias[n] : 0.f;
        #pragma unroll
        for (int i = 0; i < 2; i++) {
            int mrow = m0 + wm + i * 16 + quad * 4;
            #pragma unroll
            for (int rr2 = 0; rr2 < 4; rr2++) {
                size_t idx = (size_t)(mrow + rr2) * ldc + n;
                float v = acc[i][j][rr2] + bv;
                if (do_sp) {
                    v += spb;
                    v = (v > 20.f) ? v : log1pf(__expf(v));
                }
                if (flags & 8) {
                    Cb[idx] = f2bf(v);
                } else {
                    if (flags & 2) v += C[idx];
                    C[idx] = v;
                    if (flags & 16) Cb[idx] = f2bf(v);
                }
            }
        }
    }
}

// ---------------------------------------------------------------------------
// stepA split-K GEMM: Cpart[kq] = u[:, kq*256:(kq+1)*256] @ xw_t^T (N=64).
// ---------------------------------------------------------------------------
__global__ __launch_bounds__(256, 3) void gemm_stepA(
    const ushort_t* __restrict__ A,   // [NTOK][1024] bf16 (u)
    const ushort_t* __restrict__ Bt,  // [64][1024] bf16 (xw_t)
    float* __restrict__ Cpart)        // [4][NTOK][64]
{
    __shared__ ushort_t As[3][4096];
    __shared__ ushort_t Bs[3][4096];

    const int kq = blockIdx.x;          // 0..3 (K window)
    const int m0 = blockIdx.y * 64;
    const int k0 = kq * 256;

    const int tid = threadIdx.x;
    const int w = tid >> 6;
    const int lane = tid & 63;
    const int quad = lane >> 4;
    const int l16 = lane & 15;
    const int wm = (w & 1) * 32;
    const int wn = (w >> 1) * 32;

    const int srow = tid >> 3;
    const int schunk = ((tid & 7) ^ (srow & 7)) * 8;
    const ushort_t* ga = A + (size_t)(m0 + srow) * 1024 + k0 + schunk;
    const ushort_t* gb = Bt + (size_t)srow * 1024 + k0 + schunk;
    const int lofs = tid * 8;

    const int swz0 = ((0 * 4 + quad) ^ (l16 & 7)) * 8;
    const int swz1 = ((1 * 4 + quad) ^ (l16 & 7)) * 8;

    floatx4 acc[2][2] = {};
    const int nt = 4;

    #define STAGE(t, b)                                            \
        do {                                                       \
            const ushort_t* pa_ = ga + (t) * 64;                   \
            const ushort_t* pb_ = gb + (t) * 64;                   \
            gll16(pa_, &As[(b)][lofs]);                            \
            gll16(pa_ + (size_t)32 * 1024, &As[(b)][2048 + lofs]); \
            gll16(pb_, &Bs[(b)][lofs]);                            \
            gll16(pb_ + (size_t)32 * 1024, &Bs[(b)][2048 + lofs]); \
        } while (0)

    STAGE(0, 0);
    STAGE(1, 1);

    int cur = 0;
    for (int kt = 0; kt < nt; kt++) {
        if (kt + 1 < nt) __builtin_amdgcn_s_waitcnt(WC_VM4);
        else             __builtin_amdgcn_s_waitcnt(WC_VM0);
        __builtin_amdgcn_s_barrier();
        __builtin_amdgcn_sched_barrier(0);

        if (kt + 2 < nt) {
            int nb = cur + 2; if (nb >= 3) nb -= 3;
            STAGE(kt + 2, nb);
        }

        short8 af[2][2], bfr[2][2];
        #pragma unroll
        for (int i = 0; i < 2; i++) {
            const int r = wm + i * 16 + l16;
            af[0][i] = *(const short8*)&As[cur][r * 64 + swz0];
            af[1][i] = *(const short8*)&As[cur][r * 64 + swz1];
        }
        #pragma unroll
        for (int j = 0; j < 2; j++) {
            const int r = wn + j * 16 + l16;
            bfr[0][j] = *(const short8*)&Bs[cur][r * 64 + swz0];
            bfr[1][j] = *(const short8*)&Bs[cur][r * 64 + swz1];
        }
        __builtin_amdgcn_s_waitcnt(WC_LGKM0);
        __builtin_amdgcn_sched_barrier(0);

        #pragma unroll
        for (int ks = 0; ks < 2; ks++)
            #pragma unroll
            for (int i = 0; i < 2; i++)
                #pragma unroll
                for (int j = 0; j < 2; j++)
                    acc[i][j] = __builtin_amdgcn_mfma_f32_16x16x32_bf16(
                        af[ks][i], bfr[ks][j], acc[i][j], 0, 0, 0);

        cur++; if (cur == 3) cur = 0;
    }
    #undef STAGE

    float* Cp = Cpart + (size_t)kq * NTOK * 64;
    #pragma unroll
    for (int j = 0; j < 2; j++) {
        int n = wn + j * 16 + l16;
        #pragma unroll
        for (int i = 0; i < 2; i++) {
            int mrow = m0 + wm + i * 16 + quad * 4;
            #pragma unroll
            for (int rr2 = 0; rr2 < 4; rr2++)
                Cp[(size_t)(mrow + rr2) * 64 + n] = acc[i][j][rr2];
        }
    }
}

// ---------------------------------------------------------------------------
// reduce_dblr: dblr = sum of 4 split-K partials (fp32) + bf16 copy for stepB.
// ---------------------------------------------------------------------------
__global__ __launch_bounds__(256) void reduce_dblr(
    const float* __restrict__ part, float* __restrict__ dblr,
    ushort_t* __restrict__ dblr_bf)
{
    const int i = blockIdx.x * 256 + threadIdx.x;
    const size_t st = (size_t)NTOK * 64;
    float s = part[i] + part[i + st] + part[i + 2 * st] + part[i + 3 * st];
    dblr[i] = s;
    dblr_bf[i] = f2bf(s);
}

// ---------------------------------------------------------------------------
// build_w2t: W2t[l][n][k] = (k<32) ? bf16(dt_w[l][k][n]) : 0.
// (Pad MUST be written every launch: d_ws is re-poisoned to 0xAA.)
// ---------------------------------------------------------------------------
__global__ __launch_bounds__(256) void build_w2t_kernel(
    const float* __restrict__ dt_w, ushort_t* __restrict__ w2t)
{
    const int idx = blockIdx.x * 256 + threadIdx.x;
    const int k = idx & 63;
    const int n = (idx >> 6) & 1023;
    const int l = idx >> 16;
    ushort_t v = 0;
    if (k < 32)
        v = f2bf(dt_w[((size_t)l * DT_RANK + k) * D_INNER + n]);
    w2t[((size_t)l * 1024 + n) * 64 + k] = v;
}

// ---------------------------------------------------------------------------
// Batched transpose+cast: z-dim = layer. in[l][K][N] -> out[l][N][K] bf16.
// ---------------------------------------------------------------------------
__global__ __launch_bounds__(256) void transpose_cast_b(
    const float* __restrict__ in0, ushort_t* __restrict__ out0, int K, int N,
    size_t in_ls, size_t out_ls)
{
    const float* in = in0 + (size_t)blockIdx.z * in_ls;
    ushort_t* out = out0 + (size_t)blockIdx.z * out_ls;
    __shared__ float tile[32][33];
    const int n0 = blockIdx.x * 32, k0 = blockIdx.y * 32;
    const int tx = threadIdx.x & 31, ty = threadIdx.x >> 5;
    #pragma unroll
    for (int i = 0; i < 4; i++)
        tile[ty + i * 8][tx] = in[(size_t)(k0 + ty + i * 8) * N + n0 + tx];
    __syncthreads();
    #pragma unroll
    for (int i = 0; i < 4; i++)
        out[(size_t)(n0 + ty + i * 8) * K + k0 + tx] = f2bf(tile[tx][ty + i * 8]);
}

// ---------------------------------------------------------------------------
// r13: vectorized fp32 -> bf16 cast (float4 x2 -> short8; G13).
// ---------------------------------------------------------------------------
__global__ __launch_bounds__(256) void cast_bf16_kernel(
    const float* __restrict__ in, ushort_t* __restrict__ out)
{
    const int i = (blockIdx.x * 256 + threadIdx.x) * 8;
    floatx4 a = *(const floatx4*)&in[i];
    floatx4 b = *(const floatx4*)&in[i + 4];
    short8 o;
    o[0] = (short)f2bf(a[0]); o[1] = (short)f2bf(a[1]);
    o[2] = (short)f2bf(a[2]); o[3] = (short)f2bf(a[3]);
    o[4] = (short)f2bf(b[0]); o[5] = (short)f2bf(b[1]);
    o[6] = (short)f2bf(b[2]); o[7] = (short)f2bf(b[3]);
    *(short8*)&out[i] = o;
}

// ---------------------------------------------------------------------------
// r13: rmsnorm with float2 loads/stores (was scalar; G13).
// ---------------------------------------------------------------------------
__global__ __launch_bounds__(256) void rmsnorm_kernel(
    const float* __restrict__ x, const float* __restrict__ w,
    ushort_t* __restrict__ y)
{
    const int row = blockIdx.x;
    const float* xr = x + (size_t)row * D_MODEL;
    ushort_t* yr = y + (size_t)row * D_MODEL;
    const int tid = threadIdx.x;

    float2 v = *(const float2*)&xr[tid * 2];
    float ss = v.x * v.x + v.y * v.y;
    #pragma unroll
    for (int off = 32; off > 0; off >>= 1) ss += __shfl_down(ss, off);

    __shared__ float wsum[4];
    __shared__ float scale_s;
    int wid = tid >> 6, lane = tid & 63;
    if (lane == 0) wsum[wid] = ss;
    __syncthreads();
    if (tid == 0) {
        float tot = wsum[0] + wsum[1] + wsum[2] + wsum[3];
        scale_s = 1.0f / sqrtf(tot / (float)D_MODEL + 1e-5f);
    }
    __syncthreads();
    float sc = scale_s;
    float2 wv = *(const float2*)&w[tid * 2];
    ushort2 o;
    o.x = f2bf(v.x * sc * wv.x);
    o.y = f2bf(v.y * sc * wv.y);
    *(ushort2*)&yr[tid * 2] = o;
}

// ---------------------------------------------------------------------------
// r13: causal dwconv (K=4) + bias + silu, VECTORIZED (short8, 8 d/thread;
// was 4 scalar bf16 loads + 1 scalar store — the measured 2-2.5x G13 tax).
// Reads bf16 xz (stride 2048, xp plane), writes bf16 u. Same arithmetic
// order per element as the scalar version (k ascending fmaf).
// ---------------------------------------------------------------------------
__global__ __launch_bounds__(256) void conv_silu_kernel(
    const ushort_t* __restrict__ xz, const float* __restrict__ w,
    const float* __restrict__ bconv, ushort_t* __restrict__ outb)
{
    const int idx = blockIdx.x * 256 + threadIdx.x;   // NTOK*128 threads
    const int d0 = (idx & 127) * 8;
    const int row = idx >> 7;
    const int t = row & (SEQ - 1);
    const ushort_t* base = xz + (size_t)row * 2048 + d0;

    short8 xv[4];
    #pragma unroll
    for (int k = 0; k < KCONV; k++) {
        if (t + k - (KCONV - 1) >= 0)
            xv[k] = *(const short8*)(base + (ptrdiff_t)(k - (KCONV - 1)) * 2048);
        else
            xv[k] = short8{0, 0, 0, 0, 0, 0, 0, 0};
    }

    short8 o;
    #pragma unroll
    for (int q = 0; q < 8; q++) {
        floatx4 wq = *(const floatx4*)&w[(size_t)(d0 + q) * KCONV];
        float s = 0.f;
        #pragma unroll
        for (int k = 0; k < KCONV; k++)
            s = fmaf(bf2f((ushort_t)xv[k][q]), wq[k], s);
        s += bconv[d0 + q];
        float r = s / (1.f + __expf(-s));
        o[q] = (short)f2bf(r);
    }
    *(short8*)&outb[(size_t)row * D_INNER + d0] = o;
}

// ---------------------------------------------------------------------------
// Chunked selective scan (3 passes), CLEN=32 — r10/r12 structure.
// dt in dtb (stride 1024, softplus'ed); B/C in bc (stride 64):
// bc[row][32+n]=B[n], bc[row][48+n]=C[n]. u bf16 in ub; z bf16 in xz[:,1024:].
// ---------------------------------------------------------------------------
__global__ __launch_bounds__(256) void scan_pass1(
    const float* __restrict__ dtb, const float* __restrict__ bc,
    const ushort_t* __restrict__ ub, const float* __restrict__ A_log,
    float* __restrict__ hfin, float* __restrict__ sumdt)
{
    const int tid = threadIdx.x;
    const int b = blockIdx.x >> 7;
    const int p = (blockIdx.x >> 2) & 31;
    const int d = ((blockIdx.x & 3) << 8) + tid;
    const int t0 = p * CLEN;

    float A[D_STATE];
    #pragma unroll
    for (int n = 0; n < D_STATE; n++) A[n] = -expf(A_log[d * D_STATE + n]);

    float h[D_STATE] = {};
    float sdt = 0.f;

    const float* dtp = dtb + ((size_t)b * SEQ + t0) * 1024 + d;
    const float* bp  = bc + ((size_t)b * SEQ + t0) * 64 + 32;
    const ushort_t* up = ub + ((size_t)b * SEQ + t0) * D_INNER + d;

    for (int t = 0; t < CLEN; t++) {
        float dtv = dtp[(size_t)t * 1024];
        float uv  = bf2f(up[(size_t)t * D_INNER]);
        float dtu = dtv * uv;
        sdt += dtv;
        #pragma unroll
        for (int n = 0; n < D_STATE; n++)
            h[n] = fmaf(__expf(dtv * A[n]), h[n], dtu * bp[t * 64 + n]);
    }

    size_t base = (size_t)(b * PCH + p) * D_STATE * D_INNER + d;
    #pragma unroll
    for (int n = 0; n < D_STATE; n++) hfin[base + (size_t)n * D_INNER] = h[n];
    sumdt[(size_t)(b * PCH + p) * D_INNER + d] = sdt;
}

// preload all 32 chunk-final states + sumdt (independent loads), then the
// serial recurrence runs as pure VALU with fire-and-forget writes (r9 win).
__global__ __launch_bounds__(256) void scan_pass2(
    const float* __restrict__ A_log, const float* __restrict__ sumdt,
    float* __restrict__ hc)
{
    const int tid = threadIdx.x;
    const int b = blockIdx.x >> 6;
    const int n = (blockIdx.x >> 2) & 15;
    const int d = ((blockIdx.x & 3) << 8) + tid;

    const float Aval = -expf(A_log[d * D_STATE + n]);

    float fin[PCH], sd[PCH];
    #pragma unroll
    for (int p = 0; p < PCH; p++) {
        fin[p] = hc[((size_t)(b * PCH + p) * D_STATE + n) * D_INNER + d];
        sd[p]  = sumdt[(size_t)(b * PCH + p) * D_INNER + d];
    }
    float h = 0.f;
    #pragma unroll
    for (int p = 0; p < PCH; p++) {
        hc[((size_t)(b * PCH + p) * D_STATE + n) * D_INNER + d] = h;
        h = fmaf(__expf(Aval * sd[p]), h, fin[p]);
    }
}

// pass3: u (bf16, in ub) read then overwritten IN PLACE with y*silu(z).
__global__ __launch_bounds__(256) void scan_pass3(
    const float* __restrict__ dtb, const float* __restrict__ bc,
    const ushort_t* __restrict__ xz, const float* __restrict__ A_log,
    const float* __restrict__ Dp, const float* __restrict__ hstart,
    ushort_t* ub)
{
    const int tid = threadIdx.x;
    const int b = blockIdx.x >> 7;
    const int p = (blockIdx.x >> 2) & 31;
    const int d = ((blockIdx.x & 3) << 8) + tid;
    const int t0 = p * CLEN;

    float A[D_STATE];
    #pragma unroll
    for (int n = 0; n < D_STATE; n++) A[n] = -expf(A_log[d * D_STATE + n]);
    const float Dv = Dp[d];

    float h[D_STATE];
    size_t base = (size_t)(b * PCH + p) * D_STATE * D_INNER + d;
    #pragma unroll
    for (int n = 0; n < D_STATE; n++) h[n] = hstart[base + (size_t)n * D_INNER];

    const float* dtp = dtb + ((size_t)b * SEQ + t0) * 1024 + d;
    const float* bp  = bc + ((size_t)b * SEQ + t0) * 64 + 32;
    const ushort_t* zp = xz + ((size_t)b * SEQ + t0) * 2048 + 1024 + d;
    ushort_t* up = ub + ((size_t)b * SEQ + t0) * D_INNER + d;

    for (int t = 0; t < CLEN; t++) {
        float dtv = dtp[(size_t)t * 1024];
        float uv  = bf2f(up[(size_t)t * D_INNER]);
        float zv  = bf2f(zp[(size_t)t * 2048]);
        float dtu = dtv * uv;
        float y = 0.f;
        #pragma unroll
        for (int n = 0; n < D_STATE; n++) {
            h[n] = fmaf(__expf(dtv * A[n]), h[n], dtu * bp[t * 64 + n]);
            y = fmaf(h[n], bp[t * 64 + 16 + n], y);
        }
        float res = fmaf(uv, Dv, y);
        res *= zv / (1.f + __expf(-zv));
        up[(size_t)t * D_INNER] = f2bf(res);
    }
}

// ---------------------------------------------------------------------------
extern "C" void kernel_launch(void* const* d_in, const int* in_sizes, int n_in,
                              void* d_out, int out_size, void* d_ws, size_t ws_size,
                              hipStream_t stream)
{
    const float* x       = (const float*)d_in[0];
    const float* lin1_w  = (const float*)d_in[1];
    const float* lin1_b  = (const float*)d_in[2];
    const float* norm_w  = (const float*)d_in[3];
    const float* in_w    = (const float*)d_in[4];
    const float* conv_w  = (const float*)d_in[5];
    const float* conv_b  = (const float*)d_in[6];
    const float* xproj_w = (const float*)d_in[7];
    const float* dt_w    = (const float*)d_in[8];
    const float* dt_b    = (const float*)d_in[9];
    const float* A_log   = (const float*)d_in[10];
    const float* Dp      = (const float*)d_in[11];
    const float* out_w   = (const float*)d_in[12];
    const float* lin2_w  = (const float*)d_in[13];
    const float* lin2_b  = (const float*)d_in[14];
    float* outp = (float*)d_out;
    (void)ws_size; (void)in_sizes; (void)n_in; (void)out_size;

    float* ws = (float*)d_ws;
    const size_t F1M = 1u << 20;
    float* h     = ws;                                  // 2M fl
    float* dtb   = h + 2 * F1M;                         // 4M fl (dt)
    float* dblr  = dtb + 4 * F1M;                       // 256K fl
    float* dpart = dblr + (size_t)NTOK * 64;            // 1M fl (4 split-K partials)
    float* sumdt = dpart + (size_t)4 * NTOK * 64;       // 128K fl
    float* hfin  = sumdt + (size_t)BATCH * PCH * D_INNER;  // 2M fl
    ushort_t* xzb     = (ushort_t*)(hfin + 2 * F1M);       // 8M us (xp|z, 2048)
    ushort_t* hn_bf   = xzb + 8 * F1M;                     // 2M us
    ushort_t* xb      = hn_bf + 2 * F1M;                   // 4M us
    ushort_t* dblr_bf = xb + 4 * F1M;                      // 256K us
    ushort_t* lin1_wt = dblr_bf + (size_t)NTOK * 64;       // 512*1024
    ushort_t* in_wt   = lin1_wt + (size_t)512 * 1024;      // 4*2048*512
    ushort_t* out_wt  = in_wt + (size_t)4 * 2048 * 512;    // 4*512*1024
    ushort_t* lin2_wt = out_wt + (size_t)4 * 512 * 1024;   // 1024*512
    ushort_t* xw_t    = lin2_wt + (size_t)1024 * 512;      // 4*64*1024
    ushort_t* w2t     = xw_t + (size_t)4 * 64 * 1024;      // 4*1024*64

    dim3 blk(256);

    // --- weight prep (batched: 6 launches) ---
    transpose_cast_b<<<dim3(512 / 32, 1024 / 32, 1), blk, 0, stream>>>(
        lin1_w, lin1_wt, LATENT, D_MODEL, 0, 0);
    transpose_cast_b<<<dim3(2048 / 32, 512 / 32, N_LAYERS), blk, 0, stream>>>(
        in_w, in_wt, 512, 2048, (size_t)512 * 2048, (size_t)2048 * 512);
    transpose_cast_b<<<dim3(512 / 32, 1024 / 32, N_LAYERS), blk, 0, stream>>>(
        out_w, out_wt, 1024, 512, (size_t)1024 * 512, (size_t)512 * 1024);
    transpose_cast_b<<<dim3(64 / 32, 1024 / 32, N_LAYERS), blk, 0, stream>>>(
        xproj_w, xw_t, 1024, 64, (size_t)1024 * 64, (size_t)64 * 1024);
    transpose_cast_b<<<dim3(1024 / 32, 512 / 32, 1), blk, 0, stream>>>(
        lin2_w, lin2_wt, D_MODEL, LATENT, 0, 0);
    build_w2t_kernel<<<dim3((N_LAYERS * 1024 * 64) / 256), blk, 0, stream>>>(
        dt_w, w2t);

    // x -> bf16 (vectorized: 8 elems/thread)
    cast_bf16_kernel<<<dim3((NTOK * LATENT) / 2048), blk, 0, stream>>>(x, xb);

    // lin1: h = x_bf @ lin1_wt^T + b  (fp32 out; 8x64=512 blocks)
    gemm_bf16_tile<<<dim3(D_MODEL / 64, NTOK / 64), blk, 0, stream>>>(
        xb, LATENT, lin1_wt, LATENT, h, nullptr, D_MODEL, lin1_b,
        NTOK, D_MODEL, LATENT, 1);

    for (int l = 0; l < N_LAYERS; l++) {
        const float* nw = norm_w + (size_t)l * D_MODEL;
        const float* cw = conv_w + (size_t)l * D_INNER * KCONV;
        const float* cb = conv_b + (size_t)l * D_INNER;
        const float* db = dt_b + (size_t)l * D_INNER;
        const float* al = A_log + (size_t)l * D_INNER * D_STATE;
        const float* dp = Dp + (size_t)l * D_INNER;
        const ushort_t* iwt = in_wt + (size_t)l * 2048 * 512;
        const ushort_t* owt = out_wt + (size_t)l * 512 * 1024;
        const ushort_t* xwt = xw_t + (size_t)l * 64 * 1024;
        const ushort_t* w2  = w2t + (size_t)l * 1024 * 64;

        rmsnorm_kernel<<<dim3(NTOK), blk, 0, stream>>>(h, nw, hn_bf);

        // fused in-proj: xzb = hn @ in_w[l] (bf16 out; 256^2 2-phase)
        gemm_bf16_t256<<<dim3(2048 / 256, NTOK / 256), dim3(512), 0, stream>>>(
            hn_bf, D_MODEL, iwt, D_MODEL, xzb, 2048, NTOK, 2048, D_MODEL);

        // conv + silu: xzb[:, :1024] -> xb (bf16 u); vectorized, 8 d/thread
        conv_silu_kernel<<<dim3((NTOK * D_INNER) / 2048), blk, 0, stream>>>(
            xzb, cw, cb, xb);

        // xproj step A (split-K x4): dpart[kq] = u @ xw_t^T  (4x64=256 blocks)
        gemm_stepA<<<dim3(4, NTOK / 64), blk, 0, stream>>>(xb, xwt, dpart);
        reduce_dblr<<<dim3((NTOK * 64) / 256), blk, 0, stream>>>(
            dpart, dblr, dblr_bf);

        // step B: dtb = softplus(dblr_bf @ W2t^T + dt_b)  (N=1024, K=64)
        gemm_bf16_tile<<<dim3(1024 / 64, NTOK / 64), blk, 0, stream>>>(
            dblr_bf, 64, w2, 64, dtb, nullptr, 1024, db,
            NTOK, 1024, 64, 4);

        // chunked scan; pass3 overwrites xb in place with y*silu(z)
        scan_pass1<<<dim3(BATCH * PCH * (D_INNER / 256)), blk, 0, stream>>>(
            dtb, dblr, xb, al, hfin, sumdt);
        scan_pass2<<<dim3(BATCH * D_STATE * (D_INNER / 256)), blk, 0, stream>>>(
            al, sumdt, hfin);
        scan_pass3<<<dim3(BATCH * PCH * (D_INNER / 256)), blk, 0, stream>>>(
            dtb, dblr, xzb, al, dp, hfin, xb);

        // h += y_bf @ out_wt^T  (fp32 accumulate; 8x64=512 blocks).
        // Last layer also emits bf16(h) -> hn_bf for lin2 (flag 16).
        gemm_bf16_tile<<<dim3(D_MODEL / 64, NTOK / 64), blk, 0, stream>>>(
            xb, D_INNER, owt, D_INNER, h, hn_bf, D_MODEL, nullptr,
            NTOK, D_MODEL, D_INNER, (l == N_LAYERS - 1) ? 18 : 2);
    }

    // lin2 with FUSED softmax epilogue (flag 32): writes outp directly.
    gemm_bf16_tile<<<dim3(LATENT / 64, NTOK / 64), blk, 0, stream>>>(
        hn_bf, D_MODEL, lin2_wt, D_MODEL, outp, nullptr, LATENT, lin2_b,
        NTOK, LATENT, D_MODEL, 1 | 32);
}

// Round 15
// 651.934 us; speedup vs baseline: 1.2108x; 1.0115x over previous
//
#include <hip/hip_runtime.h>
#include <math.h>

#define D_MODEL 512
#define N_LAYERS 4
#define LATENT 1024
#define D_INNER 1024
#define D_STATE 16
#define DT_RANK 32
#define KCONV 4
#define BATCH 4
#define SEQ 1024
#define NTOK (BATCH * SEQ) /* 4096 */
#define PCH 32
#define CLEN 32

typedef __attribute__((ext_vector_type(8))) short short8;
typedef __attribute__((ext_vector_type(4))) float floatx4;
typedef unsigned short ushort_t;

// gfx9 s_waitcnt immediates: vmcnt lo[3:0] hi[15:14], expcnt[6:4], lgkm[11:8]
#define WC_VM4   0x0F74  /* vmcnt(4) */
#define WC_VM8   0x0F78  /* vmcnt(8) */
#define WC_VM0   0x0F70  /* vmcnt(0) */
#define WC_LGKM0 0xC07F  /* lgkmcnt(0), vm/exp free */

__device__ __forceinline__ ushort_t f2bf(float f) {
    union { float f; unsigned u; } v; v.f = f;
    unsigned r = v.u + 0x7FFFu + ((v.u >> 16) & 1u);  // RNE
    return (ushort_t)(r >> 16);
}
__device__ __forceinline__ float bf2f(ushort_t u) {
    union { unsigned u; float f; } v; v.u = ((unsigned)u) << 16;
    return v.f;
}
// async global -> LDS, 16B per lane (verified width=16 on gfx950, m97).
__device__ __forceinline__ void gll16(const void* g, void* l) {
    __builtin_amdgcn_global_load_lds(
        (const __attribute__((address_space(1))) void*)g,
        (__attribute__((address_space(3))) void*)l, 16, 0, 0);
}

// ---------------------------------------------------------------------------
// 256x256 2-phase GEMM (inproj): bf16 out = A[M,K] @ Bt[N,K]^T.
// ---------------------------------------------------------------------------
__global__ __launch_bounds__(512, 2) void gemm_bf16_t256(
    const ushort_t* __restrict__ A, int lda,
    const ushort_t* __restrict__ Bt, int ldb,
    ushort_t* __restrict__ Cb, int ldc,
    int M, int N, int K)
{
    __shared__ ushort_t As[2][16384];   // [buf][256 rows x 64 cols]
    __shared__ ushort_t Bs[2][16384];

    const int gx = gridDim.x;
    const int nwg = gx * gridDim.y;
    const int orig = blockIdx.y * gx + blockIdx.x;
    const int qq = nwg >> 3, rr = nwg & 7;
    const int xcd = orig & 7, loc = orig >> 3;
    const int swz = (xcd < rr ? xcd * (qq + 1) : rr * (qq + 1) + (xcd - rr) * qq) + loc;
    const int m0 = (swz / gx) * 256;
    const int n0 = (swz % gx) * 256;

    const int tid = threadIdx.x;          // 0..511
    const int w = tid >> 6;               // 0..7
    const int lane = tid & 63;
    const int quad = lane >> 4;
    const int l16 = lane & 15;
    const int wm = (w & 1) * 128;         // wave grid 2M x 4N
    const int wn = (w >> 1) * 64;

    const int srow = tid >> 3;                     // 0..63
    const int schunk = ((tid & 7) ^ (srow & 7)) * 8;
    const ushort_t* ga = A + (size_t)(m0 + srow) * lda + schunk;
    const ushort_t* gb = Bt + (size_t)(n0 + srow) * ldb + schunk;
    const int lofs = tid * 8;

    const int swz0 = ((0 * 4 + quad) ^ (l16 & 7)) * 8;
    const int swz1 = ((1 * 4 + quad) ^ (l16 & 7)) * 8;

    floatx4 acc[8][4] = {};
    const int nt = K >> 6;

    #define STAGE(t, b)                                                         \
        do {                                                                    \
            const ushort_t* pa_ = ga + (t) * 64;                                \
            const ushort_t* pb_ = gb + (t) * 64;                                \
            _Pragma("unroll")                                                   \
            for (int q = 0; q < 4; q++) {                                       \
                gll16(pa_ + (size_t)(q * 64) * lda, &As[(b)][q * 4096 + lofs]); \
                gll16(pb_ + (size_t)(q * 64) * ldb, &Bs[(b)][q * 4096 + lofs]); \
            }                                                                   \
        } while (0)

    STAGE(0, 0);

    for (int kt = 0; kt < nt; kt++) {
        const int cur = kt & 1;
        if (kt + 1 < nt) {
            STAGE(kt + 1, 1 - cur);
            __builtin_amdgcn_s_waitcnt(WC_VM8);
        } else {
            __builtin_amdgcn_s_waitcnt(WC_VM0);
        }
        __builtin_amdgcn_s_barrier();

        {
            short8 af[8], bfr[4];
            #pragma unroll
            for (int i = 0; i < 8; i++)
                af[i] = *(const short8*)&As[cur][(wm + i * 16 + l16) * 64 + swz0];
            #pragma unroll
            for (int j = 0; j < 4; j++)
                bfr[j] = *(const short8*)&Bs[cur][(wn + j * 16 + l16) * 64 + swz0];
            __builtin_amdgcn_s_waitcnt(WC_LGKM0);
            #pragma unroll
            for (int i = 0; i < 8; i++)
                #pragma unroll
                for (int j = 0; j < 4; j++)
                    acc[i][j] = __builtin_amdgcn_mfma_f32_16x16x32_bf16(
                        af[i], bfr[j], acc[i][j], 0, 0, 0);
        }
        {
            short8 af[8], bfr[4];
            #pragma unroll
            for (int i = 0; i < 8; i++)
                af[i] = *(const short8*)&As[cur][(wm + i * 16 + l16) * 64 + swz1];
            #pragma unroll
            for (int j = 0; j < 4; j++)
                bfr[j] = *(const short8*)&Bs[cur][(wn + j * 16 + l16) * 64 + swz1];
            __builtin_amdgcn_s_waitcnt(WC_LGKM0);
            #pragma unroll
            for (int i = 0; i < 8; i++)
                #pragma unroll
                for (int j = 0; j < 4; j++)
                    acc[i][j] = __builtin_amdgcn_mfma_f32_16x16x32_bf16(
                        af[i], bfr[j], acc[i][j], 0, 0, 0);
        }
        __builtin_amdgcn_s_barrier();
    }
    #undef STAGE

    #pragma unroll
    for (int j = 0; j < 4; j++) {
        int n = n0 + wn + j * 16 + l16;
        #pragma unroll
        for (int i = 0; i < 8; i++) {
            int mrow = m0 + wm + i * 16 + quad * 4;
            #pragma unroll
            for (int rr2 = 0; rr2 < 4; rr2++)
                Cb[(size_t)(mrow + rr2) * ldc + n] = f2bf(acc[i][j][rr2]);
        }
    }
}

// ---------------------------------------------------------------------------
// bf16 MFMA GEMM, 64x64 tile (r3 structure — proven across 9 passing runs).
// flags: 1 = add bias[n], 2 = accumulate into C (fp32),
//        4 = softplus(v + bias[n]) for n<1024,
//        8 = write bf16 to Cb only,
//       16 = also write bf16 to Cb (combine with 2),
//       32 = fused 32-wide softmax epilogue (lin2, r11/r12-verified).
// ---------------------------------------------------------------------------
__global__ __launch_bounds__(256, 3) void gemm_bf16_tile(
    const ushort_t* __restrict__ A, int lda,
    const ushort_t* __restrict__ Bt, int ldb,
    float* __restrict__ C, ushort_t* __restrict__ Cb, int ldc,
    const float* __restrict__ bias,
    int M, int N, int K, int flags)
{
    __shared__ ushort_t As[3][4096];   // 3 x 8 KB
    __shared__ ushort_t Bs[3][4096];   // 3 x 8 KB

    const int gx = gridDim.x;
    const int nwg = gx * gridDim.y;
    const int orig = blockIdx.y * gx + blockIdx.x;
    const int qq = nwg >> 3, rr = nwg & 7;
    const int xcd = orig & 7, loc = orig >> 3;
    const int swz = (xcd < rr ? xcd * (qq + 1) : rr * (qq + 1) + (xcd - rr) * qq) + loc;
    const int m0 = (swz / gx) * 64;
    const int n0 = (swz % gx) * 64;

    const int tid = threadIdx.x;
    const int w = tid >> 6;
    const int lane = tid & 63;
    const int quad = lane >> 4;
    const int l16 = lane & 15;
    const int wm = (w & 1) * 32;
    const int wn = (w >> 1) * 32;

    const int srow = tid >> 3;
    const int schunk = ((tid & 7) ^ (srow & 7)) * 8;
    const ushort_t* ga = A + (size_t)(m0 + srow) * lda + schunk;
    const ushort_t* gb = Bt + (size_t)(n0 + srow) * ldb + schunk;
    const int lofs = tid * 8;

    const int swz0 = ((0 * 4 + quad) ^ (l16 & 7)) * 8;
    const int swz1 = ((1 * 4 + quad) ^ (l16 & 7)) * 8;

    floatx4 acc[2][2] = {};
    const int nt = K >> 6;

    #define STAGE(t, b)                                         \
        do {                                                    \
            const ushort_t* pa_ = ga + (t) * 64;                \
            const ushort_t* pb_ = gb + (t) * 64;                \
            gll16(pa_, &As[(b)][lofs]);                         \
            gll16(pa_ + (size_t)32 * lda, &As[(b)][2048 + lofs]); \
            gll16(pb_, &Bs[(b)][lofs]);                         \
            gll16(pb_ + (size_t)32 * ldb, &Bs[(b)][2048 + lofs]); \
        } while (0)

    STAGE(0, 0);
    if (nt > 1) STAGE(1, 1);

    int cur = 0;
    for (int kt = 0; kt < nt; kt++) {
        if (kt + 1 < nt) __builtin_amdgcn_s_waitcnt(WC_VM4);
        else             __builtin_amdgcn_s_waitcnt(WC_VM0);
        __builtin_amdgcn_s_barrier();
        __builtin_amdgcn_sched_barrier(0);

        if (kt + 2 < nt) {
            int nb = cur + 2; if (nb >= 3) nb -= 3;
            STAGE(kt + 2, nb);
        }

        short8 af[2][2], bfr[2][2];
        #pragma unroll
        for (int i = 0; i < 2; i++) {
            const int r = wm + i * 16 + l16;
            af[0][i] = *(const short8*)&As[cur][r * 64 + swz0];
            af[1][i] = *(const short8*)&As[cur][r * 64 + swz1];
        }
        #pragma unroll
        for (int j = 0; j < 2; j++) {
            const int r = wn + j * 16 + l16;
            bfr[0][j] = *(const short8*)&Bs[cur][r * 64 + swz0];
            bfr[1][j] = *(const short8*)&Bs[cur][r * 64 + swz1];
        }
        __builtin_amdgcn_s_waitcnt(WC_LGKM0);
        __builtin_amdgcn_sched_barrier(0);

        #pragma unroll
        for (int ks = 0; ks < 2; ks++)
            #pragma unroll
            for (int i = 0; i < 2; i++)
                #pragma unroll
                for (int j = 0; j < 2; j++)
                    acc[i][j] = __builtin_amdgcn_mfma_f32_16x16x32_bf16(
                        af[ks][i], bfr[ks][j], acc[i][j], 0, 0, 0);

        cur++; if (cur == 3) cur = 0;
    }
    #undef STAGE

    // C/D layout (m89-verified): col = lane&15, row = quad*4 + reg.
    if (flags & 32) {
        #pragma unroll
        for (int i = 0; i < 2; i++) {
            #pragma unroll
            for (int rr2 = 0; rr2 < 4; rr2++) {
                float v0 = acc[i][0][rr2] + bias[n0 + wn + l16];
                float v1 = acc[i][1][rr2] + bias[n0 + wn + 16 + l16];
                float m = fmaxf(v0, v1);
                #pragma unroll
                for (int off = 1; off < 16; off <<= 1)
                    m = fmaxf(m, __shfl_xor(m, off));
                float e0 = __expf(v0 - m), e1 = __expf(v1 - m);
                float s = e0 + e1;
                #pragma unroll
                for (int off = 1; off < 16; off <<= 1)
                    s += __shfl_xor(s, off);
                float inv = 1.f / s;
                size_t row = (size_t)(m0 + wm + i * 16 + quad * 4 + rr2) * ldc;
                C[row + n0 + wn + l16] = e0 * inv;
                C[row + n0 + wn + 16 + l16] = e1 * inv;
            }
        }
        return;
    }
    #pragma unroll
    for (int j = 0; j < 2; j++) {
        int n = n0 + wn + j * 16 + l16;
        float bv = (flags & 1) ? bias[n] : 0.f;
        bool do_sp = (flags & 4) && (n < 1024);
        float spb = do_sp ? bias[n] : 0.f;
        #pragma unroll
        for (int i = 0; i < 2; i++) {
            int mrow = m0 + wm + i * 16 + quad * 4;
            #pragma unroll
            for (int rr2 = 0; rr2 < 4; rr2++) {
                size_t idx = (size_t)(mrow + rr2) * ldc + n;
                float v = acc[i][j][rr2] + bv;
                if (do_sp) {
                    v += spb;
                    v = (v > 20.f) ? v : log1pf(__expf(v));
                }
                if (flags & 8) {
                    Cb[idx] = f2bf(v);
                } else {
                    if (flags & 2) v += C[idx];
                    C[idx] = v;
                    if (flags & 16) Cb[idx] = f2bf(v);
                }
            }
        }
    }
}

// ---------------------------------------------------------------------------
// stepA split-K GEMM: Cpart[kq] = u[:, kq*256:(kq+1)*256] @ xw_t^T (N=64).
// ---------------------------------------------------------------------------
__global__ __launch_bounds__(256, 3) void gemm_stepA(
    const ushort_t* __restrict__ A,   // [NTOK][1024] bf16 (u)
    const ushort_t* __restrict__ Bt,  // [64][1024] bf16 (xw_t)
    float* __restrict__ Cpart)        // [4][NTOK][64]
{
    __shared__ ushort_t As[3][4096];
    __shared__ ushort_t Bs[3][4096];

    const int kq = blockIdx.x;          // 0..3 (K window)
    const int m0 = blockIdx.y * 64;
    const int k0 = kq * 256;

    const int tid = threadIdx.x;
    const int w = tid >> 6;
    const int lane = tid & 63;
    const int quad = lane >> 4;
    const int l16 = lane & 15;
    const int wm = (w & 1) * 32;
    const int wn = (w >> 1) * 32;

    const int srow = tid >> 3;
    const int schunk = ((tid & 7) ^ (srow & 7)) * 8;
    const ushort_t* ga = A + (size_t)(m0 + srow) * 1024 + k0 + schunk;
    const ushort_t* gb = Bt + (size_t)srow * 1024 + k0 + schunk;
    const int lofs = tid * 8;

    const int swz0 = ((0 * 4 + quad) ^ (l16 & 7)) * 8;
    const int swz1 = ((1 * 4 + quad) ^ (l16 & 7)) * 8;

    floatx4 acc[2][2] = {};
    const int nt = 4;

    #define STAGE(t, b)                                            \
        do {                                                       \
            const ushort_t* pa_ = ga + (t) * 64;                   \
            const ushort_t* pb_ = gb + (t) * 64;                   \
            gll16(pa_, &As[(b)][lofs]);                            \
            gll16(pa_ + (size_t)32 * 1024, &As[(b)][2048 + lofs]); \
            gll16(pb_, &Bs[(b)][lofs]);                            \
            gll16(pb_ + (size_t)32 * 1024, &Bs[(b)][2048 + lofs]); \
        } while (0)

    STAGE(0, 0);
    STAGE(1, 1);

    int cur = 0;
    for (int kt = 0; kt < nt; kt++) {
        if (kt + 1 < nt) __builtin_amdgcn_s_waitcnt(WC_VM4);
        else             __builtin_amdgcn_s_waitcnt(WC_VM0);
        __builtin_amdgcn_s_barrier();
        __builtin_amdgcn_sched_barrier(0);

        if (kt + 2 < nt) {
            int nb = cur + 2; if (nb >= 3) nb -= 3;
            STAGE(kt + 2, nb);
        }

        short8 af[2][2], bfr[2][2];
        #pragma unroll
        for (int i = 0; i < 2; i++) {
            const int r = wm + i * 16 + l16;
            af[0][i] = *(const short8*)&As[cur][r * 64 + swz0];
            af[1][i] = *(const short8*)&As[cur][r * 64 + swz1];
        }
        #pragma unroll
        for (int j = 0; j < 2; j++) {
            const int r = wn + j * 16 + l16;
            bfr[0][j] = *(const short8*)&Bs[cur][r * 64 + swz0];
            bfr[1][j] = *(const short8*)&Bs[cur][r * 64 + swz1];
        }
        __builtin_amdgcn_s_waitcnt(WC_LGKM0);
        __builtin_amdgcn_sched_barrier(0);

        #pragma unroll
        for (int ks = 0; ks < 2; ks++)
            #pragma unroll
            for (int i = 0; i < 2; i++)
                #pragma unroll
                for (int j = 0; j < 2; j++)
                    acc[i][j] = __builtin_amdgcn_mfma_f32_16x16x32_bf16(
                        af[ks][i], bfr[ks][j], acc[i][j], 0, 0, 0);

        cur++; if (cur == 3) cur = 0;
    }
    #undef STAGE

    float* Cp = Cpart + (size_t)kq * NTOK * 64;
    #pragma unroll
    for (int j = 0; j < 2; j++) {
        int n = wn + j * 16 + l16;
        #pragma unroll
        for (int i = 0; i < 2; i++) {
            int mrow = m0 + wm + i * 16 + quad * 4;
            #pragma unroll
            for (int rr2 = 0; rr2 < 4; rr2++)
                Cp[(size_t)(mrow + rr2) * 64 + n] = acc[i][j][rr2];
        }
    }
}

// ---------------------------------------------------------------------------
// r15: stepB with INLINE split-K reduction (reduce_dblr kernel deleted).
// dtb = softplus(sum_kq(part[kq]) @ W2t^T + dt_b); single K=64 tile.
// A is REG-STAGED: thread loads its 8 cols x 2 rows from all 4 partials
// (kq-ascending sum — bit-identical to the old reduce_dblr), converts to
// bf16 into the SAME XOR-8 LDS layout the proven ds_read expects
// (LDS[srow][(tid&7)*8] = global[srow][schunk], identical to gll16 path).
// Blocks with swz%gx==0 (exactly one per m-panel) also write fp32 dblr
// for the scan. B staged via gll16 unchanged. __syncthreads ordering
// (single tile, no pipelining — compiler drains vmcnt/lgkm at barrier).
// ---------------------------------------------------------------------------
__global__ __launch_bounds__(256, 3) void gemm_stepB(
    const float* __restrict__ part,   // [4][NTOK][64] split-K partials
    const ushort_t* __restrict__ Bt,  // [1024][64] bf16 (w2t)
    float* __restrict__ dblr,         // [NTOK][64] fp32 (side output)
    float* __restrict__ dtb,          // [NTOK][1024] fp32
    const float* __restrict__ bias)   // dt_b
{
    __shared__ ushort_t As[4096];   // 64 x 64 bf16
    __shared__ ushort_t Bs[4096];

    const int gx = gridDim.x;            // 16
    const int nwg = gx * gridDim.y;      // 1024 (%8==0)
    const int orig = blockIdx.y * gx + blockIdx.x;
    const int qq = nwg >> 3, rr = nwg & 7;
    const int xcd = orig & 7, loc = orig >> 3;
    const int swz = (xcd < rr ? xcd * (qq + 1) : rr * (qq + 1) + (xcd - rr) * qq) + loc;
    const int m0 = (swz / gx) * 64;
    const int n0 = (swz % gx) * 64;
    const bool wdblr = ((swz % gx) == 0);

    const int tid = threadIdx.x;
    const int w = tid >> 6;
    const int lane = tid & 63;
    const int quad = lane >> 4;
    const int l16 = lane & 15;
    const int wm = (w & 1) * 32;
    const int wn = (w >> 1) * 32;

    const int srow = tid >> 3;                    // 0..31
    const int schunk = ((tid & 7) ^ (srow & 7)) * 8;
    const int lofs = tid * 8;

    // B: gll16 staging (w2t rows n0+srow, n0+srow+32), as in the old stepB.
    const ushort_t* gb = Bt + (size_t)(n0 + srow) * 64 + schunk;
    gll16(gb, &Bs[lofs]);
    gll16(gb + (size_t)32 * 64, &Bs[2048 + lofs]);

    // A: inline 4-way reduction, rows m0+srow and m0+srow+32.
    const size_t st = (size_t)NTOK * 64;
    const float* pa0 = part + (size_t)(m0 + srow) * 64 + schunk;
    const float* pa1 = pa0 + (size_t)32 * 64;
    floatx4 a0l = *(const floatx4*)(pa0);
    floatx4 a0h = *(const floatx4*)(pa0 + 4);
    floatx4 a1l = *(const floatx4*)(pa1);
    floatx4 a1h = *(const floatx4*)(pa1 + 4);
    #pragma unroll
    for (int kq = 1; kq < 4; kq++) {
        a0l += *(const floatx4*)(pa0 + (size_t)kq * st);
        a0h += *(const floatx4*)(pa0 + (size_t)kq * st + 4);
        a1l += *(const floatx4*)(pa1 + (size_t)kq * st);
        a1h += *(const floatx4*)(pa1 + (size_t)kq * st + 4);
    }
    short8 u0, u1;
    #pragma unroll
    for (int q = 0; q < 4; q++) {
        u0[q] = (short)f2bf(a0l[q]); u0[4 + q] = (short)f2bf(a0h[q]);
        u1[q] = (short)f2bf(a1l[q]); u1[4 + q] = (short)f2bf(a1h[q]);
    }
    *(short8*)&As[lofs] = u0;
    *(short8*)&As[2048 + lofs] = u1;
    if (wdblr) {
        float* d0 = dblr + (size_t)(m0 + srow) * 64 + schunk;
        *(floatx4*)(d0) = a0l;       *(floatx4*)(d0 + 4) = a0h;
        *(floatx4*)(d0 + 32 * 64) = a1l; *(floatx4*)(d0 + 32 * 64 + 4) = a1h;
    }
    __syncthreads();

    const int swz0 = ((0 * 4 + quad) ^ (l16 & 7)) * 8;
    const int swz1 = ((1 * 4 + quad) ^ (l16 & 7)) * 8;

    floatx4 acc[2][2] = {};
    short8 af[2][2], bfr[2][2];
    #pragma unroll
    for (int i = 0; i < 2; i++) {
        const int r = wm + i * 16 + l16;
        af[0][i] = *(const short8*)&As[r * 64 + swz0];
        af[1][i] = *(const short8*)&As[r * 64 + swz1];
    }
    #pragma unroll
    for (int j = 0; j < 2; j++) {
        const int r = wn + j * 16 + l16;
        bfr[0][j] = *(const short8*)&Bs[r * 64 + swz0];
        bfr[1][j] = *(const short8*)&Bs[r * 64 + swz1];
    }
    #pragma unroll
    for (int ks = 0; ks < 2; ks++)
        #pragma unroll
        for (int i = 0; i < 2; i++)
            #pragma unroll
            for (int j = 0; j < 2; j++)
                acc[i][j] = __builtin_amdgcn_mfma_f32_16x16x32_bf16(
                    af[ks][i], bfr[ks][j], acc[i][j], 0, 0, 0);

    // epilogue: softplus(v + dt_b[n]) -> dtb (matches old flags=4 path)
    #pragma unroll
    for (int j = 0; j < 2; j++) {
        int n = n0 + wn + j * 16 + l16;
        float spb = bias[n];
        #pragma unroll
        for (int i = 0; i < 2; i++) {
            int mrow = m0 + wm + i * 16 + quad * 4;
            #pragma unroll
            for (int rr2 = 0; rr2 < 4; rr2++) {
                float v = acc[i][j][rr2] + spb;
                v = (v > 20.f) ? v : log1pf(__expf(v));
                dtb[(size_t)(mrow + rr2) * 1024 + n] = v;
            }
        }
    }
}

// ---------------------------------------------------------------------------
// build_w2t: W2t[l][n][k] = (k<32) ? bf16(dt_w[l][k][n]) : 0.
// (Pad MUST be written every launch: d_ws is re-poisoned to 0xAA.)
// ---------------------------------------------------------------------------
__global__ __launch_bounds__(256) void build_w2t_kernel(
    const float* __restrict__ dt_w, ushort_t* __restrict__ w2t)
{
    const int idx = blockIdx.x * 256 + threadIdx.x;
    const int k = idx & 63;
    const int n = (idx >> 6) & 1023;
    const int l = idx >> 16;
    ushort_t v = 0;
    if (k < 32)
        v = f2bf(dt_w[((size_t)l * DT_RANK + k) * D_INNER + n]);
    w2t[((size_t)l * 1024 + n) * 64 + k] = v;
}

// ---------------------------------------------------------------------------
// Batched transpose+cast: z-dim = layer. in[l][K][N] -> out[l][N][K] bf16.
// ---------------------------------------------------------------------------
__global__ __launch_bounds__(256) void transpose_cast_b(
    const float* __restrict__ in0, ushort_t* __restrict__ out0, int K, int N,
    size_t in_ls, size_t out_ls)
{
    const float* in = in0 + (size_t)blockIdx.z * in_ls;
    ushort_t* out = out0 + (size_t)blockIdx.z * out_ls;
    __shared__ float tile[32][33];
    const int n0 = blockIdx.x * 32, k0 = blockIdx.y * 32;
    const int tx = threadIdx.x & 31, ty = threadIdx.x >> 5;
    #pragma unroll
    for (int i = 0; i < 4; i++)
        tile[ty + i * 8][tx] = in[(size_t)(k0 + ty + i * 8) * N + n0 + tx];
    __syncthreads();
    #pragma unroll
    for (int i = 0; i < 4; i++)
        out[(size_t)(n0 + ty + i * 8) * K + k0 + tx] = f2bf(tile[tx][ty + i * 8]);
}

// ---------------------------------------------------------------------------
// vectorized fp32 -> bf16 cast (float4 x2 -> short8; G13, r13-verified).
// ---------------------------------------------------------------------------
__global__ __launch_bounds__(256) void cast_bf16_kernel(
    const float* __restrict__ in, ushort_t* __restrict__ out)
{
    const int i = (blockIdx.x * 256 + threadIdx.x) * 8;
    floatx4 a = *(const floatx4*)&in[i];
    floatx4 b = *(const floatx4*)&in[i + 4];
    short8 o;
    o[0] = (short)f2bf(a[0]); o[1] = (short)f2bf(a[1]);
    o[2] = (short)f2bf(a[2]); o[3] = (short)f2bf(a[3]);
    o[4] = (short)f2bf(b[0]); o[5] = (short)f2bf(b[1]);
    o[6] = (short)f2bf(b[2]); o[7] = (short)f2bf(b[3]);
    *(short8*)&out[i] = o;
}

// ---------------------------------------------------------------------------
// rmsnorm with float2 loads/stores (G13, r13-verified).
// ---------------------------------------------------------------------------
__global__ __launch_bounds__(256) void rmsnorm_kernel(
    const float* __restrict__ x, const float* __restrict__ w,
    ushort_t* __restrict__ y)
{
    const int row = blockIdx.x;
    const float* xr = x + (size_t)row * D_MODEL;
    ushort_t* yr = y + (size_t)row * D_MODEL;
    const int tid = threadIdx.x;

    float2 v = *(const float2*)&xr[tid * 2];
    float ss = v.x * v.x + v.y * v.y;
    #pragma unroll
    for (int off = 32; off > 0; off >>= 1) ss += __shfl_down(ss, off);

    __shared__ float wsum[4];
    __shared__ float scale_s;
    int wid = tid >> 6, lane = tid & 63;
    if (lane == 0) wsum[wid] = ss;
    __syncthreads();
    if (tid == 0) {
        float tot = wsum[0] + wsum[1] + wsum[2] + wsum[3];
        scale_s = 1.0f / sqrtf(tot / (float)D_MODEL + 1e-5f);
    }
    __syncthreads();
    float sc = scale_s;
    float2 wv = *(const float2*)&w[tid * 2];
    ushort2 o;
    o.x = f2bf(v.x * sc * wv.x);
    o.y = f2bf(v.y * sc * wv.y);
    *(ushort2*)&yr[tid * 2] = o;
}

// ---------------------------------------------------------------------------
// causal dwconv (K=4) + bias + silu, VECTORIZED (short8, 8 d/thread;
// G13, r13-verified). Reads bf16 xz (stride 2048), writes bf16 u.
// ---------------------------------------------------------------------------
__global__ __launch_bounds__(256) void conv_silu_kernel(
    const ushort_t* __restrict__ xz, const float* __restrict__ w,
    const float* __restrict__ bconv, ushort_t* __restrict__ outb)
{
    const int idx = blockIdx.x * 256 + threadIdx.x;   // NTOK*128 threads
    const int d0 = (idx & 127) * 8;
    const int row = idx >> 7;
    const int t = row & (SEQ - 1);
    const ushort_t* base = xz + (size_t)row * 2048 + d0;

    short8 xv[4];
    #pragma unroll
    for (int k = 0; k < KCONV; k++) {
        if (t + k - (KCONV - 1) >= 0)
            xv[k] = *(const short8*)(base + (ptrdiff_t)(k - (KCONV - 1)) * 2048);
        else
            xv[k] = short8{0, 0, 0, 0, 0, 0, 0, 0};
    }

    short8 o;
    #pragma unroll
    for (int q = 0; q < 8; q++) {
        floatx4 wq = *(const floatx4*)&w[(size_t)(d0 + q) * KCONV];
        float s = 0.f;
        #pragma unroll
        for (int k = 0; k < KCONV; k++)
            s = fmaf(bf2f((ushort_t)xv[k][q]), wq[k], s);
        s += bconv[d0 + q];
        float r = s / (1.f + __expf(-s));
        o[q] = (short)f2bf(r);
    }
    *(short8*)&outb[(size_t)row * D_INNER + d0] = o;
}

// ---------------------------------------------------------------------------
// Chunked selective scan (3 passes), CLEN=32 — r10/r12 structure.
// dt in dtb (stride 1024, softplus'ed); B/C in bc (stride 64):
// bc[row][32+n]=B[n], bc[row][48+n]=C[n]. u bf16 in ub; z bf16 in xz[:,1024:].
// ---------------------------------------------------------------------------
__global__ __launch_bounds__(256) void scan_pass1(
    const float* __restrict__ dtb, const float* __restrict__ bc,
    const ushort_t* __restrict__ ub, const float* __restrict__ A_log,
    float* __restrict__ hfin, float* __restrict__ sumdt)
{
    const int tid = threadIdx.x;
    const int b = blockIdx.x >> 7;
    const int p = (blockIdx.x >> 2) & 31;
    const int d = ((blockIdx.x & 3) << 8) + tid;
    const int t0 = p * CLEN;

    float A[D_STATE];
    #pragma unroll
    for (int n = 0; n < D_STATE; n++) A[n] = -expf(A_log[d * D_STATE + n]);

    float h[D_STATE] = {};
    float sdt = 0.f;

    const float* dtp = dtb + ((size_t)b * SEQ + t0) * 1024 + d;
    const float* bp  = bc + ((size_t)b * SEQ + t0) * 64 + 32;
    const ushort_t* up = ub + ((size_t)b * SEQ + t0) * D_INNER + d;

    for (int t = 0; t < CLEN; t++) {
        float dtv = dtp[(size_t)t * 1024];
        float uv  = bf2f(up[(size_t)t * D_INNER]);
        float dtu = dtv * uv;
        sdt += dtv;
        #pragma unroll
        for (int n = 0; n < D_STATE; n++)
            h[n] = fmaf(__expf(dtv * A[n]), h[n], dtu * bp[t * 64 + n]);
    }

    size_t base = (size_t)(b * PCH + p) * D_STATE * D_INNER + d;
    #pragma unroll
    for (int n = 0; n < D_STATE; n++) hfin[base + (size_t)n * D_INNER] = h[n];
    sumdt[(size_t)(b * PCH + p) * D_INNER + d] = sdt;
}

// preload all 32 chunk-final states + sumdt (independent loads), then the
// serial recurrence runs as pure VALU with fire-and-forget writes (r9 win).
__global__ __launch_bounds__(256) void scan_pass2(
    const float* __restrict__ A_log, const float* __restrict__ sumdt,
    float* __restrict__ hc)
{
    const int tid = threadIdx.x;
    const int b = blockIdx.x >> 6;
    const int n = (blockIdx.x >> 2) & 15;
    const int d = ((blockIdx.x & 3) << 8) + tid;

    const float Aval = -expf(A_log[d * D_STATE + n]);

    float fin[PCH], sd[PCH];
    #pragma unroll
    for (int p = 0; p < PCH; p++) {
        fin[p] = hc[((size_t)(b * PCH + p) * D_STATE + n) * D_INNER + d];
        sd[p]  = sumdt[(size_t)(b * PCH + p) * D_INNER + d];
    }
    float h = 0.f;
    #pragma unroll
    for (int p = 0; p < PCH; p++) {
        hc[((size_t)(b * PCH + p) * D_STATE + n) * D_INNER + d] = h;
        h = fmaf(__expf(Aval * sd[p]), h, fin[p]);
    }
}

// pass3: u (bf16, in ub) read then overwritten IN PLACE with y*silu(z).
__global__ __launch_bounds__(256) void scan_pass3(
    const float* __restrict__ dtb, const float* __restrict__ bc,
    const ushort_t* __restrict__ xz, const float* __restrict__ A_log,
    const float* __restrict__ Dp, const float* __restrict__ hstart,
    ushort_t* ub)
{
    const int tid = threadIdx.x;
    const int b = blockIdx.x >> 7;
    const int p = (blockIdx.x >> 2) & 31;
    const int d = ((blockIdx.x & 3) << 8) + tid;
    const int t0 = p * CLEN;

    float A[D_STATE];
    #pragma unroll
    for (int n = 0; n < D_STATE; n++) A[n] = -expf(A_log[d * D_STATE + n]);
    const float Dv = Dp[d];

    float h[D_STATE];
    size_t base = (size_t)(b * PCH + p) * D_STATE * D_INNER + d;
    #pragma unroll
    for (int n = 0; n < D_STATE; n++) h[n] = hstart[base + (size_t)n * D_INNER];

    const float* dtp = dtb + ((size_t)b * SEQ + t0) * 1024 + d;
    const float* bp  = bc + ((size_t)b * SEQ + t0) * 64 + 32;
    const ushort_t* zp = xz + ((size_t)b * SEQ + t0) * 2048 + 1024 + d;
    ushort_t* up = ub + ((size_t)b * SEQ + t0) * D_INNER + d;

    for (int t = 0; t < CLEN; t++) {
        float dtv = dtp[(size_t)t * 1024];
        float uv  = bf2f(up[(size_t)t * D_INNER]);
        float zv  = bf2f(zp[(size_t)t * 2048]);
        float dtu = dtv * uv;
        float y = 0.f;
        #pragma unroll
        for (int n = 0; n < D_STATE; n++) {
            h[n] = fmaf(__expf(dtv * A[n]), h[n], dtu * bp[t * 64 + n]);
            y = fmaf(h[n], bp[t * 64 + 16 + n], y);
        }
        float res = fmaf(uv, Dv, y);
        res *= zv / (1.f + __expf(-zv));
        up[(size_t)t * D_INNER] = f2bf(res);
    }
}

// ---------------------------------------------------------------------------
extern "C" void kernel_launch(void* const* d_in, const int* in_sizes, int n_in,
                              void* d_out, int out_size, void* d_ws, size_t ws_size,
                              hipStream_t stream)
{
    const float* x       = (const float*)d_in[0];
    const float* lin1_w  = (const float*)d_in[1];
    const float* lin1_b  = (const float*)d_in[2];
    const float* norm_w  = (const float*)d_in[3];
    const float* in_w    = (const float*)d_in[4];
    const float* conv_w  = (const float*)d_in[5];
    const float* conv_b  = (const float*)d_in[6];
    const float* xproj_w = (const float*)d_in[7];
    const float* dt_w    = (const float*)d_in[8];
    const float* dt_b    = (const float*)d_in[9];
    const float* A_log   = (const float*)d_in[10];
    const float* Dp      = (const float*)d_in[11];
    const float* out_w   = (const float*)d_in[12];
    const float* lin2_w  = (const float*)d_in[13];
    const float* lin2_b  = (const float*)d_in[14];
    float* outp = (float*)d_out;
    (void)ws_size; (void)in_sizes; (void)n_in; (void)out_size;

    float* ws = (float*)d_ws;
    const size_t F1M = 1u << 20;
    float* h     = ws;                                  // 2M fl
    float* dtb   = h + 2 * F1M;                         // 4M fl (dt)
    float* dblr  = dtb + 4 * F1M;                       // 256K fl
    float* dpart = dblr + (size_t)NTOK * 64;            // 1M fl (4 split-K partials)
    float* sumdt = dpart + (size_t)4 * NTOK * 64;       // 128K fl
    float* hfin  = sumdt + (size_t)BATCH * PCH * D_INNER;  // 2M fl
    ushort_t* xzb     = (ushort_t*)(hfin + 2 * F1M);       // 8M us (xp|z, 2048)
    ushort_t* hn_bf   = xzb + 8 * F1M;                     // 2M us
    ushort_t* xb      = hn_bf + 2 * F1M;                   // 4M us
    ushort_t* dblr_bf = xb + 4 * F1M;                      // 256K us (unused, kept)
    ushort_t* lin1_wt = dblr_bf + (size_t)NTOK * 64;       // 512*1024
    ushort_t* in_wt   = lin1_wt + (size_t)512 * 1024;      // 4*2048*512
    ushort_t* out_wt  = in_wt + (size_t)4 * 2048 * 512;    // 4*512*1024
    ushort_t* lin2_wt = out_wt + (size_t)4 * 512 * 1024;   // 1024*512
    ushort_t* xw_t    = lin2_wt + (size_t)1024 * 512;      // 4*64*1024
    ushort_t* w2t     = xw_t + (size_t)4 * 64 * 1024;      // 4*1024*64

    dim3 blk(256);

    // --- weight prep (batched: 6 launches) ---
    transpose_cast_b<<<dim3(512 / 32, 1024 / 32, 1), blk, 0, stream>>>(
        lin1_w, lin1_wt, LATENT, D_MODEL, 0, 0);
    transpose_cast_b<<<dim3(2048 / 32, 512 / 32, N_LAYERS), blk, 0, stream>>>(
        in_w, in_wt, 512, 2048, (size_t)512 * 2048, (size_t)2048 * 512);
    transpose_cast_b<<<dim3(512 / 32, 1024 / 32, N_LAYERS), blk, 0, stream>>>(
        out_w, out_wt, 1024, 512, (size_t)1024 * 512, (size_t)512 * 1024);
    transpose_cast_b<<<dim3(64 / 32, 1024 / 32, N_LAYERS), blk, 0, stream>>>(
        xproj_w, xw_t, 1024, 64, (size_t)1024 * 64, (size_t)64 * 1024);
    transpose_cast_b<<<dim3(1024 / 32, 512 / 32, 1), blk, 0, stream>>>(
        lin2_w, lin2_wt, D_MODEL, LATENT, 0, 0);
    build_w2t_kernel<<<dim3((N_LAYERS * 1024 * 64) / 256), blk, 0, stream>>>(
        dt_w, w2t);

    // x -> bf16 (vectorized: 8 elems/thread)
    cast_bf16_kernel<<<dim3((NTOK * LATENT) / 2048), blk, 0, stream>>>(x, xb);

    // lin1: h = x_bf @ lin1_wt^T + b  (fp32 out; 8x64=512 blocks)
    gemm_bf16_tile<<<dim3(D_MODEL / 64, NTOK / 64), blk, 0, stream>>>(
        xb, LATENT, lin1_wt, LATENT, h, nullptr, D_MODEL, lin1_b,
        NTOK, D_MODEL, LATENT, 1);

    for (int l = 0; l < N_LAYERS; l++) {
        const float* nw = norm_w + (size_t)l * D_MODEL;
        const float* cw = conv_w + (size_t)l * D_INNER * KCONV;
        const float* cb = conv_b + (size_t)l * D_INNER;
        const float* db = dt_b + (size_t)l * D_INNER;
        const float* al = A_log + (size_t)l * D_INNER * D_STATE;
        const float* dp = Dp + (size_t)l * D_INNER;
        const ushort_t* iwt = in_wt + (size_t)l * 2048 * 512;
        const ushort_t* owt = out_wt + (size_t)l * 512 * 1024;
        const ushort_t* xwt = xw_t + (size_t)l * 64 * 1024;
        const ushort_t* w2  = w2t + (size_t)l * 1024 * 64;

        rmsnorm_kernel<<<dim3(NTOK), blk, 0, stream>>>(h, nw, hn_bf);

        // fused in-proj: xzb = hn @ in_w[l] (bf16 out; 256^2 2-phase)
        gemm_bf16_t256<<<dim3(2048 / 256, NTOK / 256), dim3(512), 0, stream>>>(
            hn_bf, D_MODEL, iwt, D_MODEL, xzb, 2048, NTOK, 2048, D_MODEL);

        // conv + silu: xzb[:, :1024] -> xb (bf16 u); vectorized, 8 d/thread
        conv_silu_kernel<<<dim3((NTOK * D_INNER) / 2048), blk, 0, stream>>>(
            xzb, cw, cb, xb);

        // xproj step A (split-K x4): dpart[kq] = u @ xw_t^T  (4x64=256 blocks)
        gemm_stepA<<<dim3(4, NTOK / 64), blk, 0, stream>>>(xb, xwt, dpart);

        // step B with INLINE reduce (r15): dtb = softplus(sum(dpart) @ W2t^T
        // + dt_b); also writes fp32 dblr (B/C for scan). reduce_dblr deleted.
        gemm_stepB<<<dim3(1024 / 64, NTOK / 64), blk, 0, stream>>>(
            dpart, w2, dblr, dtb, db);

        // chunked scan; pass3 overwrites xb in place with y*silu(z)
        scan_pass1<<<dim3(BATCH * PCH * (D_INNER / 256)), blk, 0, stream>>>(
            dtb, dblr, xb, al, hfin, sumdt);
        scan_pass2<<<dim3(BATCH * D_STATE * (D_INNER / 256)), blk, 0, stream>>>(
            al, sumdt, hfin);
        scan_pass3<<<dim3(BATCH * PCH * (D_INNER / 256)), blk, 0, stream>>>(
            dtb, dblr, xzb, al, dp, hfin, xb);

        // h += y_bf @ out_wt^T  (fp32 accumulate; 8x64=512 blocks).
        // Last layer also emits bf16(h) -> hn_bf for lin2 (flag 16).
        gemm_bf16_tile<<<dim3(D_MODEL / 64, NTOK / 64), blk, 0, stream>>>(
            xb, D_INNER, owt, D_INNER, h, hn_bf, D_MODEL, nullptr,
            NTOK, D_MODEL, D_INNER, (l == N_LAYERS - 1) ? 18 : 2);
    }

    // lin2 with FUSED softmax epilogue (flag 32): writes outp directly.
    gemm_bf16_tile<<<dim3(LATENT / 64, NTOK / 64), blk, 0, stream>>>(
        hn_bf, D_MODEL, lin2_wt, D_MODEL, outp, nullptr, LATENT, lin2_b,
        NTOK, LATENT, D_MODEL, 1 | 32);
}

// Round 16
// 637.102 us; speedup vs baseline: 1.2390x; 1.0233x over previous
//
#include <hip/hip_runtime.h>
#include <math.h>

#define D_MODEL 512
#define N_LAYERS 4
#define LATENT 1024
#define D_INNER 1024
#define D_STATE 16
#define DT_RANK 32
#define KCONV 4
#define BATCH 4
#define SEQ 1024
#define NTOK (BATCH * SEQ) /* 4096 */
#define PCH 32
#define CLEN 32

typedef __attribute__((ext_vector_type(8))) short short8;
typedef __attribute__((ext_vector_type(4))) float floatx4;
typedef unsigned short ushort_t;

// gfx9 s_waitcnt immediates: vmcnt lo[3:0] hi[15:14], expcnt[6:4], lgkm[11:8]
#define WC_VM4   0x0F74  /* vmcnt(4) */
#define WC_VM8   0x0F78  /* vmcnt(8) */
#define WC_VM0   0x0F70  /* vmcnt(0) */
#define WC_LGKM0 0xC07F  /* lgkmcnt(0), vm/exp free */

__device__ __forceinline__ ushort_t f2bf(float f) {
    union { float f; unsigned u; } v; v.f = f;
    unsigned r = v.u + 0x7FFFu + ((v.u >> 16) & 1u);  // RNE
    return (ushort_t)(r >> 16);
}
__device__ __forceinline__ float bf2f(ushort_t u) {
    union { unsigned u; float f; } v; v.u = ((unsigned)u) << 16;
    return v.f;
}
// async global -> LDS, 16B per lane (verified width=16 on gfx950, m97).
__device__ __forceinline__ void gll16(const void* g, void* l) {
    __builtin_amdgcn_global_load_lds(
        (const __attribute__((address_space(1))) void*)g,
        (__attribute__((address_space(3))) void*)l, 16, 0, 0);
}

// ---------------------------------------------------------------------------
// 256x256 2-phase GEMM (inproj): bf16 out = A[M,K] @ Bt[N,K]^T.
// ---------------------------------------------------------------------------
__global__ __launch_bounds__(512, 2) void gemm_bf16_t256(
    const ushort_t* __restrict__ A, int lda,
    const ushort_t* __restrict__ Bt, int ldb,
    ushort_t* __restrict__ Cb, int ldc,
    int M, int N, int K)
{
    __shared__ ushort_t As[2][16384];   // [buf][256 rows x 64 cols]
    __shared__ ushort_t Bs[2][16384];

    const int gx = gridDim.x;
    const int nwg = gx * gridDim.y;
    const int orig = blockIdx.y * gx + blockIdx.x;
    const int qq = nwg >> 3, rr = nwg & 7;
    const int xcd = orig & 7, loc = orig >> 3;
    const int swz = (xcd < rr ? xcd * (qq + 1) : rr * (qq + 1) + (xcd - rr) * qq) + loc;
    const int m0 = (swz / gx) * 256;
    const int n0 = (swz % gx) * 256;

    const int tid = threadIdx.x;          // 0..511
    const int w = tid >> 6;               // 0..7
    const int lane = tid & 63;
    const int quad = lane >> 4;
    const int l16 = lane & 15;
    const int wm = (w & 1) * 128;         // wave grid 2M x 4N
    const int wn = (w >> 1) * 64;

    const int srow = tid >> 3;                     // 0..63
    const int schunk = ((tid & 7) ^ (srow & 7)) * 8;
    const ushort_t* ga = A + (size_t)(m0 + srow) * lda + schunk;
    const ushort_t* gb = Bt + (size_t)(n0 + srow) * ldb + schunk;
    const int lofs = tid * 8;

    const int swz0 = ((0 * 4 + quad) ^ (l16 & 7)) * 8;
    const int swz1 = ((1 * 4 + quad) ^ (l16 & 7)) * 8;

    floatx4 acc[8][4] = {};
    const int nt = K >> 6;

    #define STAGE(t, b)                                                         \
        do {                                                                    \
            const ushort_t* pa_ = ga + (t) * 64;                                \
            const ushort_t* pb_ = gb + (t) * 64;                                \
            _Pragma("unroll")                                                   \
            for (int q = 0; q < 4; q++) {                                       \
                gll16(pa_ + (size_t)(q * 64) * lda, &As[(b)][q * 4096 + lofs]); \
                gll16(pb_ + (size_t)(q * 64) * ldb, &Bs[(b)][q * 4096 + lofs]); \
            }                                                                   \
        } while (0)

    STAGE(0, 0);

    for (int kt = 0; kt < nt; kt++) {
        const int cur = kt & 1;
        if (kt + 1 < nt) {
            STAGE(kt + 1, 1 - cur);
            __builtin_amdgcn_s_waitcnt(WC_VM8);
        } else {
            __builtin_amdgcn_s_waitcnt(WC_VM0);
        }
        __builtin_amdgcn_s_barrier();

        {
            short8 af[8], bfr[4];
            #pragma unroll
            for (int i = 0; i < 8; i++)
                af[i] = *(const short8*)&As[cur][(wm + i * 16 + l16) * 64 + swz0];
            #pragma unroll
            for (int j = 0; j < 4; j++)
                bfr[j] = *(const short8*)&Bs[cur][(wn + j * 16 + l16) * 64 + swz0];
            __builtin_amdgcn_s_waitcnt(WC_LGKM0);
            #pragma unroll
            for (int i = 0; i < 8; i++)
                #pragma unroll
                for (int j = 0; j < 4; j++)
                    acc[i][j] = __builtin_amdgcn_mfma_f32_16x16x32_bf16(
                        af[i], bfr[j], acc[i][j], 0, 0, 0);
        }
        {
            short8 af[8], bfr[4];
            #pragma unroll
            for (int i = 0; i < 8; i++)
                af[i] = *(const short8*)&As[cur][(wm + i * 16 + l16) * 64 + swz1];
            #pragma unroll
            for (int j = 0; j < 4; j++)
                bfr[j] = *(const short8*)&Bs[cur][(wn + j * 16 + l16) * 64 + swz1];
            __builtin_amdgcn_s_waitcnt(WC_LGKM0);
            #pragma unroll
            for (int i = 0; i < 8; i++)
                #pragma unroll
                for (int j = 0; j < 4; j++)
                    acc[i][j] = __builtin_amdgcn_mfma_f32_16x16x32_bf16(
                        af[i], bfr[j], acc[i][j], 0, 0, 0);
        }
        __builtin_amdgcn_s_barrier();
    }
    #undef STAGE

    #pragma unroll
    for (int j = 0; j < 4; j++) {
        int n = n0 + wn + j * 16 + l16;
        #pragma unroll
        for (int i = 0; i < 8; i++) {
            int mrow = m0 + wm + i * 16 + quad * 4;
            #pragma unroll
            for (int rr2 = 0; rr2 < 4; rr2++)
                Cb[(size_t)(mrow + rr2) * ldc + n] = f2bf(acc[i][j][rr2]);
        }
    }
}

// ---------------------------------------------------------------------------
// bf16 MFMA GEMM, 64x64 tile (r3 structure — proven across 10 passing runs).
// flags: 1 = add bias[n], 2 = accumulate into C (fp32),
//        4 = softplus(v + bias[n]) for n<1024,
//        8 = write bf16 to Cb only,
//       16 = also write bf16 to Cb (combine with 2),
//       32 = fused 32-wide softmax epilogue (lin2, r11/r12-verified).
// ---------------------------------------------------------------------------
__global__ __launch_bounds__(256, 3) void gemm_bf16_tile(
    const ushort_t* __restrict__ A, int lda,
    const ushort_t* __restrict__ Bt, int ldb,
    float* __restrict__ C, ushort_t* __restrict__ Cb, int ldc,
    const float* __restrict__ bias,
    int M, int N, int K, int flags)
{
    __shared__ ushort_t As[3][4096];   // 3 x 8 KB
    __shared__ ushort_t Bs[3][4096];   // 3 x 8 KB

    const int gx = gridDim.x;
    const int nwg = gx * gridDim.y;
    const int orig = blockIdx.y * gx + blockIdx.x;
    const int qq = nwg >> 3, rr = nwg & 7;
    const int xcd = orig & 7, loc = orig >> 3;
    const int swz = (xcd < rr ? xcd * (qq + 1) : rr * (qq + 1) + (xcd - rr) * qq) + loc;
    const int m0 = (swz / gx) * 64;
    const int n0 = (swz % gx) * 64;

    const int tid = threadIdx.x;
    const int w = tid >> 6;
    const int lane = tid & 63;
    const int quad = lane >> 4;
    const int l16 = lane & 15;
    const int wm = (w & 1) * 32;
    const int wn = (w >> 1) * 32;

    const int srow = tid >> 3;
    const int schunk = ((tid & 7) ^ (srow & 7)) * 8;
    const ushort_t* ga = A + (size_t)(m0 + srow) * lda + schunk;
    const ushort_t* gb = Bt + (size_t)(n0 + srow) * ldb + schunk;
    const int lofs = tid * 8;

    const int swz0 = ((0 * 4 + quad) ^ (l16 & 7)) * 8;
    const int swz1 = ((1 * 4 + quad) ^ (l16 & 7)) * 8;

    floatx4 acc[2][2] = {};
    const int nt = K >> 6;

    #define STAGE(t, b)                                         \
        do {                                                    \
            const ushort_t* pa_ = ga + (t) * 64;                \
            const ushort_t* pb_ = gb + (t) * 64;                \
            gll16(pa_, &As[(b)][lofs]);                         \
            gll16(pa_ + (size_t)32 * lda, &As[(b)][2048 + lofs]); \
            gll16(pb_, &Bs[(b)][lofs]);                         \
            gll16(pb_ + (size_t)32 * ldb, &Bs[(b)][2048 + lofs]); \
        } while (0)

    STAGE(0, 0);
    if (nt > 1) STAGE(1, 1);

    int cur = 0;
    for (int kt = 0; kt < nt; kt++) {
        if (kt + 1 < nt) __builtin_amdgcn_s_waitcnt(WC_VM4);
        else             __builtin_amdgcn_s_waitcnt(WC_VM0);
        __builtin_amdgcn_s_barrier();
        __builtin_amdgcn_sched_barrier(0);

        if (kt + 2 < nt) {
            int nb = cur + 2; if (nb >= 3) nb -= 3;
            STAGE(kt + 2, nb);
        }

        short8 af[2][2], bfr[2][2];
        #pragma unroll
        for (int i = 0; i < 2; i++) {
            const int r = wm + i * 16 + l16;
            af[0][i] = *(const short8*)&As[cur][r * 64 + swz0];
            af[1][i] = *(const short8*)&As[cur][r * 64 + swz1];
        }
        #pragma unroll
        for (int j = 0; j < 2; j++) {
            const int r = wn + j * 16 + l16;
            bfr[0][j] = *(const short8*)&Bs[cur][r * 64 + swz0];
            bfr[1][j] = *(const short8*)&Bs[cur][r * 64 + swz1];
        }
        __builtin_amdgcn_s_waitcnt(WC_LGKM0);
        __builtin_amdgcn_sched_barrier(0);

        #pragma unroll
        for (int ks = 0; ks < 2; ks++)
            #pragma unroll
            for (int i = 0; i < 2; i++)
                #pragma unroll
                for (int j = 0; j < 2; j++)
                    acc[i][j] = __builtin_amdgcn_mfma_f32_16x16x32_bf16(
                        af[ks][i], bfr[ks][j], acc[i][j], 0, 0, 0);

        cur++; if (cur == 3) cur = 0;
    }
    #undef STAGE

    // C/D layout (m89-verified): col = lane&15, row = quad*4 + reg.
    if (flags & 32) {
        #pragma unroll
        for (int i = 0; i < 2; i++) {
            #pragma unroll
            for (int rr2 = 0; rr2 < 4; rr2++) {
                float v0 = acc[i][0][rr2] + bias[n0 + wn + l16];
                float v1 = acc[i][1][rr2] + bias[n0 + wn + 16 + l16];
                float m = fmaxf(v0, v1);
                #pragma unroll
                for (int off = 1; off < 16; off <<= 1)
                    m = fmaxf(m, __shfl_xor(m, off));
                float e0 = __expf(v0 - m), e1 = __expf(v1 - m);
                float s = e0 + e1;
                #pragma unroll
                for (int off = 1; off < 16; off <<= 1)
                    s += __shfl_xor(s, off);
                float inv = 1.f / s;
                size_t row = (size_t)(m0 + wm + i * 16 + quad * 4 + rr2) * ldc;
                C[row + n0 + wn + l16] = e0 * inv;
                C[row + n0 + wn + 16 + l16] = e1 * inv;
            }
        }
        return;
    }
    #pragma unroll
    for (int j = 0; j < 2; j++) {
        int n = n0 + wn + j * 16 + l16;
        float bv = (flags & 1) ? bias[n] : 0.f;
        bool do_sp = (flags & 4) && (n < 1024);
        float spb = do_sp ? bias[n] : 0.f;
        #pragma unroll
        for (int i = 0; i < 2; i++) {
            int mrow = m0 + wm + i * 16 + quad * 4;
            #pragma unroll
            for (int rr2 = 0; rr2 < 4; rr2++) {
                size_t idx = (size_t)(mrow + rr2) * ldc + n;
                float v = acc[i][j][rr2] + bv;
                if (do_sp) {
                    v += spb;
                    v = (v > 20.f) ? v : log1pf(__expf(v));
                }
                if (flags & 8) {
                    Cb[idx] = f2bf(v);
                } else {
                    if (flags & 2) v += C[idx];
                    C[idx] = v;
                    if (flags & 16) Cb[idx] = f2bf(v);
                }
            }
        }
    }
}

// ---------------------------------------------------------------------------
// stepA split-K GEMM: Cpart[kq] = u[:, kq*256:(kq+1)*256] @ xw_t^T (N=64).
// ---------------------------------------------------------------------------
__global__ __launch_bounds__(256, 3) void gemm_stepA(
    const ushort_t* __restrict__ A,   // [NTOK][1024] bf16 (u)
    const ushort_t* __restrict__ Bt,  // [64][1024] bf16 (xw_t)
    float* __restrict__ Cpart)        // [4][NTOK][64]
{
    __shared__ ushort_t As[3][4096];
    __shared__ ushort_t Bs[3][4096];

    const int kq = blockIdx.x;          // 0..3 (K window)
    const int m0 = blockIdx.y * 64;
    const int k0 = kq * 256;

    const int tid = threadIdx.x;
    const int w = tid >> 6;
    const int lane = tid & 63;
    const int quad = lane >> 4;
    const int l16 = lane & 15;
    const int wm = (w & 1) * 32;
    const int wn = (w >> 1) * 32;

    const int srow = tid >> 3;
    const int schunk = ((tid & 7) ^ (srow & 7)) * 8;
    const ushort_t* ga = A + (size_t)(m0 + srow) * 1024 + k0 + schunk;
    const ushort_t* gb = Bt + (size_t)srow * 1024 + k0 + schunk;
    const int lofs = tid * 8;

    const int swz0 = ((0 * 4 + quad) ^ (l16 & 7)) * 8;
    const int swz1 = ((1 * 4 + quad) ^ (l16 & 7)) * 8;

    floatx4 acc[2][2] = {};
    const int nt = 4;

    #define STAGE(t, b)                                            \
        do {                                                       \
            const ushort_t* pa_ = ga + (t) * 64;                   \
            const ushort_t* pb_ = gb + (t) * 64;                   \
            gll16(pa_, &As[(b)][lofs]);                            \
            gll16(pa_ + (size_t)32 * 1024, &As[(b)][2048 + lofs]); \
            gll16(pb_, &Bs[(b)][lofs]);                            \
            gll16(pb_ + (size_t)32 * 1024, &Bs[(b)][2048 + lofs]); \
        } while (0)

    STAGE(0, 0);
    STAGE(1, 1);

    int cur = 0;
    for (int kt = 0; kt < nt; kt++) {
        if (kt + 1 < nt) __builtin_amdgcn_s_waitcnt(WC_VM4);
        else             __builtin_amdgcn_s_waitcnt(WC_VM0);
        __builtin_amdgcn_s_barrier();
        __builtin_amdgcn_sched_barrier(0);

        if (kt + 2 < nt) {
            int nb = cur + 2; if (nb >= 3) nb -= 3;
            STAGE(kt + 2, nb);
        }

        short8 af[2][2], bfr[2][2];
        #pragma unroll
        for (int i = 0; i < 2; i++) {
            const int r = wm + i * 16 + l16;
            af[0][i] = *(const short8*)&As[cur][r * 64 + swz0];
            af[1][i] = *(const short8*)&As[cur][r * 64 + swz1];
        }
        #pragma unroll
        for (int j = 0; j < 2; j++) {
            const int r = wn + j * 16 + l16;
            bfr[0][j] = *(const short8*)&Bs[cur][r * 64 + swz0];
            bfr[1][j] = *(const short8*)&Bs[cur][r * 64 + swz1];
        }
        __builtin_amdgcn_s_waitcnt(WC_LGKM0);
        __builtin_amdgcn_sched_barrier(0);

        #pragma unroll
        for (int ks = 0; ks < 2; ks++)
            #pragma unroll
            for (int i = 0; i < 2; i++)
                #pragma unroll
                for (int j = 0; j < 2; j++)
                    acc[i][j] = __builtin_amdgcn_mfma_f32_16x16x32_bf16(
                        af[ks][i], bfr[ks][j], acc[i][j], 0, 0, 0);

        cur++; if (cur == 3) cur = 0;
    }
    #undef STAGE

    float* Cp = Cpart + (size_t)kq * NTOK * 64;
    #pragma unroll
    for (int j = 0; j < 2; j++) {
        int n = wn + j * 16 + l16;
        #pragma unroll
        for (int i = 0; i < 2; i++) {
            int mrow = m0 + wm + i * 16 + quad * 4;
            #pragma unroll
            for (int rr2 = 0; rr2 < 4; rr2++)
                Cp[(size_t)(mrow + rr2) * 64 + n] = acc[i][j][rr2];
        }
    }
}

// ---------------------------------------------------------------------------
// stepB with INLINE split-K reduction (r15-verified).
// dtb = softplus(sum_kq(part[kq]) @ W2t^T + dt_b); single K=64 tile.
// Blocks with swz%gx==0 also write fp32 dblr (B/C for the scan).
// ---------------------------------------------------------------------------
__global__ __launch_bounds__(256, 3) void gemm_stepB(
    const float* __restrict__ part,   // [4][NTOK][64] split-K partials
    const ushort_t* __restrict__ Bt,  // [1024][64] bf16 (w2t)
    float* __restrict__ dblr,         // [NTOK][64] fp32 (side output)
    float* __restrict__ dtb,          // [NTOK][1024] fp32
    const float* __restrict__ bias)   // dt_b
{
    __shared__ ushort_t As[4096];   // 64 x 64 bf16
    __shared__ ushort_t Bs[4096];

    const int gx = gridDim.x;            // 16
    const int nwg = gx * gridDim.y;      // 1024 (%8==0)
    const int orig = blockIdx.y * gx + blockIdx.x;
    const int qq = nwg >> 3, rr = nwg & 7;
    const int xcd = orig & 7, loc = orig >> 3;
    const int swz = (xcd < rr ? xcd * (qq + 1) : rr * (qq + 1) + (xcd - rr) * qq) + loc;
    const int m0 = (swz / gx) * 64;
    const int n0 = (swz % gx) * 64;
    const bool wdblr = ((swz % gx) == 0);

    const int tid = threadIdx.x;
    const int w = tid >> 6;
    const int lane = tid & 63;
    const int quad = lane >> 4;
    const int l16 = lane & 15;
    const int wm = (w & 1) * 32;
    const int wn = (w >> 1) * 32;

    const int srow = tid >> 3;                    // 0..31
    const int schunk = ((tid & 7) ^ (srow & 7)) * 8;
    const int lofs = tid * 8;

    // B: gll16 staging (w2t rows n0+srow, n0+srow+32).
    const ushort_t* gb = Bt + (size_t)(n0 + srow) * 64 + schunk;
    gll16(gb, &Bs[lofs]);
    gll16(gb + (size_t)32 * 64, &Bs[2048 + lofs]);

    // A: inline 4-way reduction, rows m0+srow and m0+srow+32.
    const size_t st = (size_t)NTOK * 64;
    const float* pa0 = part + (size_t)(m0 + srow) * 64 + schunk;
    const float* pa1 = pa0 + (size_t)32 * 64;
    floatx4 a0l = *(const floatx4*)(pa0);
    floatx4 a0h = *(const floatx4*)(pa0 + 4);
    floatx4 a1l = *(const floatx4*)(pa1);
    floatx4 a1h = *(const floatx4*)(pa1 + 4);
    #pragma unroll
    for (int kq = 1; kq < 4; kq++) {
        a0l += *(const floatx4*)(pa0 + (size_t)kq * st);
        a0h += *(const floatx4*)(pa0 + (size_t)kq * st + 4);
        a1l += *(const floatx4*)(pa1 + (size_t)kq * st);
        a1h += *(const floatx4*)(pa1 + (size_t)kq * st + 4);
    }
    short8 u0, u1;
    #pragma unroll
    for (int q = 0; q < 4; q++) {
        u0[q] = (short)f2bf(a0l[q]); u0[4 + q] = (short)f2bf(a0h[q]);
        u1[q] = (short)f2bf(a1l[q]); u1[4 + q] = (short)f2bf(a1h[q]);
    }
    *(short8*)&As[lofs] = u0;
    *(short8*)&As[2048 + lofs] = u1;
    if (wdblr) {
        float* d0 = dblr + (size_t)(m0 + srow) * 64 + schunk;
        *(floatx4*)(d0) = a0l;       *(floatx4*)(d0 + 4) = a0h;
        *(floatx4*)(d0 + 32 * 64) = a1l; *(floatx4*)(d0 + 32 * 64 + 4) = a1h;
    }
    __syncthreads();

    const int swz0 = ((0 * 4 + quad) ^ (l16 & 7)) * 8;
    const int swz1 = ((1 * 4 + quad) ^ (l16 & 7)) * 8;

    floatx4 acc[2][2] = {};
    short8 af[2][2], bfr[2][2];
    #pragma unroll
    for (int i = 0; i < 2; i++) {
        const int r = wm + i * 16 + l16;
        af[0][i] = *(const short8*)&As[r * 64 + swz0];
        af[1][i] = *(const short8*)&As[r * 64 + swz1];
    }
    #pragma unroll
    for (int j = 0; j < 2; j++) {
        const int r = wn + j * 16 + l16;
        bfr[0][j] = *(const short8*)&Bs[r * 64 + swz0];
        bfr[1][j] = *(const short8*)&Bs[r * 64 + swz1];
    }
    #pragma unroll
    for (int ks = 0; ks < 2; ks++)
        #pragma unroll
        for (int i = 0; i < 2; i++)
            #pragma unroll
            for (int j = 0; j < 2; j++)
                acc[i][j] = __builtin_amdgcn_mfma_f32_16x16x32_bf16(
                    af[ks][i], bfr[ks][j], acc[i][j], 0, 0, 0);

    // epilogue: softplus(v + dt_b[n]) -> dtb
    #pragma unroll
    for (int j = 0; j < 2; j++) {
        int n = n0 + wn + j * 16 + l16;
        float spb = bias[n];
        #pragma unroll
        for (int i = 0; i < 2; i++) {
            int mrow = m0 + wm + i * 16 + quad * 4;
            #pragma unroll
            for (int rr2 = 0; rr2 < 4; rr2++) {
                float v = acc[i][j][rr2] + spb;
                v = (v > 20.f) ? v : log1pf(__expf(v));
                dtb[(size_t)(mrow + rr2) * 1024 + n] = v;
            }
        }
    }
}

// ---------------------------------------------------------------------------
// r16: ONE mega-prep kernel replacing 7 prologue launches: 5 weight
// transposes + build_w2t + x->bf16 cast. Flat 1D grid, section ranges;
// each section runs the byte-identical body of the kernel it replaces.
// Sections (block ranges):
//   [0,512)        lin1_w  [1024][512]  -> lin1_wt  (gxt=16)
//   [512,4608)     in_w    4x[512][2048]-> in_wt    (gxt=64, 1024/layer)
//   [4608,6656)    out_w   4x[1024][512]-> out_wt   (gxt=16, 512/layer)
//   [6656,6912)    xproj_w 4x[1024][64] -> xw_t     (gxt=2,  64/layer)
//   [6912,7424)    lin2_w  [512][1024]  -> lin2_wt  (gxt=32)
//   [7424,8448)    build_w2t (1024 elementwise blocks)
//   [8448,10496)   x -> xb vector cast (2048 blocks, 8 elems/thread)
// ---------------------------------------------------------------------------
__global__ __launch_bounds__(256) void prep_all(
    const float* __restrict__ lin1_w, const float* __restrict__ in_w,
    const float* __restrict__ out_w, const float* __restrict__ xproj_w,
    const float* __restrict__ lin2_w, const float* __restrict__ dt_w,
    const float* __restrict__ x,
    ushort_t* __restrict__ lin1_wt, ushort_t* __restrict__ in_wt,
    ushort_t* __restrict__ out_wt, ushort_t* __restrict__ xw_t,
    ushort_t* __restrict__ lin2_wt, ushort_t* __restrict__ w2t,
    ushort_t* __restrict__ xb)
{
    const int bid = blockIdx.x;
    const int tid = threadIdx.x;

    if (bid >= 8448) {                       // x -> bf16 cast
        const int i = ((bid - 8448) * 256 + tid) * 8;
        floatx4 a = *(const floatx4*)&x[i];
        floatx4 b = *(const floatx4*)&x[i + 4];
        short8 o;
        o[0] = (short)f2bf(a[0]); o[1] = (short)f2bf(a[1]);
        o[2] = (short)f2bf(a[2]); o[3] = (short)f2bf(a[3]);
        o[4] = (short)f2bf(b[0]); o[5] = (short)f2bf(b[1]);
        o[6] = (short)f2bf(b[2]); o[7] = (short)f2bf(b[3]);
        *(short8*)&xb[i] = o;
        return;
    }
    if (bid >= 7424) {                       // build_w2t
        const int idx = (bid - 7424) * 256 + tid;
        const int k = idx & 63;
        const int n = (idx >> 6) & 1023;
        const int l = idx >> 16;
        ushort_t v = 0;
        if (k < 32)
            v = f2bf(dt_w[((size_t)l * DT_RANK + k) * D_INNER + n]);
        w2t[((size_t)l * 1024 + n) * 64 + k] = v;
        return;
    }

    // transpose sections: in[K][N] -> out[N][K] bf16, 32x32 tiles.
    const float* in; ushort_t* out; int K, N, t;
    if (bid < 512) {
        in = lin1_w; out = lin1_wt; K = 1024; N = 512; t = bid;
    } else if (bid < 4608) {
        int lb = bid - 512, l = lb >> 10; t = lb & 1023;
        in = in_w + (size_t)l * 512 * 2048; out = in_wt + (size_t)l * 2048 * 512;
        K = 512; N = 2048;
    } else if (bid < 6656) {
        int lb = bid - 4608, l = lb >> 9; t = lb & 511;
        in = out_w + (size_t)l * 1024 * 512; out = out_wt + (size_t)l * 512 * 1024;
        K = 1024; N = 512;
    } else if (bid < 6912) {
        int lb = bid - 6656, l = lb >> 6; t = lb & 63;
        in = xproj_w + (size_t)l * 1024 * 64; out = xw_t + (size_t)l * 64 * 1024;
        K = 1024; N = 64;
    } else {
        in = lin2_w; out = lin2_wt; K = 512; N = 1024; t = bid - 6912;
    }
    const int gxt = N >> 5;
    const int n0 = (t % gxt) * 32, k0 = (t / gxt) * 32;

    __shared__ float tile[32][33];
    const int tx = tid & 31, ty = tid >> 5;
    #pragma unroll
    for (int i = 0; i < 4; i++)
        tile[ty + i * 8][tx] = in[(size_t)(k0 + ty + i * 8) * N + n0 + tx];
    __syncthreads();
    #pragma unroll
    for (int i = 0; i < 4; i++)
        out[(size_t)(n0 + ty + i * 8) * K + k0 + tx] = f2bf(tile[tx][ty + i * 8]);
}

// ---------------------------------------------------------------------------
// rmsnorm with float2 loads/stores (G13, r13-verified).
// ---------------------------------------------------------------------------
__global__ __launch_bounds__(256) void rmsnorm_kernel(
    const float* __restrict__ x, const float* __restrict__ w,
    ushort_t* __restrict__ y)
{
    const int row = blockIdx.x;
    const float* xr = x + (size_t)row * D_MODEL;
    ushort_t* yr = y + (size_t)row * D_MODEL;
    const int tid = threadIdx.x;

    float2 v = *(const float2*)&xr[tid * 2];
    float ss = v.x * v.x + v.y * v.y;
    #pragma unroll
    for (int off = 32; off > 0; off >>= 1) ss += __shfl_down(ss, off);

    __shared__ float wsum[4];
    __shared__ float scale_s;
    int wid = tid >> 6, lane = tid & 63;
    if (lane == 0) wsum[wid] = ss;
    __syncthreads();
    if (tid == 0) {
        float tot = wsum[0] + wsum[1] + wsum[2] + wsum[3];
        scale_s = 1.0f / sqrtf(tot / (float)D_MODEL + 1e-5f);
    }
    __syncthreads();
    float sc = scale_s;
    float2 wv = *(const float2*)&w[tid * 2];
    ushort2 o;
    o.x = f2bf(v.x * sc * wv.x);
    o.y = f2bf(v.y * sc * wv.y);
    *(ushort2*)&yr[tid * 2] = o;
}

// ---------------------------------------------------------------------------
// causal dwconv (K=4) + bias + silu, VECTORIZED (short8, 8 d/thread;
// G13, r13-verified). Reads bf16 xz (stride 2048), writes bf16 u.
// ---------------------------------------------------------------------------
__global__ __launch_bounds__(256) void conv_silu_kernel(
    const ushort_t* __restrict__ xz, const float* __restrict__ w,
    const float* __restrict__ bconv, ushort_t* __restrict__ outb)
{
    const int idx = blockIdx.x * 256 + threadIdx.x;   // NTOK*128 threads
    const int d0 = (idx & 127) * 8;
    const int row = idx >> 7;
    const int t = row & (SEQ - 1);
    const ushort_t* base = xz + (size_t)row * 2048 + d0;

    short8 xv[4];
    #pragma unroll
    for (int k = 0; k < KCONV; k++) {
        if (t + k - (KCONV - 1) >= 0)
            xv[k] = *(const short8*)(base + (ptrdiff_t)(k - (KCONV - 1)) * 2048);
        else
            xv[k] = short8{0, 0, 0, 0, 0, 0, 0, 0};
    }

    short8 o;
    #pragma unroll
    for (int q = 0; q < 8; q++) {
        floatx4 wq = *(const floatx4*)&w[(size_t)(d0 + q) * KCONV];
        float s = 0.f;
        #pragma unroll
        for (int k = 0; k < KCONV; k++)
            s = fmaf(bf2f((ushort_t)xv[k][q]), wq[k], s);
        s += bconv[d0 + q];
        float r = s / (1.f + __expf(-s));
        o[q] = (short)f2bf(r);
    }
    *(short8*)&outb[(size_t)row * D_INNER + d0] = o;
}

// ---------------------------------------------------------------------------
// Chunked selective scan (3 passes), CLEN=32 — r10/r12 structure.
// ---------------------------------------------------------------------------
__global__ __launch_bounds__(256) void scan_pass1(
    const float* __restrict__ dtb, const float* __restrict__ bc,
    const ushort_t* __restrict__ ub, const float* __restrict__ A_log,
    float* __restrict__ hfin, float* __restrict__ sumdt)
{
    const int tid = threadIdx.x;
    const int b = blockIdx.x >> 7;
    const int p = (blockIdx.x >> 2) & 31;
    const int d = ((blockIdx.x & 3) << 8) + tid;
    const int t0 = p * CLEN;

    float A[D_STATE];
    #pragma unroll
    for (int n = 0; n < D_STATE; n++) A[n] = -expf(A_log[d * D_STATE + n]);

    float h[D_STATE] = {};
    float sdt = 0.f;

    const float* dtp = dtb + ((size_t)b * SEQ + t0) * 1024 + d;
    const float* bp  = bc + ((size_t)b * SEQ + t0) * 64 + 32;
    const ushort_t* up = ub + ((size_t)b * SEQ + t0) * D_INNER + d;

    for (int t = 0; t < CLEN; t++) {
        float dtv = dtp[(size_t)t * 1024];
        float uv  = bf2f(up[(size_t)t * D_INNER]);
        float dtu = dtv * uv;
        sdt += dtv;
        #pragma unroll
        for (int n = 0; n < D_STATE; n++)
            h[n] = fmaf(__expf(dtv * A[n]), h[n], dtu * bp[t * 64 + n]);
    }

    size_t base = (size_t)(b * PCH + p) * D_STATE * D_INNER + d;
    #pragma unroll
    for (int n = 0; n < D_STATE; n++) hfin[base + (size_t)n * D_INNER] = h[n];
    sumdt[(size_t)(b * PCH + p) * D_INNER + d] = sdt;
}

// preload all 32 chunk-final states + sumdt, then recurrence as pure VALU.
__global__ __launch_bounds__(256) void scan_pass2(
    const float* __restrict__ A_log, const float* __restrict__ sumdt,
    float* __restrict__ hc)
{
    const int tid = threadIdx.x;
    const int b = blockIdx.x >> 6;
    const int n = (blockIdx.x >> 2) & 15;
    const int d = ((blockIdx.x & 3) << 8) + tid;

    const float Aval = -expf(A_log[d * D_STATE + n]);

    float fin[PCH], sd[PCH];
    #pragma unroll
    for (int p = 0; p < PCH; p++) {
        fin[p] = hc[((size_t)(b * PCH + p) * D_STATE + n) * D_INNER + d];
        sd[p]  = sumdt[(size_t)(b * PCH + p) * D_INNER + d];
    }
    float h = 0.f;
    #pragma unroll
    for (int p = 0; p < PCH; p++) {
        hc[((size_t)(b * PCH + p) * D_STATE + n) * D_INNER + d] = h;
        h = fmaf(__expf(Aval * sd[p]), h, fin[p]);
    }
}

// pass3: u (bf16, in ub) read then overwritten IN PLACE with y*silu(z).
__global__ __launch_bounds__(256) void scan_pass3(
    const float* __restrict__ dtb, const float* __restrict__ bc,
    const ushort_t* __restrict__ xz, const float* __restrict__ A_log,
    const float* __restrict__ Dp, const float* __restrict__ hstart,
    ushort_t* ub)
{
    const int tid = threadIdx.x;
    const int b = blockIdx.x >> 7;
    const int p = (blockIdx.x >> 2) & 31;
    const int d = ((blockIdx.x & 3) << 8) + tid;
    const int t0 = p * CLEN;

    float A[D_STATE];
    #pragma unroll
    for (int n = 0; n < D_STATE; n++) A[n] = -expf(A_log[d * D_STATE + n]);
    const float Dv = Dp[d];

    float h[D_STATE];
    size_t base = (size_t)(b * PCH + p) * D_STATE * D_INNER + d;
    #pragma unroll
    for (int n = 0; n < D_STATE; n++) h[n] = hstart[base + (size_t)n * D_INNER];

    const float* dtp = dtb + ((size_t)b * SEQ + t0) * 1024 + d;
    const float* bp  = bc + ((size_t)b * SEQ + t0) * 64 + 32;
    const ushort_t* zp = xz + ((size_t)b * SEQ + t0) * 2048 + 1024 + d;
    ushort_t* up = ub + ((size_t)b * SEQ + t0) * D_INNER + d;

    for (int t = 0; t < CLEN; t++) {
        float dtv = dtp[(size_t)t * 1024];
        float uv  = bf2f(up[(size_t)t * D_INNER]);
        float zv  = bf2f(zp[(size_t)t * 2048]);
        float dtu = dtv * uv;
        float y = 0.f;
        #pragma unroll
        for (int n = 0; n < D_STATE; n++) {
            h[n] = fmaf(__expf(dtv * A[n]), h[n], dtu * bp[t * 64 + n]);
            y = fmaf(h[n], bp[t * 64 + 16 + n], y);
        }
        float res = fmaf(uv, Dv, y);
        res *= zv / (1.f + __expf(-zv));
        up[(size_t)t * D_INNER] = f2bf(res);
    }
}

// ---------------------------------------------------------------------------
extern "C" void kernel_launch(void* const* d_in, const int* in_sizes, int n_in,
                              void* d_out, int out_size, void* d_ws, size_t ws_size,
                              hipStream_t stream)
{
    const float* x       = (const float*)d_in[0];
    const float* lin1_w  = (const float*)d_in[1];
    const float* lin1_b  = (const float*)d_in[2];
    const float* norm_w  = (const float*)d_in[3];
    const float* in_w    = (const float*)d_in[4];
    const float* conv_w  = (const float*)d_in[5];
    const float* conv_b  = (const float*)d_in[6];
    const float* xproj_w = (const float*)d_in[7];
    const float* dt_w    = (const float*)d_in[8];
    const float* dt_b    = (const float*)d_in[9];
    const float* A_log   = (const float*)d_in[10];
    const float* Dp      = (const float*)d_in[11];
    const float* out_w   = (const float*)d_in[12];
    const float* lin2_w  = (const float*)d_in[13];
    const float* lin2_b  = (const float*)d_in[14];
    float* outp = (float*)d_out;
    (void)ws_size; (void)in_sizes; (void)n_in; (void)out_size;

    float* ws = (float*)d_ws;
    const size_t F1M = 1u << 20;
    float* h     = ws;                                  // 2M fl
    float* dtb   = h + 2 * F1M;                         // 4M fl (dt)
    float* dblr  = dtb + 4 * F1M;                       // 256K fl
    float* dpart = dblr + (size_t)NTOK * 64;            // 1M fl (4 split-K partials)
    float* sumdt = dpart + (size_t)4 * NTOK * 64;       // 128K fl
    float* hfin  = sumdt + (size_t)BATCH * PCH * D_INNER;  // 2M fl
    ushort_t* xzb     = (ushort_t*)(hfin + 2 * F1M);       // 8M us (xp|z, 2048)
    ushort_t* hn_bf   = xzb + 8 * F1M;                     // 2M us
    ushort_t* xb      = hn_bf + 2 * F1M;                   // 4M us
    ushort_t* dblr_bf = xb + 4 * F1M;                      // 256K us (unused, kept)
    ushort_t* lin1_wt = dblr_bf + (size_t)NTOK * 64;       // 512*1024
    ushort_t* in_wt   = lin1_wt + (size_t)512 * 1024;      // 4*2048*512
    ushort_t* out_wt  = in_wt + (size_t)4 * 2048 * 512;    // 4*512*1024
    ushort_t* lin2_wt = out_wt + (size_t)4 * 512 * 1024;   // 1024*512
    ushort_t* xw_t    = lin2_wt + (size_t)1024 * 512;      // 4*64*1024
    ushort_t* w2t     = xw_t + (size_t)4 * 64 * 1024;      // 4*1024*64

    dim3 blk(256);

    // --- r16: all prep (5 transposes + w2t + x-cast) in ONE launch ---
    prep_all<<<dim3(10496), blk, 0, stream>>>(
        lin1_w, in_w, out_w, xproj_w, lin2_w, dt_w, x,
        lin1_wt, in_wt, out_wt, xw_t, lin2_wt, w2t, xb);

    // lin1: h = x_bf @ lin1_wt^T + b  (fp32 out; 8x64=512 blocks)
    gemm_bf16_tile<<<dim3(D_MODEL / 64, NTOK / 64), blk, 0, stream>>>(
        xb, LATENT, lin1_wt, LATENT, h, nullptr, D_MODEL, lin1_b,
        NTOK, D_MODEL, LATENT, 1);

    for (int l = 0; l < N_LAYERS; l++) {
        const float* nw = norm_w + (size_t)l * D_MODEL;
        const float* cw = conv_w + (size_t)l * D_INNER * KCONV;
        const float* cb = conv_b + (size_t)l * D_INNER;
        const float* db = dt_b + (size_t)l * D_INNER;
        const float* al = A_log + (size_t)l * D_INNER * D_STATE;
        const float* dp = Dp + (size_t)l * D_INNER;
        const ushort_t* iwt = in_wt + (size_t)l * 2048 * 512;
        const ushort_t* owt = out_wt + (size_t)l * 512 * 1024;
        const ushort_t* xwt = xw_t + (size_t)l * 64 * 1024;
        const ushort_t* w2  = w2t + (size_t)l * 1024 * 64;

        rmsnorm_kernel<<<dim3(NTOK), blk, 0, stream>>>(h, nw, hn_bf);

        // fused in-proj: xzb = hn @ in_w[l] (bf16 out; 256^2 2-phase)
        gemm_bf16_t256<<<dim3(2048 / 256, NTOK / 256), dim3(512), 0, stream>>>(
            hn_bf, D_MODEL, iwt, D_MODEL, xzb, 2048, NTOK, 2048, D_MODEL);

        // conv + silu: xzb[:, :1024] -> xb (bf16 u); vectorized, 8 d/thread
        conv_silu_kernel<<<dim3((NTOK * D_INNER) / 2048), blk, 0, stream>>>(
            xzb, cw, cb, xb);

        // xproj step A (split-K x4): dpart[kq] = u @ xw_t^T  (4x64=256 blocks)
        gemm_stepA<<<dim3(4, NTOK / 64), blk, 0, stream>>>(xb, xwt, dpart);

        // step B with inline reduce: dtb = softplus(sum(dpart) @ W2t^T + dt_b)
        // + fp32 dblr side-output (r15-verified).
        gemm_stepB<<<dim3(1024 / 64, NTOK / 64), blk, 0, stream>>>(
            dpart, w2, dblr, dtb, db);

        // chunked scan; pass3 overwrites xb in place with y*silu(z)
        scan_pass1<<<dim3(BATCH * PCH * (D_INNER / 256)), blk, 0, stream>>>(
            dtb, dblr, xb, al, hfin, sumdt);
        scan_pass2<<<dim3(BATCH * D_STATE * (D_INNER / 256)), blk, 0, stream>>>(
            al, sumdt, hfin);
        scan_pass3<<<dim3(BATCH * PCH * (D_INNER / 256)), blk, 0, stream>>>(
            dtb, dblr, xzb, al, dp, hfin, xb);

        // h += y_bf @ out_wt^T  (fp32 accumulate; 8x64=512 blocks).
        // Last layer also emits bf16(h) -> hn_bf for lin2 (flag 16).
        gemm_bf16_tile<<<dim3(D_MODEL / 64, NTOK / 64), blk, 0, stream>>>(
            xb, D_INNER, owt, D_INNER, h, hn_bf, D_MODEL, nullptr,
            NTOK, D_MODEL, D_INNER, (l == N_LAYERS - 1) ? 18 : 2);
    }

    // lin2 with FUSED softmax epilogue (flag 32): writes outp directly.
    gemm_bf16_tile<<<dim3(LATENT / 64, NTOK / 64), blk, 0, stream>>>(
        hn_bf, D_MODEL, lin2_wt, D_MODEL, outp, nullptr, LATENT, lin2_b,
        NTOK, LATENT, D_MODEL, 1 | 32);
}

// Round 17
// 628.099 us; speedup vs baseline: 1.2568x; 1.0143x over previous
//
#include <hip/hip_runtime.h>
#include <math.h>

#define D_MODEL 512
#define N_LAYERS 4
#define LATENT 1024
#define D_INNER 1024
#define D_STATE 16
#define DT_RANK 32
#define KCONV 4
#define BATCH 4
#define SEQ 1024
#define NTOK (BATCH * SEQ) /* 4096 */
#define PCH 32
#define CLEN 32

typedef __attribute__((ext_vector_type(8))) short short8;
typedef __attribute__((ext_vector_type(4))) float floatx4;
typedef unsigned short ushort_t;

// gfx9 s_waitcnt immediates: vmcnt lo[3:0] hi[15:14], expcnt[6:4], lgkm[11:8]
#define WC_VM4   0x0F74  /* vmcnt(4) */
#define WC_VM8   0x0F78  /* vmcnt(8) */
#define WC_VM0   0x0F70  /* vmcnt(0) */
#define WC_LGKM0 0xC07F  /* lgkmcnt(0), vm/exp free */

__device__ __forceinline__ ushort_t f2bf(float f) {
    union { float f; unsigned u; } v; v.f = f;
    unsigned r = v.u + 0x7FFFu + ((v.u >> 16) & 1u);  // RNE
    return (ushort_t)(r >> 16);
}
__device__ __forceinline__ float bf2f(ushort_t u) {
    union { unsigned u; float f; } v; v.u = ((unsigned)u) << 16;
    return v.f;
}
// async global -> LDS, 16B per lane (verified width=16 on gfx950, m97).
__device__ __forceinline__ void gll16(const void* g, void* l) {
    __builtin_amdgcn_global_load_lds(
        (const __attribute__((address_space(1))) void*)g,
        (__attribute__((address_space(3))) void*)l, 16, 0, 0);
}

// ---------------------------------------------------------------------------
// 256x256 2-phase GEMM (inproj): bf16 out = A[M,K] @ Bt[N,K]^T.
// ---------------------------------------------------------------------------
__global__ __launch_bounds__(512, 2) void gemm_bf16_t256(
    const ushort_t* __restrict__ A, int lda,
    const ushort_t* __restrict__ Bt, int ldb,
    ushort_t* __restrict__ Cb, int ldc,
    int M, int N, int K)
{
    __shared__ ushort_t As[2][16384];   // [buf][256 rows x 64 cols]
    __shared__ ushort_t Bs[2][16384];

    const int gx = gridDim.x;
    const int nwg = gx * gridDim.y;
    const int orig = blockIdx.y * gx + blockIdx.x;
    const int qq = nwg >> 3, rr = nwg & 7;
    const int xcd = orig & 7, loc = orig >> 3;
    const int swz = (xcd < rr ? xcd * (qq + 1) : rr * (qq + 1) + (xcd - rr) * qq) + loc;
    const int m0 = (swz / gx) * 256;
    const int n0 = (swz % gx) * 256;

    const int tid = threadIdx.x;          // 0..511
    const int w = tid >> 6;               // 0..7
    const int lane = tid & 63;
    const int quad = lane >> 4;
    const int l16 = lane & 15;
    const int wm = (w & 1) * 128;         // wave grid 2M x 4N
    const int wn = (w >> 1) * 64;

    const int srow = tid >> 3;                     // 0..63
    const int schunk = ((tid & 7) ^ (srow & 7)) * 8;
    const ushort_t* ga = A + (size_t)(m0 + srow) * lda + schunk;
    const ushort_t* gb = Bt + (size_t)(n0 + srow) * ldb + schunk;
    const int lofs = tid * 8;

    const int swz0 = ((0 * 4 + quad) ^ (l16 & 7)) * 8;
    const int swz1 = ((1 * 4 + quad) ^ (l16 & 7)) * 8;

    floatx4 acc[8][4] = {};
    const int nt = K >> 6;

    #define STAGE(t, b)                                                         \
        do {                                                                    \
            const ushort_t* pa_ = ga + (t) * 64;                                \
            const ushort_t* pb_ = gb + (t) * 64;                                \
            _Pragma("unroll")                                                   \
            for (int q = 0; q < 4; q++) {                                       \
                gll16(pa_ + (size_t)(q * 64) * lda, &As[(b)][q * 4096 + lofs]); \
                gll16(pb_ + (size_t)(q * 64) * ldb, &Bs[(b)][q * 4096 + lofs]); \
            }                                                                   \
        } while (0)

    STAGE(0, 0);

    for (int kt = 0; kt < nt; kt++) {
        const int cur = kt & 1;
        if (kt + 1 < nt) {
            STAGE(kt + 1, 1 - cur);
            __builtin_amdgcn_s_waitcnt(WC_VM8);
        } else {
            __builtin_amdgcn_s_waitcnt(WC_VM0);
        }
        __builtin_amdgcn_s_barrier();

        {
            short8 af[8], bfr[4];
            #pragma unroll
            for (int i = 0; i < 8; i++)
                af[i] = *(const short8*)&As[cur][(wm + i * 16 + l16) * 64 + swz0];
            #pragma unroll
            for (int j = 0; j < 4; j++)
                bfr[j] = *(const short8*)&Bs[cur][(wn + j * 16 + l16) * 64 + swz0];
            __builtin_amdgcn_s_waitcnt(WC_LGKM0);
            #pragma unroll
            for (int i = 0; i < 8; i++)
                #pragma unroll
                for (int j = 0; j < 4; j++)
                    acc[i][j] = __builtin_amdgcn_mfma_f32_16x16x32_bf16(
                        af[i], bfr[j], acc[i][j], 0, 0, 0);
        }
        {
            short8 af[8], bfr[4];
            #pragma unroll
            for (int i = 0; i < 8; i++)
                af[i] = *(const short8*)&As[cur][(wm + i * 16 + l16) * 64 + swz1];
            #pragma unroll
            for (int j = 0; j < 4; j++)
                bfr[j] = *(const short8*)&Bs[cur][(wn + j * 16 + l16) * 64 + swz1];
            __builtin_amdgcn_s_waitcnt(WC_LGKM0);
            #pragma unroll
            for (int i = 0; i < 8; i++)
                #pragma unroll
                for (int j = 0; j < 4; j++)
                    acc[i][j] = __builtin_amdgcn_mfma_f32_16x16x32_bf16(
                        af[i], bfr[j], acc[i][j], 0, 0, 0);
        }
        __builtin_amdgcn_s_barrier();
    }
    #undef STAGE

    #pragma unroll
    for (int j = 0; j < 4; j++) {
        int n = n0 + wn + j * 16 + l16;
        #pragma unroll
        for (int i = 0; i < 8; i++) {
            int mrow = m0 + wm + i * 16 + quad * 4;
            #pragma unroll
            for (int rr2 = 0; rr2 < 4; rr2++)
                Cb[(size_t)(mrow + rr2) * ldc + n] = f2bf(acc[i][j][rr2]);
        }
    }
}

// ---------------------------------------------------------------------------
// bf16 MFMA GEMM, 64x64 tile (r3 structure — proven across 11 passing runs).
// flags: 1 = add bias[n], 2 = accumulate into C (fp32),
//        4 = softplus(v + bias[n]) for n<1024,
//        8 = write bf16 to Cb only,
//       16 = also write bf16 to Cb (combine with 2),
//       32 = fused 32-wide softmax epilogue (lin2, r11/r12-verified).
// ---------------------------------------------------------------------------
__global__ __launch_bounds__(256, 3) void gemm_bf16_tile(
    const ushort_t* __restrict__ A, int lda,
    const ushort_t* __restrict__ Bt, int ldb,
    float* __restrict__ C, ushort_t* __restrict__ Cb, int ldc,
    const float* __restrict__ bias,
    int M, int N, int K, int flags)
{
    __shared__ ushort_t As[3][4096];   // 3 x 8 KB
    __shared__ ushort_t Bs[3][4096];   // 3 x 8 KB

    const int gx = gridDim.x;
    const int nwg = gx * gridDim.y;
    const int orig = blockIdx.y * gx + blockIdx.x;
    const int qq = nwg >> 3, rr = nwg & 7;
    const int xcd = orig & 7, loc = orig >> 3;
    const int swz = (xcd < rr ? xcd * (qq + 1) : rr * (qq + 1) + (xcd - rr) * qq) + loc;
    const int m0 = (swz / gx) * 64;
    const int n0 = (swz % gx) * 64;

    const int tid = threadIdx.x;
    const int w = tid >> 6;
    const int lane = tid & 63;
    const int quad = lane >> 4;
    const int l16 = lane & 15;
    const int wm = (w & 1) * 32;
    const int wn = (w >> 1) * 32;

    const int srow = tid >> 3;
    const int schunk = ((tid & 7) ^ (srow & 7)) * 8;
    const ushort_t* ga = A + (size_t)(m0 + srow) * lda + schunk;
    const ushort_t* gb = Bt + (size_t)(n0 + srow) * ldb + schunk;
    const int lofs = tid * 8;

    const int swz0 = ((0 * 4 + quad) ^ (l16 & 7)) * 8;
    const int swz1 = ((1 * 4 + quad) ^ (l16 & 7)) * 8;

    floatx4 acc[2][2] = {};
    const int nt = K >> 6;

    #define STAGE(t, b)                                         \
        do {                                                    \
            const ushort_t* pa_ = ga + (t) * 64;                \
            const ushort_t* pb_ = gb + (t) * 64;                \
            gll16(pa_, &As[(b)][lofs]);                         \
            gll16(pa_ + (size_t)32 * lda, &As[(b)][2048 + lofs]); \
            gll16(pb_, &Bs[(b)][lofs]);                         \
            gll16(pb_ + (size_t)32 * ldb, &Bs[(b)][2048 + lofs]); \
        } while (0)

    STAGE(0, 0);
    if (nt > 1) STAGE(1, 1);

    int cur = 0;
    for (int kt = 0; kt < nt; kt++) {
        if (kt + 1 < nt) __builtin_amdgcn_s_waitcnt(WC_VM4);
        else             __builtin_amdgcn_s_waitcnt(WC_VM0);
        __builtin_amdgcn_s_barrier();
        __builtin_amdgcn_sched_barrier(0);

        if (kt + 2 < nt) {
            int nb = cur + 2; if (nb >= 3) nb -= 3;
            STAGE(kt + 2, nb);
        }

        short8 af[2][2], bfr[2][2];
        #pragma unroll
        for (int i = 0; i < 2; i++) {
            const int r = wm + i * 16 + l16;
            af[0][i] = *(const short8*)&As[cur][r * 64 + swz0];
            af[1][i] = *(const short8*)&As[cur][r * 64 + swz1];
        }
        #pragma unroll
        for (int j = 0; j < 2; j++) {
            const int r = wn + j * 16 + l16;
            bfr[0][j] = *(const short8*)&Bs[cur][r * 64 + swz0];
            bfr[1][j] = *(const short8*)&Bs[cur][r * 64 + swz1];
        }
        __builtin_amdgcn_s_waitcnt(WC_LGKM0);
        __builtin_amdgcn_sched_barrier(0);

        #pragma unroll
        for (int ks = 0; ks < 2; ks++)
            #pragma unroll
            for (int i = 0; i < 2; i++)
                #pragma unroll
                for (int j = 0; j < 2; j++)
                    acc[i][j] = __builtin_amdgcn_mfma_f32_16x16x32_bf16(
                        af[ks][i], bfr[ks][j], acc[i][j], 0, 0, 0);

        cur++; if (cur == 3) cur = 0;
    }
    #undef STAGE

    // C/D layout (m89-verified): col = lane&15, row = quad*4 + reg.
    if (flags & 32) {
        #pragma unroll
        for (int i = 0; i < 2; i++) {
            #pragma unroll
            for (int rr2 = 0; rr2 < 4; rr2++) {
                float v0 = acc[i][0][rr2] + bias[n0 + wn + l16];
                float v1 = acc[i][1][rr2] + bias[n0 + wn + 16 + l16];
                float m = fmaxf(v0, v1);
                #pragma unroll
                for (int off = 1; off < 16; off <<= 1)
                    m = fmaxf(m, __shfl_xor(m, off));
                float e0 = __expf(v0 - m), e1 = __expf(v1 - m);
                float s = e0 + e1;
                #pragma unroll
                for (int off = 1; off < 16; off <<= 1)
                    s += __shfl_xor(s, off);
                float inv = 1.f / s;
                size_t row = (size_t)(m0 + wm + i * 16 + quad * 4 + rr2) * ldc;
                C[row + n0 + wn + l16] = e0 * inv;
                C[row + n0 + wn + 16 + l16] = e1 * inv;
            }
        }
        return;
    }
    #pragma unroll
    for (int j = 0; j < 2; j++) {
        int n = n0 + wn + j * 16 + l16;
        float bv = (flags & 1) ? bias[n] : 0.f;
        bool do_sp = (flags & 4) && (n < 1024);
        float spb = do_sp ? bias[n] : 0.f;
        #pragma unroll
        for (int i = 0; i < 2; i++) {
            int mrow = m0 + wm + i * 16 + quad * 4;
            #pragma unroll
            for (int rr2 = 0; rr2 < 4; rr2++) {
                size_t idx = (size_t)(mrow + rr2) * ldc + n;
                float v = acc[i][j][rr2] + bv;
                if (do_sp) {
                    v += spb;
                    v = (v > 20.f) ? v : log1pf(__expf(v));
                }
                if (flags & 8) {
                    Cb[idx] = f2bf(v);
                } else {
                    if (flags & 2) v += C[idx];
                    C[idx] = v;
                    if (flags & 16) Cb[idx] = f2bf(v);
                }
            }
        }
    }
}

// ---------------------------------------------------------------------------
// r17: stepA with FUSED conv+silu staging (conv_silu kernel deleted).
// Cpart[kq] = u[:, kq*256:(kq+1)*256] @ xw_t^T, where the A-tile
// u = silu(dwconv(xzb[:, :1024]) + bconv) is COMPUTED inline during
// staging (reg-stage, r15 stepB pattern: LDS[srow][(tid&7)*8] =
// f(global[srow][schunk]); byte-identical conv math to the r13 kernel),
// written to both LDS (own MFMA) and global ub (for the scans — grid
// covers each (row,d) exactly once: d-window = kq*256, rows = m0..+64).
// B staged via gll16. Single __syncthreads (compiler drains vm/lgkm).
// LDS 64 KB -> 2 blocks/CU (grid 256 = 1/CU).
// ---------------------------------------------------------------------------
__global__ __launch_bounds__(256, 2) void gemm_stepA_conv(
    const ushort_t* __restrict__ xz,   // [NTOK][2048] bf16 (xp|z)
    const float* __restrict__ w,       // conv_w [1024][4]
    const float* __restrict__ bconv,   // [1024]
    const ushort_t* __restrict__ Bt,   // xw_t [64][1024] bf16
    ushort_t* __restrict__ ub,         // u out [NTOK][1024] bf16
    float* __restrict__ Cpart)         // [4][NTOK][64]
{
    __shared__ ushort_t As[4][4096];   // 4 slabs of [64 rows][64 cols]
    __shared__ ushort_t Bs[4][4096];

    const int kq = blockIdx.x;          // 0..3 (d window)
    const int m0 = blockIdx.y * 64;
    const int k0 = kq * 256;

    const int tid = threadIdx.x;
    const int wv = tid >> 6;
    const int lane = tid & 63;
    const int quad = lane >> 4;
    const int l16 = lane & 15;
    const int wm = (wv & 1) * 32;
    const int wn = (wv >> 1) * 32;

    const int srow = tid >> 3;                    // 0..31
    const int schunk = ((tid & 7) ^ (srow & 7)) * 8;
    const int lofs = tid * 8;

    // B: gll16 staging, 4 slabs x 2 rows/thread.
    #pragma unroll
    for (int s = 0; s < 4; s++) {
        const ushort_t* gb = Bt + (size_t)srow * 1024 + k0 + s * 64 + schunk;
        gll16(gb, &Bs[s][lofs]);
        gll16(gb + (size_t)32 * 1024, &Bs[s][2048 + lofs]);
    }

    // A: inline conv+silu (same math/order as the r13 conv kernel).
    #pragma unroll
    for (int s = 0; s < 4; s++) {
        #pragma unroll
        for (int half = 0; half < 2; half++) {
            const int row = m0 + srow + half * 32;
            const int t = row & (SEQ - 1);
            const int d0 = k0 + s * 64 + schunk;
            short8 xv[4];
            #pragma unroll
            for (int k = 0; k < KCONV; k++) {
                if (t + k - (KCONV - 1) >= 0)
                    xv[k] = *(const short8*)(xz +
                        (size_t)(row + k - (KCONV - 1)) * 2048 + d0);
                else
                    xv[k] = short8{0, 0, 0, 0, 0, 0, 0, 0};
            }
            short8 o;
            #pragma unroll
            for (int q = 0; q < 8; q++) {
                floatx4 wq = *(const floatx4*)&w[(size_t)(d0 + q) * KCONV];
                float sa = 0.f;
                #pragma unroll
                for (int k = 0; k < KCONV; k++)
                    sa = fmaf(bf2f((ushort_t)xv[k][q]), wq[k], sa);
                sa += bconv[d0 + q];
                float r = sa / (1.f + __expf(-sa));
                o[q] = (short)f2bf(r);
            }
            *(short8*)&As[s][half * 2048 + lofs] = o;
            *(short8*)&ub[(size_t)row * D_INNER + d0] = o;
        }
    }
    __syncthreads();   // drains gll16 (vmcnt) + orders LDS writes

    const int swz0 = ((0 * 4 + quad) ^ (l16 & 7)) * 8;
    const int swz1 = ((1 * 4 + quad) ^ (l16 & 7)) * 8;

    floatx4 acc[2][2] = {};
    #pragma unroll
    for (int s = 0; s < 4; s++) {
        short8 af[2][2], bfr[2][2];
        #pragma unroll
        for (int i = 0; i < 2; i++) {
            const int r = wm + i * 16 + l16;
            af[0][i] = *(const short8*)&As[s][r * 64 + swz0];
            af[1][i] = *(const short8*)&As[s][r * 64 + swz1];
        }
        #pragma unroll
        for (int j = 0; j < 2; j++) {
            const int r = wn + j * 16 + l16;
            bfr[0][j] = *(const short8*)&Bs[s][r * 64 + swz0];
            bfr[1][j] = *(const short8*)&Bs[s][r * 64 + swz1];
        }
        #pragma unroll
        for (int ks = 0; ks < 2; ks++)
            #pragma unroll
            for (int i = 0; i < 2; i++)
                #pragma unroll
                for (int j = 0; j < 2; j++)
                    acc[i][j] = __builtin_amdgcn_mfma_f32_16x16x32_bf16(
                        af[ks][i], bfr[ks][j], acc[i][j], 0, 0, 0);
    }

    float* Cp = Cpart + (size_t)kq * NTOK * 64;
    #pragma unroll
    for (int j = 0; j < 2; j++) {
        int n = wn + j * 16 + l16;
        #pragma unroll
        for (int i = 0; i < 2; i++) {
            int mrow = m0 + wm + i * 16 + quad * 4;
            #pragma unroll
            for (int rr2 = 0; rr2 < 4; rr2++)
                Cp[(size_t)(mrow + rr2) * 64 + n] = acc[i][j][rr2];
        }
    }
}

// ---------------------------------------------------------------------------
// stepB with INLINE split-K reduction (r15-verified).
// dtb = softplus(sum_kq(part[kq]) @ W2t^T + dt_b); single K=64 tile.
// Blocks with swz%gx==0 also write fp32 dblr (B/C for the scan).
// ---------------------------------------------------------------------------
__global__ __launch_bounds__(256, 3) void gemm_stepB(
    const float* __restrict__ part,   // [4][NTOK][64] split-K partials
    const ushort_t* __restrict__ Bt,  // [1024][64] bf16 (w2t)
    float* __restrict__ dblr,         // [NTOK][64] fp32 (side output)
    float* __restrict__ dtb,          // [NTOK][1024] fp32
    const float* __restrict__ bias)   // dt_b
{
    __shared__ ushort_t As[4096];   // 64 x 64 bf16
    __shared__ ushort_t Bs[4096];

    const int gx = gridDim.x;            // 16
    const int nwg = gx * gridDim.y;      // 1024 (%8==0)
    const int orig = blockIdx.y * gx + blockIdx.x;
    const int qq = nwg >> 3, rr = nwg & 7;
    const int xcd = orig & 7, loc = orig >> 3;
    const int swz = (xcd < rr ? xcd * (qq + 1) : rr * (qq + 1) + (xcd - rr) * qq) + loc;
    const int m0 = (swz / gx) * 64;
    const int n0 = (swz % gx) * 64;
    const bool wdblr = ((swz % gx) == 0);

    const int tid = threadIdx.x;
    const int w = tid >> 6;
    const int lane = tid & 63;
    const int quad = lane >> 4;
    const int l16 = lane & 15;
    const int wm = (w & 1) * 32;
    const int wn = (w >> 1) * 32;

    const int srow = tid >> 3;                    // 0..31
    const int schunk = ((tid & 7) ^ (srow & 7)) * 8;
    const int lofs = tid * 8;

    // B: gll16 staging (w2t rows n0+srow, n0+srow+32).
    const ushort_t* gb = Bt + (size_t)(n0 + srow) * 64 + schunk;
    gll16(gb, &Bs[lofs]);
    gll16(gb + (size_t)32 * 64, &Bs[2048 + lofs]);

    // A: inline 4-way reduction, rows m0+srow and m0+srow+32.
    const size_t st = (size_t)NTOK * 64;
    const float* pa0 = part + (size_t)(m0 + srow) * 64 + schunk;
    const float* pa1 = pa0 + (size_t)32 * 64;
    floatx4 a0l = *(const floatx4*)(pa0);
    floatx4 a0h = *(const floatx4*)(pa0 + 4);
    floatx4 a1l = *(const floatx4*)(pa1);
    floatx4 a1h = *(const floatx4*)(pa1 + 4);
    #pragma unroll
    for (int kq = 1; kq < 4; kq++) {
        a0l += *(const floatx4*)(pa0 + (size_t)kq * st);
        a0h += *(const floatx4*)(pa0 + (size_t)kq * st + 4);
        a1l += *(const floatx4*)(pa1 + (size_t)kq * st);
        a1h += *(const floatx4*)(pa1 + (size_t)kq * st + 4);
    }
    short8 u0, u1;
    #pragma unroll
    for (int q = 0; q < 4; q++) {
        u0[q] = (short)f2bf(a0l[q]); u0[4 + q] = (short)f2bf(a0h[q]);
        u1[q] = (short)f2bf(a1l[q]); u1[4 + q] = (short)f2bf(a1h[q]);
    }
    *(short8*)&As[lofs] = u0;
    *(short8*)&As[2048 + lofs] = u1;
    if (wdblr) {
        float* d0 = dblr + (size_t)(m0 + srow) * 64 + schunk;
        *(floatx4*)(d0) = a0l;       *(floatx4*)(d0 + 4) = a0h;
        *(floatx4*)(d0 + 32 * 64) = a1l; *(floatx4*)(d0 + 32 * 64 + 4) = a1h;
    }
    __syncthreads();

    const int swz0 = ((0 * 4 + quad) ^ (l16 & 7)) * 8;
    const int swz1 = ((1 * 4 + quad) ^ (l16 & 7)) * 8;

    floatx4 acc[2][2] = {};
    short8 af[2][2], bfr[2][2];
    #pragma unroll
    for (int i = 0; i < 2; i++) {
        const int r = wm + i * 16 + l16;
        af[0][i] = *(const short8*)&As[r * 64 + swz0];
        af[1][i] = *(const short8*)&As[r * 64 + swz1];
    }
    #pragma unroll
    for (int j = 0; j < 2; j++) {
        const int r = wn + j * 16 + l16;
        bfr[0][j] = *(const short8*)&Bs[r * 64 + swz0];
        bfr[1][j] = *(const short8*)&Bs[r * 64 + swz1];
    }
    #pragma unroll
    for (int ks = 0; ks < 2; ks++)
        #pragma unroll
        for (int i = 0; i < 2; i++)
            #pragma unroll
            for (int j = 0; j < 2; j++)
                acc[i][j] = __builtin_amdgcn_mfma_f32_16x16x32_bf16(
                    af[ks][i], bfr[ks][j], acc[i][j], 0, 0, 0);

    // epilogue: softplus(v + dt_b[n]) -> dtb
    #pragma unroll
    for (int j = 0; j < 2; j++) {
        int n = n0 + wn + j * 16 + l16;
        float spb = bias[n];
        #pragma unroll
        for (int i = 0; i < 2; i++) {
            int mrow = m0 + wm + i * 16 + quad * 4;
            #pragma unroll
            for (int rr2 = 0; rr2 < 4; rr2++) {
                float v = acc[i][j][rr2] + spb;
                v = (v > 20.f) ? v : log1pf(__expf(v));
                dtb[(size_t)(mrow + rr2) * 1024 + n] = v;
            }
        }
    }
}

// ---------------------------------------------------------------------------
// r16: ONE mega-prep kernel (5 transposes + build_w2t + x->bf16 cast).
// Sections (block ranges):
//   [0,512)        lin1_w  [1024][512]  -> lin1_wt  (gxt=16)
//   [512,4608)     in_w    4x[512][2048]-> in_wt    (gxt=64, 1024/layer)
//   [4608,6656)    out_w   4x[1024][512]-> out_wt   (gxt=16, 512/layer)
//   [6656,6912)    xproj_w 4x[1024][64] -> xw_t     (gxt=2,  64/layer)
//   [6912,7424)    lin2_w  [512][1024]  -> lin2_wt  (gxt=32)
//   [7424,8448)    build_w2t (1024 elementwise blocks)
//   [8448,10496)   x -> xb vector cast (2048 blocks, 8 elems/thread)
// ---------------------------------------------------------------------------
__global__ __launch_bounds__(256) void prep_all(
    const float* __restrict__ lin1_w, const float* __restrict__ in_w,
    const float* __restrict__ out_w, const float* __restrict__ xproj_w,
    const float* __restrict__ lin2_w, const float* __restrict__ dt_w,
    const float* __restrict__ x,
    ushort_t* __restrict__ lin1_wt, ushort_t* __restrict__ in_wt,
    ushort_t* __restrict__ out_wt, ushort_t* __restrict__ xw_t,
    ushort_t* __restrict__ lin2_wt, ushort_t* __restrict__ w2t,
    ushort_t* __restrict__ xb)
{
    const int bid = blockIdx.x;
    const int tid = threadIdx.x;

    if (bid >= 8448) {                       // x -> bf16 cast
        const int i = ((bid - 8448) * 256 + tid) * 8;
        floatx4 a = *(const floatx4*)&x[i];
        floatx4 b = *(const floatx4*)&x[i + 4];
        short8 o;
        o[0] = (short)f2bf(a[0]); o[1] = (short)f2bf(a[1]);
        o[2] = (short)f2bf(a[2]); o[3] = (short)f2bf(a[3]);
        o[4] = (short)f2bf(b[0]); o[5] = (short)f2bf(b[1]);
        o[6] = (short)f2bf(b[2]); o[7] = (short)f2bf(b[3]);
        *(short8*)&xb[i] = o;
        return;
    }
    if (bid >= 7424) {                       // build_w2t
        const int idx = (bid - 7424) * 256 + tid;
        const int k = idx & 63;
        const int n = (idx >> 6) & 1023;
        const int l = idx >> 16;
        ushort_t v = 0;
        if (k < 32)
            v = f2bf(dt_w[((size_t)l * DT_RANK + k) * D_INNER + n]);
        w2t[((size_t)l * 1024 + n) * 64 + k] = v;
        return;
    }

    // transpose sections: in[K][N] -> out[N][K] bf16, 32x32 tiles.
    const float* in; ushort_t* out; int K, N, t;
    if (bid < 512) {
        in = lin1_w; out = lin1_wt; K = 1024; N = 512; t = bid;
    } else if (bid < 4608) {
        int lb = bid - 512, l = lb >> 10; t = lb & 1023;
        in = in_w + (size_t)l * 512 * 2048; out = in_wt + (size_t)l * 2048 * 512;
        K = 512; N = 2048;
    } else if (bid < 6656) {
        int lb = bid - 4608, l = lb >> 9; t = lb & 511;
        in = out_w + (size_t)l * 1024 * 512; out = out_wt + (size_t)l * 512 * 1024;
        K = 1024; N = 512;
    } else if (bid < 6912) {
        int lb = bid - 6656, l = lb >> 6; t = lb & 63;
        in = xproj_w + (size_t)l * 1024 * 64; out = xw_t + (size_t)l * 64 * 1024;
        K = 1024; N = 64;
    } else {
        in = lin2_w; out = lin2_wt; K = 512; N = 1024; t = bid - 6912;
    }
    const int gxt = N >> 5;
    const int n0 = (t % gxt) * 32, k0 = (t / gxt) * 32;

    __shared__ float tile[32][33];
    const int tx = tid & 31, ty = tid >> 5;
    #pragma unroll
    for (int i = 0; i < 4; i++)
        tile[ty + i * 8][tx] = in[(size_t)(k0 + ty + i * 8) * N + n0 + tx];
    __syncthreads();
    #pragma unroll
    for (int i = 0; i < 4; i++)
        out[(size_t)(n0 + ty + i * 8) * K + k0 + tx] = f2bf(tile[tx][ty + i * 8]);
}

// ---------------------------------------------------------------------------
// rmsnorm with float2 loads/stores (G13, r13-verified).
// ---------------------------------------------------------------------------
__global__ __launch_bounds__(256) void rmsnorm_kernel(
    const float* __restrict__ x, const float* __restrict__ w,
    ushort_t* __restrict__ y)
{
    const int row = blockIdx.x;
    const float* xr = x + (size_t)row * D_MODEL;
    ushort_t* yr = y + (size_t)row * D_MODEL;
    const int tid = threadIdx.x;

    float2 v = *(const float2*)&xr[tid * 2];
    float ss = v.x * v.x + v.y * v.y;
    #pragma unroll
    for (int off = 32; off > 0; off >>= 1) ss += __shfl_down(ss, off);

    __shared__ float wsum[4];
    __shared__ float scale_s;
    int wid = tid >> 6, lane = tid & 63;
    if (lane == 0) wsum[wid] = ss;
    __syncthreads();
    if (tid == 0) {
        float tot = wsum[0] + wsum[1] + wsum[2] + wsum[3];
        scale_s = 1.0f / sqrtf(tot / (float)D_MODEL + 1e-5f);
    }
    __syncthreads();
    float sc = scale_s;
    float2 wv = *(const float2*)&w[tid * 2];
    ushort2 o;
    o.x = f2bf(v.x * sc * wv.x);
    o.y = f2bf(v.y * sc * wv.y);
    *(ushort2*)&yr[tid * 2] = o;
}

// ---------------------------------------------------------------------------
// Chunked selective scan (3 passes), CLEN=32 — r10/r12 structure.
// ---------------------------------------------------------------------------
__global__ __launch_bounds__(256) void scan_pass1(
    const float* __restrict__ dtb, const float* __restrict__ bc,
    const ushort_t* __restrict__ ub, const float* __restrict__ A_log,
    float* __restrict__ hfin, float* __restrict__ sumdt)
{
    const int tid = threadIdx.x;
    const int b = blockIdx.x >> 7;
    const int p = (blockIdx.x >> 2) & 31;
    const int d = ((blockIdx.x & 3) << 8) + tid;
    const int t0 = p * CLEN;

    float A[D_STATE];
    #pragma unroll
    for (int n = 0; n < D_STATE; n++) A[n] = -expf(A_log[d * D_STATE + n]);

    float h[D_STATE] = {};
    float sdt = 0.f;

    const float* dtp = dtb + ((size_t)b * SEQ + t0) * 1024 + d;
    const float* bp  = bc + ((size_t)b * SEQ + t0) * 64 + 32;
    const ushort_t* up = ub + ((size_t)b * SEQ + t0) * D_INNER + d;

    for (int t = 0; t < CLEN; t++) {
        float dtv = dtp[(size_t)t * 1024];
        float uv  = bf2f(up[(size_t)t * D_INNER]);
        float dtu = dtv * uv;
        sdt += dtv;
        #pragma unroll
        for (int n = 0; n < D_STATE; n++)
            h[n] = fmaf(__expf(dtv * A[n]), h[n], dtu * bp[t * 64 + n]);
    }

    size_t base = (size_t)(b * PCH + p) * D_STATE * D_INNER + d;
    #pragma unroll
    for (int n = 0; n < D_STATE; n++) hfin[base + (size_t)n * D_INNER] = h[n];
    sumdt[(size_t)(b * PCH + p) * D_INNER + d] = sdt;
}

// preload all 32 chunk-final states + sumdt, then recurrence as pure VALU.
__global__ __launch_bounds__(256) void scan_pass2(
    const float* __restrict__ A_log, const float* __restrict__ sumdt,
    float* __restrict__ hc)
{
    const int tid = threadIdx.x;
    const int b = blockIdx.x >> 6;
    const int n = (blockIdx.x >> 2) & 15;
    const int d = ((blockIdx.x & 3) << 8) + tid;

    const float Aval = -expf(A_log[d * D_STATE + n]);

    float fin[PCH], sd[PCH];
    #pragma unroll
    for (int p = 0; p < PCH; p++) {
        fin[p] = hc[((size_t)(b * PCH + p) * D_STATE + n) * D_INNER + d];
        sd[p]  = sumdt[(size_t)(b * PCH + p) * D_INNER + d];
    }
    float h = 0.f;
    #pragma unroll
    for (int p = 0; p < PCH; p++) {
        hc[((size_t)(b * PCH + p) * D_STATE + n) * D_INNER + d] = h;
        h = fmaf(__expf(Aval * sd[p]), h, fin[p]);
    }
}

// pass3: u (bf16, in ub) read then overwritten IN PLACE with y*silu(z).
__global__ __launch_bounds__(256) void scan_pass3(
    const float* __restrict__ dtb, const float* __restrict__ bc,
    const ushort_t* __restrict__ xz, const float* __restrict__ A_log,
    const float* __restrict__ Dp, const float* __restrict__ hstart,
    ushort_t* ub)
{
    const int tid = threadIdx.x;
    const int b = blockIdx.x >> 7;
    const int p = (blockIdx.x >> 2) & 31;
    const int d = ((blockIdx.x & 3) << 8) + tid;
    const int t0 = p * CLEN;

    float A[D_STATE];
    #pragma unroll
    for (int n = 0; n < D_STATE; n++) A[n] = -expf(A_log[d * D_STATE + n]);
    const float Dv = Dp[d];

    float h[D_STATE];
    size_t base = (size_t)(b * PCH + p) * D_STATE * D_INNER + d;
    #pragma unroll
    for (int n = 0; n < D_STATE; n++) h[n] = hstart[base + (size_t)n * D_INNER];

    const float* dtp = dtb + ((size_t)b * SEQ + t0) * 1024 + d;
    const float* bp  = bc + ((size_t)b * SEQ + t0) * 64 + 32;
    const ushort_t* zp = xz + ((size_t)b * SEQ + t0) * 2048 + 1024 + d;
    ushort_t* up = ub + ((size_t)b * SEQ + t0) * D_INNER + d;

    for (int t = 0; t < CLEN; t++) {
        float dtv = dtp[(size_t)t * 1024];
        float uv  = bf2f(up[(size_t)t * D_INNER]);
        float zv  = bf2f(zp[(size_t)t * 2048]);
        float dtu = dtv * uv;
        float y = 0.f;
        #pragma unroll
        for (int n = 0; n < D_STATE; n++) {
            h[n] = fmaf(__expf(dtv * A[n]), h[n], dtu * bp[t * 64 + n]);
            y = fmaf(h[n], bp[t * 64 + 16 + n], y);
        }
        float res = fmaf(uv, Dv, y);
        res *= zv / (1.f + __expf(-zv));
        up[(size_t)t * D_INNER] = f2bf(res);
    }
}

// ---------------------------------------------------------------------------
extern "C" void kernel_launch(void* const* d_in, const int* in_sizes, int n_in,
                              void* d_out, int out_size, void* d_ws, size_t ws_size,
                              hipStream_t stream)
{
    const float* x       = (const float*)d_in[0];
    const float* lin1_w  = (const float*)d_in[1];
    const float* lin1_b  = (const float*)d_in[2];
    const float* norm_w  = (const float*)d_in[3];
    const float* in_w    = (const float*)d_in[4];
    const float* conv_w  = (const float*)d_in[5];
    const float* conv_b  = (const float*)d_in[6];
    const float* xproj_w = (const float*)d_in[7];
    const float* dt_w    = (const float*)d_in[8];
    const float* dt_b    = (const float*)d_in[9];
    const float* A_log   = (const float*)d_in[10];
    const float* Dp      = (const float*)d_in[11];
    const float* out_w   = (const float*)d_in[12];
    const float* lin2_w  = (const float*)d_in[13];
    const float* lin2_b  = (const float*)d_in[14];
    float* outp = (float*)d_out;
    (void)ws_size; (void)in_sizes; (void)n_in; (void)out_size;

    float* ws = (float*)d_ws;
    const size_t F1M = 1u << 20;
    float* h     = ws;                                  // 2M fl
    float* dtb   = h + 2 * F1M;                         // 4M fl (dt)
    float* dblr  = dtb + 4 * F1M;                       // 256K fl
    float* dpart = dblr + (size_t)NTOK * 64;            // 1M fl (4 split-K partials)
    float* sumdt = dpart + (size_t)4 * NTOK * 64;       // 128K fl
    float* hfin  = sumdt + (size_t)BATCH * PCH * D_INNER;  // 2M fl
    ushort_t* xzb     = (ushort_t*)(hfin + 2 * F1M);       // 8M us (xp|z, 2048)
    ushort_t* hn_bf   = xzb + 8 * F1M;                     // 2M us
    ushort_t* xb      = hn_bf + 2 * F1M;                   // 4M us
    ushort_t* dblr_bf = xb + 4 * F1M;                      // 256K us (unused, kept)
    ushort_t* lin1_wt = dblr_bf + (size_t)NTOK * 64;       // 512*1024
    ushort_t* in_wt   = lin1_wt + (size_t)512 * 1024;      // 4*2048*512
    ushort_t* out_wt  = in_wt + (size_t)4 * 2048 * 512;    // 4*512*1024
    ushort_t* lin2_wt = out_wt + (size_t)4 * 512 * 1024;   // 1024*512
    ushort_t* xw_t    = lin2_wt + (size_t)1024 * 512;      // 4*64*1024
    ushort_t* w2t     = xw_t + (size_t)4 * 64 * 1024;      // 4*1024*64

    dim3 blk(256);

    // --- all prep (5 transposes + w2t + x-cast) in ONE launch (r16) ---
    prep_all<<<dim3(10496), blk, 0, stream>>>(
        lin1_w, in_w, out_w, xproj_w, lin2_w, dt_w, x,
        lin1_wt, in_wt, out_wt, xw_t, lin2_wt, w2t, xb);

    // lin1: h = x_bf @ lin1_wt^T + b  (fp32 out; 8x64=512 blocks)
    gemm_bf16_tile<<<dim3(D_MODEL / 64, NTOK / 64), blk, 0, stream>>>(
        xb, LATENT, lin1_wt, LATENT, h, nullptr, D_MODEL, lin1_b,
        NTOK, D_MODEL, LATENT, 1);

    for (int l = 0; l < N_LAYERS; l++) {
        const float* nw = norm_w + (size_t)l * D_MODEL;
        const float* cw = conv_w + (size_t)l * D_INNER * KCONV;
        const float* cb = conv_b + (size_t)l * D_INNER;
        const float* db = dt_b + (size_t)l * D_INNER;
        const float* al = A_log + (size_t)l * D_INNER * D_STATE;
        const float* dp = Dp + (size_t)l * D_INNER;
        const ushort_t* iwt = in_wt + (size_t)l * 2048 * 512;
        const ushort_t* owt = out_wt + (size_t)l * 512 * 1024;
        const ushort_t* xwt = xw_t + (size_t)l * 64 * 1024;
        const ushort_t* w2  = w2t + (size_t)l * 1024 * 64;

        rmsnorm_kernel<<<dim3(NTOK), blk, 0, stream>>>(h, nw, hn_bf);

        // fused in-proj: xzb = hn @ in_w[l] (bf16 out; 256^2 2-phase)
        gemm_bf16_t256<<<dim3(2048 / 256, NTOK / 256), dim3(512), 0, stream>>>(
            hn_bf, D_MODEL, iwt, D_MODEL, xzb, 2048, NTOK, 2048, D_MODEL);

        // r17: stepA with FUSED conv+silu staging (conv_silu kernel deleted).
        // Reads xzb, computes u inline, writes u to xb AND uses it as the
        // A-operand; dpart[kq] = u @ xw_t^T  (4x64=256 blocks).
        gemm_stepA_conv<<<dim3(4, NTOK / 64), blk, 0, stream>>>(
            xzb, cw, cb, xwt, xb, dpart);

        // step B with inline reduce: dtb = softplus(sum(dpart) @ W2t^T + dt_b)
        // + fp32 dblr side-output (r15-verified).
        gemm_stepB<<<dim3(1024 / 64, NTOK / 64), blk, 0, stream>>>(
            dpart, w2, dblr, dtb, db);

        // chunked scan; pass3 overwrites xb in place with y*silu(z)
        scan_pass1<<<dim3(BATCH * PCH * (D_INNER / 256)), blk, 0, stream>>>(
            dtb, dblr, xb, al, hfin, sumdt);
        scan_pass2<<<dim3(BATCH * D_STATE * (D_INNER / 256)), blk, 0, stream>>>(
            al, sumdt, hfin);
        scan_pass3<<<dim3(BATCH * PCH * (D_INNER / 256)), blk, 0, stream>>>(
            dtb, dblr, xzb, al, dp, hfin, xb);

        // h += y_bf @ out_wt^T  (fp32 accumulate; 8x64=512 blocks).
        // Last layer also emits bf16(h) -> hn_bf for lin2 (flag 16).
        gemm_bf16_tile<<<dim3(D_MODEL / 64, NTOK / 64), blk, 0, stream>>>(
            xb, D_INNER, owt, D_INNER, h, hn_bf, D_MODEL, nullptr,
            NTOK, D_MODEL, D_INNER, (l == N_LAYERS - 1) ? 18 : 2);
    }

    // lin2 with FUSED softmax epilogue (flag 32): writes outp directly.
    gemm_bf16_tile<<<dim3(LATENT / 64, NTOK / 64), blk, 0, stream>>>(
        hn_bf, D_MODEL, lin2_wt, D_MODEL, outp, nullptr, LATENT, lin2_b,
        NTOK, LATENT, D_MODEL, 1 | 32);
}